// Round 1
// baseline (364.593 us; speedup 1.0000x reference)
//
#include <hip/hip_runtime.h>

#define MMOD 8
#define BB 8192
#define DD 256

typedef unsigned short u16;
typedef __attribute__((ext_vector_type(8))) short s16x8;
typedef __attribute__((ext_vector_type(4))) float f32x4;
typedef __attribute__((ext_vector_type(8))) unsigned short u16x8;

typedef __attribute__((address_space(3))) unsigned short lds_u16;
typedef __attribute__((address_space(1))) const unsigned short gl_u16;

__device__ __forceinline__ float b2f(u16 u){ union{unsigned i; float f;} x; x.i=((unsigned)u)<<16; return x.f; }
__device__ __forceinline__ u16 f2b(float f){ union{float f; unsigned i;} x; x.f=f; unsigned r = x.i + 0x7FFF + ((x.i>>16)&1u); return (u16)(r>>16); }

// async global->LDS: per-lane src address, LDS dest = wave-uniform base + lane*16B
__device__ __forceinline__ void async_cp16(const u16* g, u16* l){
  __builtin_amdgcn_global_load_lds((gl_u16*)g, (lds_u16*)l, 16, 0, 0);
}

// ---------------- fp32 -> bf16 conversion ----------------
struct ConvArgs {
  const float* src[10];
  u16*         dst[10];
  int          n[10];
};
__global__ void convert_kernel(ConvArgs a){
  const long long stride = (long long)gridDim.x * blockDim.x;
  const long long base   = (long long)blockIdx.x * blockDim.x + threadIdx.x;
  for (int s = 0; s < 10; s++){
    const int n  = a.n[s];
    const int n8 = n >> 3;
    const float* sp = a.src[s];
    u16* dst = a.dst[s];
    for (long long i = base; i < n8; i += stride){
      float4 lo = ((const float4*)sp)[i*2];
      float4 hi = ((const float4*)sp)[i*2+1];
      u16x8 p;
      p[0]=f2b(lo.x); p[1]=f2b(lo.y); p[2]=f2b(lo.z); p[3]=f2b(lo.w);
      p[4]=f2b(hi.x); p[5]=f2b(hi.y); p[6]=f2b(hi.z); p[7]=f2b(hi.w);
      *(u16x8*)(dst + (i<<3)) = p;
    }
    for (long long i = ((long long)n8<<3) + base; i < n; i += stride)
      dst[i] = f2b(sp[i]);
  }
}

__device__ __forceinline__ s16x8 load8_f32(const float* p, long long idx){
  float4 lo = *(const float4*)(p + idx);
  float4 hi = *(const float4*)(p + idx + 4);
  s16x8 r;
  r[0]=(short)f2b(lo.x); r[1]=(short)f2b(lo.y); r[2]=(short)f2b(lo.z); r[3]=(short)f2b(lo.w);
  r[4]=(short)f2b(hi.x); r[5]=(short)f2b(hi.y); r[6]=(short)f2b(hi.z); r[7]=(short)f2b(hi.w);
  return r;
}

struct GArgs {
  const u16* A;  long long a_z; long long a_piece; int lda;  // A + z*a_z + (k>>8)*a_piece + b*lda + (k&255)
  const u16* A2; long long a2_z;                             // if non-null: base for k>=256
  const u16* B;  long long b_z; int ldb;                     // B + z*b_z + n*ldb + k   ([N,K] layout)
  u16*       C;  long long c_z; long long c_npiece; int ldc; // C + z*c_z + (n>>8)*c_npiece + b*ldc + (n&255)
  const u16* bias; long long bias_z;   // bf16 bias[n] (per z), optional
  const float* cbias;                  // fp32 bias[global n], optional
  const u16* addm;                     // bf16 addend [b,256] (shared across z), optional
  const u16* wc2;                      // score kernel: bf16 [256]
  float*     scores;                   // score kernel: [z*8192 + b]
  float scale;
  int K;
  int relu;
};

// ---------- fat tile: 128x128, BK=64 (kept for fallback/reference; unused) ----------
__global__ __launch_bounds__(256, 2) void gemm_bt(GArgs g){
  alignas(16) __shared__ u16 lA[128*64];
  alignas(16) __shared__ u16 lB[128*64];
  const int tid  = threadIdx.x;
  const int lane = tid & 63;
  const int w    = tid >> 6;
  const int z    = blockIdx.z;

  const u16* Bbase = g.B + (long long)z * g.b_z + (long long)(blockIdx.y * 128) * g.ldb;

  f32x4 acc[4][4];
  #pragma unroll
  for (int i=0;i<4;i++)
    #pragma unroll
    for (int j=0;j<4;j++)
      #pragma unroll
      for (int r=0;r<4;r++) acc[i][j][r] = 0.0f;

  const int wr = (w >> 1) * 64, wc = (w & 1) * 64;
  const int fm = lane & 15;
  const int fk = (lane >> 4) * 8;
  const long long arow0 = (long long)blockIdx.x * 128;

  const int sr = lane >> 3;
  const int sq = (lane & 7) ^ sr;

  for (int k0 = 0; k0 < g.K; k0 += 64){
    const u16* Abase0 = (g.A2 && k0 >= 256) ? (g.A2 + (long long)z * g.a2_z)
                                            : (g.A  + (long long)z * g.a_z);
    const u16* At = Abase0 + (long long)(k0 >> 8) * g.a_piece + (k0 & 255);
    const u16* Bt = Bbase + k0;
    __syncthreads();
    #pragma unroll
    for (int i=0;i<4;i++){
      int r = i*32 + w*8 + sr;
      async_cp16(At + (arow0 + r) * (long long)g.lda + sq*8, lA + (i*256 + w*64) * 8);
      async_cp16(Bt + (long long)r * g.ldb + sq*8, lB + (i*256 + w*64) * 8);
    }
    __syncthreads();
    #pragma unroll
    for (int kk = 0; kk < 64; kk += 32){
      s16x8 af[4], bfr[4];
      const int qf = (kk + fk) >> 3;
      #pragma unroll
      for (int mi=0; mi<4; mi++){
        int r = wr + mi*16 + fm;
        af[mi] = *(const s16x8*)(lA + (r*8 + (qf ^ (r & 7))) * 8);
      }
      #pragma unroll
      for (int ni=0; ni<4; ni++){
        int r = wc + ni*16 + fm;
        bfr[ni] = *(const s16x8*)(lB + (r*8 + (qf ^ (r & 7))) * 8);
      }
      #pragma unroll
      for (int mi=0; mi<4; mi++)
        #pragma unroll
        for (int ni=0; ni<4; ni++)
          acc[mi][ni] = __builtin_amdgcn_mfma_f32_16x16x32_bf16(af[mi], bfr[ni], acc[mi][ni], 0, 0, 0);
    }
  }

  u16* Cb = g.C + (long long)z * g.c_z;
  const u16* biasp = g.bias ? g.bias + (long long)z * g.bias_z : (const u16*)0;
  #pragma unroll
  for (int mi=0; mi<4; mi++){
    #pragma unroll
    for (int ni=0; ni<4; ni++){
      int n = blockIdx.y*128 + wc + ni*16 + fm;
      float bb = 0.0f;
      if (g.cbias) bb = g.cbias[n];
      else if (biasp) bb = b2f(biasp[n]);
      long long cn = ((long long)(n >> 8)) * g.c_npiece + (n & 255);
      #pragma unroll
      for (int r=0; r<4; r++){
        long long b = arow0 + wr + mi*16 + (lane>>4)*4 + r;
        float v = acc[mi][ni][r] * g.scale + bb;
        if (g.addm) v += b2f(g.addm[b*256 + n]);
        if (g.relu) v = v > 0.0f ? v : 0.0f;
        Cb[cn + b * (long long)g.ldc] = f2b(v);
      }
    }
  }
}

// ---------- 256x256 8-phase pipelined GEMM (stage 2) ----------
// BM=BN=256, BK=64, 8 waves (2M x 4N), 512 threads, 128KB LDS (2 bufs x (A 32KB + B 32KB)).
// Per K-tile t, 4 phases (phase q computes m-quadrant {2q,2q+1} x all 4 n-frags x K=64 = 16 MFMA):
//   q0: issue A(t+1).h0 -> buf c^1 ; ds_read 8 B-frags + 4 A-frags ; bar ; MFMA ; bar
//   q1: issue A(t+1).h1 -> buf c^1 ; ds_read 4 A-frags            ; bar ; MFMA ; bar
//   q2: issue B(t+2).h0 -> buf c   ; (B slots of buf c were only read in q0 -> free)
//   q3: issue B(t+2).h1 -> buf c   ; ... MFMA ; s_waitcnt vmcnt(4) ; bar
// vmcnt(4) leaves only the 2 newest halves (B(t+2)) in flight => A(t+1),B(t+1) landed
// before tile t+1's reads. Never drains to 0 in steady state (T4). Raw s_barrier only.
__global__ __launch_bounds__(512, 2) void gemm_8ph(GArgs g){
  alignas(16) __shared__ u16 L[65536]; // [buf(2)][A/B(2)][256 rows * 64 cols]
  const int tid  = threadIdx.x;
  const int lane = tid & 63;
  const int w    = tid >> 6;        // 0..7
  const int z    = blockIdx.z;

  const int wr  = w >> 2;           // 0..1 : 128-row block
  const int wcn = w & 3;            // 0..3 : 64-col block
  const int fm  = lane & 15;
  const int fq  = lane >> 4;        // 0..3

  const long long arow0 = (long long)blockIdx.x * 256;
  const long long nrow0 = (long long)blockIdx.y * 256;

  // staging geometry: thread covers slots tid (rows 0..63 of half) and tid+512 (rows 64..127)
  const int r0  = tid >> 3;
  const int r1  = r0 + 64;
  const int cs  = tid & 7;
  const int gc0 = cs ^ (r0 & 7);    // swizzle: LDS(r,cs) = global(r, cs^(r&7))
  const int gc1 = cs ^ (r1 & 7);
  const int ldst0 = (w * 64) * 8;        // wave-uniform LDS base (u16 units), i=0
  const int ldst1 = (512 + w * 64) * 8;  // i=1

  const u16* Az = g.A + (long long)z * g.a_z;
  const u16* Bz = g.B + (long long)z * g.b_z;

#define STAGE_A8(c, k0s, h) do{ \
    const u16* gb_ = Az + (long long)((k0s) >> 8) * g.a_piece + ((k0s) & 255); \
    const long long gr_ = arow0 + (h) * 128; \
    u16* lb_ = L + ((c) * 2 + 0) * 16384 + (h) * 8192; \
    async_cp16(gb_ + (gr_ + r0) * (long long)g.lda + gc0 * 8, lb_ + ldst0); \
    async_cp16(gb_ + (gr_ + r1) * (long long)g.lda + gc1 * 8, lb_ + ldst1); \
  }while(0)
#define STAGE_B8(c, k0s, h) do{ \
    const u16* gb_ = Bz + (k0s); \
    const long long gr_ = nrow0 + (h) * 128; \
    u16* lb_ = L + ((c) * 2 + 1) * 16384 + (h) * 8192; \
    async_cp16(gb_ + (gr_ + r0) * (long long)g.ldb + gc0 * 8, lb_ + ldst0); \
    async_cp16(gb_ + (gr_ + r1) * (long long)g.ldb + gc1 * 8, lb_ + ldst1); \
  }while(0)

  f32x4 acc[8][4];
  #pragma unroll
  for (int i=0;i<8;i++)
    #pragma unroll
    for (int j=0;j<4;j++)
      #pragma unroll
      for (int r=0;r<4;r++) acc[i][j][r] = 0.0f;

  const int T = g.K >> 6;

  // prologue: A(0), B(0), B(1) -> allow B(1) (2 halves = 4 loads) in flight
  STAGE_A8(0, 0, 0);  STAGE_A8(0, 0, 1);
  STAGE_B8(0, 0, 0);  STAGE_B8(0, 0, 1);
  STAGE_B8(1, 64, 0); STAGE_B8(1, 64, 1);
  asm volatile("s_waitcnt vmcnt(4)" ::: "memory");
  __builtin_amdgcn_s_barrier();

  int c = 0;
  for (int t = 0; t < T; ++t, c ^= 1){
    const int k0 = t << 6;
    const u16* lA = L + (c * 2 + 0) * 16384;
    const u16* lB = L + (c * 2 + 1) * 16384;
    s16x8 bf[4][2];
    #pragma unroll
    for (int q = 0; q < 4; ++q){
      if (q == 0 && t + 1 < T) STAGE_A8(c ^ 1, k0 + 64, 0);
      if (q == 1 && t + 1 < T) STAGE_A8(c ^ 1, k0 + 64, 1);
      if (q == 2 && t + 2 < T) STAGE_B8(c,     k0 + 128, 0);
      if (q == 3 && t + 2 < T) STAGE_B8(c,     k0 + 128, 1);
      if (q == 0){
        #pragma unroll
        for (int ni = 0; ni < 4; ni++){
          const int R = wcn * 64 + ni * 16 + fm;
          #pragma unroll
          for (int kk = 0; kk < 2; kk++){
            const int qf = kk * 4 + fq;
            bf[ni][kk] = *(const s16x8*)(lB + R * 64 + ((qf ^ (R & 7)) << 3));
          }
        }
      }
      s16x8 af[2][2];
      #pragma unroll
      for (int j = 0; j < 2; j++){
        const int R = wr * 128 + (q * 2 + j) * 16 + fm;
        #pragma unroll
        for (int kk = 0; kk < 2; kk++){
          const int qf = kk * 4 + fq;
          af[j][kk] = *(const s16x8*)(lA + R * 64 + ((qf ^ (R & 7)) << 3));
        }
      }
      __builtin_amdgcn_s_barrier();
      __builtin_amdgcn_s_setprio(1);
      #pragma unroll
      for (int kk = 0; kk < 2; kk++)
        #pragma unroll
        for (int j = 0; j < 2; j++)
          #pragma unroll
          for (int ni = 0; ni < 4; ni++)
            acc[q*2+j][ni] = __builtin_amdgcn_mfma_f32_16x16x32_bf16(af[j][kk], bf[ni][kk], acc[q*2+j][ni], 0, 0, 0);
      __builtin_amdgcn_s_setprio(0);
      if (q == 3){
        if (t + 2 < T)      asm volatile("s_waitcnt vmcnt(4)" ::: "memory");
        else if (t + 1 < T) asm volatile("s_waitcnt vmcnt(0)" ::: "memory");
      }
      __builtin_amdgcn_s_barrier();
    }
  }

  u16* Cb = g.C + (long long)z * g.c_z;
  const u16* biasp = g.bias ? g.bias + (long long)z * g.bias_z : (const u16*)0;
  #pragma unroll
  for (int mi = 0; mi < 8; mi++){
    #pragma unroll
    for (int ni = 0; ni < 4; ni++){
      const int n = (int)nrow0 + wcn * 64 + ni * 16 + fm;
      float bb = 0.0f;
      if (g.cbias) bb = g.cbias[n];
      else if (biasp) bb = b2f(biasp[n]);
      const long long cn = ((long long)(n >> 8)) * g.c_npiece + (n & 255);
      #pragma unroll
      for (int r = 0; r < 4; r++){
        const long long b = arow0 + wr * 128 + mi * 16 + fq * 4 + r;
        float v = acc[mi][ni][r] * g.scale + bb;
        if (g.relu) v = v > 0.0f ? v : 0.0f;
        Cb[cn + b * (long long)g.ldc] = f2b(v);
      }
    }
  }
#undef STAGE_A8
#undef STAGE_B8
}

// ---------- thin full-N tile: 64 rows x 256 cols, BK=64 ----------
// wave w owns rows [w*16, w*16+16), all 256 n-cols (16 n-tiles). LDS 40KB -> 4 blocks/CU.
__global__ __launch_bounds__(256, 4) void gemm_thin(GArgs g){
  alignas(16) __shared__ u16 lA[64*64];
  alignas(16) __shared__ u16 lB[256*64];
  const int tid  = threadIdx.x;
  const int lane = tid & 63;
  const int w    = tid >> 6;
  const int z    = blockIdx.z;

  const u16* Bbase = g.B + (long long)z * g.b_z;

  f32x4 acc[16];
  #pragma unroll
  for (int j=0;j<16;j++)
    #pragma unroll
    for (int r=0;r<4;r++) acc[j][r] = 0.0f;

  const int fm = lane & 15;
  const int fk = (lane >> 4) * 8;
  const long long arow0 = (long long)blockIdx.x * 64;

  const int sr = lane >> 3;
  const int sq = (lane & 7) ^ sr;

  for (int k0 = 0; k0 < g.K; k0 += 64){
    const u16* Abase0 = (g.A2 && k0 >= 256) ? (g.A2 + (long long)z * g.a2_z)
                                            : (g.A  + (long long)z * g.a_z);
    const u16* At = Abase0 + (long long)(k0 >> 8) * g.a_piece + (k0 & 255);
    const u16* Bt = Bbase + k0;
    __syncthreads();
    #pragma unroll
    for (int i=0;i<2;i++){
      int r = i*32 + w*8 + sr;
      async_cp16(At + (arow0 + r) * (long long)g.lda + sq*8, lA + (i*256 + w*64) * 8);
    }
    #pragma unroll
    for (int i=0;i<8;i++){
      int r = i*32 + w*8 + sr;
      async_cp16(Bt + (long long)r * g.ldb + sq*8, lB + (i*256 + w*64) * 8);
    }
    __syncthreads();
    #pragma unroll
    for (int kk = 0; kk < 64; kk += 32){
      const int qf = (kk + fk) >> 3;
      int ra = w*16 + fm;
      s16x8 af = *(const s16x8*)(lA + (ra*8 + (qf ^ (ra & 7))) * 8);
      #pragma unroll
      for (int ni=0; ni<16; ni++){
        int r = ni*16 + fm;
        s16x8 bfr = *(const s16x8*)(lB + (r*8 + (qf ^ (r & 7))) * 8);
        acc[ni] = __builtin_amdgcn_mfma_f32_16x16x32_bf16(af, bfr, acc[ni], 0, 0, 0);
      }
    }
  }

  u16* Cb = g.C + (long long)z * g.c_z;
  const u16* biasp = g.bias ? g.bias + (long long)z * g.bias_z : (const u16*)0;
  #pragma unroll
  for (int ni=0; ni<16; ni++){
    int n = ni*16 + fm;
    float bb = 0.0f;
    if (g.cbias) bb = g.cbias[n];
    else if (biasp) bb = b2f(biasp[n]);
    #pragma unroll
    for (int r=0; r<4; r++){
      long long b = arow0 + w*16 + (lane>>4)*4 + r;
      float v = acc[ni][r] * g.scale + bb;
      if (g.addm) v += b2f(g.addm[b*256 + n]);
      if (g.relu) v = v > 0.0f ? v : 0.0f;
      Cb[b * (long long)g.ldc + n] = f2b(v);
    }
  }
}

// ---------- stage5b fused: ch in regs -> wc2 dot -> sigmoid -> scores only ----------
__global__ __launch_bounds__(256, 4) void gemm_score(GArgs g){
  alignas(16) __shared__ u16 lA[64*64];
  alignas(16) __shared__ u16 lB[256*64];
  const int tid  = threadIdx.x;
  const int lane = tid & 63;
  const int w    = tid >> 6;
  const int z    = blockIdx.z;

  const u16* Bbase = g.B;

  f32x4 acc[16];
  #pragma unroll
  for (int j=0;j<16;j++)
    #pragma unroll
    for (int r=0;r<4;r++) acc[j][r] = 0.0f;

  const int fm = lane & 15;
  const int fk = (lane >> 4) * 8;
  const long long arow0 = (long long)blockIdx.x * 64;

  const int sr = lane >> 3;
  const int sq = (lane & 7) ^ sr;

  for (int k0 = 0; k0 < g.K; k0 += 64){
    const u16* At = g.A + (long long)z * g.a_z + k0;
    const u16* Bt = Bbase + k0;
    __syncthreads();
    #pragma unroll
    for (int i=0;i<2;i++){
      int r = i*32 + w*8 + sr;
      async_cp16(At + (arow0 + r) * (long long)g.lda + sq*8, lA + (i*256 + w*64) * 8);
    }
    #pragma unroll
    for (int i=0;i<8;i++){
      int r = i*32 + w*8 + sr;
      async_cp16(Bt + (long long)r * g.ldb + sq*8, lB + (i*256 + w*64) * 8);
    }
    __syncthreads();
    #pragma unroll
    for (int kk = 0; kk < 64; kk += 32){
      const int qf = (kk + fk) >> 3;
      int ra = w*16 + fm;
      s16x8 af = *(const s16x8*)(lA + (ra*8 + (qf ^ (ra & 7))) * 8);
      #pragma unroll
      for (int ni=0; ni<16; ni++){
        int r = ni*16 + fm;
        s16x8 bfr = *(const s16x8*)(lB + (r*8 + (qf ^ (r & 7))) * 8);
        acc[ni] = __builtin_amdgcn_mfma_f32_16x16x32_bf16(af, bfr, acc[ni], 0, 0, 0);
      }
    }
  }

  // epilogue: ch = relu(acc + qctx + bc1); p[r] = sum_n ch*wc2[n]; score = sigmoid(p + bc2)
  float p[4] = {0.f, 0.f, 0.f, 0.f};
  #pragma unroll
  for (int ni=0; ni<16; ni++){
    int n = ni*16 + fm;
    float bb = b2f(g.bias[n]);
    float wcv = b2f(g.wc2[n]);
    #pragma unroll
    for (int r=0; r<4; r++){
      long long b = arow0 + w*16 + (lane>>4)*4 + r;
      float v = acc[ni][r] + bb + b2f(g.addm[b*256 + n]);
      v = v > 0.0f ? v : 0.0f;
      p[r] += v * wcv;
    }
  }
  // reduce across the 16 lanes of the quad (fm = low 4 bits)
  #pragma unroll
  for (int r=0; r<4; r++){
    #pragma unroll
    for (int off=1; off<16; off<<=1) p[r] += __shfl_xor(p[r], off);
  }
  if (fm == 0){
    float bc2f = g.cbias[0];
    #pragma unroll
    for (int r=0; r<4; r++){
      long long b = arow0 + w*16 + (lane>>4)*4 + r;
      g.scores[(long long)z*BB + b] = 1.0f / (1.0f + __expf(-(p[r] + bc2f)));
    }
  }
}

// WB[n=(s*256+o)][k=(t*256+d)] = sum_e Wo[s,t,o,e]*Wv[s,t,e,d], zeroed on s==t diagonal.
__global__ __launch_bounds__(256, 2) void build_wb(const float* Wo, const float* Wv, u16* WB){
  alignas(16) __shared__ u16 lA[128*64];
  alignas(16) __shared__ u16 lB[128*64];
  const int tid  = threadIdx.x;
  const int lane = tid & 63;
  const int w    = tid >> 6;
  const int z = blockIdx.z, s = z >> 3, t = z & 7;
  const long long zoff = (long long)z * 65536;

  f32x4 acc[4][4];
  #pragma unroll
  for (int i=0;i<4;i++)
    #pragma unroll
    for (int j=0;j<4;j++)
      #pragma unroll
      for (int r=0;r<4;r++) acc[i][j][r] = 0.0f;

  const int wr = (w >> 1) * 64, wc = (w & 1) * 64;
  const int fm = lane & 15;
  const int fk = (lane >> 4) * 8;

  int srow[4], sq[4];
  #pragma unroll
  for (int i=0;i<4;i++){
    int c = i*256 + tid;
    srow[i] = c >> 3;
    sq[i]   = (c & 7) ^ (srow[i] & 7);
  }

  for (int k0 = 0; k0 < 256; k0 += 64){
    s16x8 va[4], vt[4];
    #pragma unroll
    for (int i=0;i<4;i++){
      long long aidx = zoff + (long long)(blockIdx.x*128 + srow[i]) * 256 + k0 + sq[i]*8;
      va[i] = load8_f32(Wo, aidx);
    }
    #pragma unroll
    for (int j=0;j<4;j++){
      int id = j*256 + tid;
      int e  = id >> 4;
      int dc = (id & 15) * 8;
      long long bidx = zoff + (long long)(k0 + e) * 256 + blockIdx.y*128 + dc;
      vt[j] = load8_f32(Wv, bidx);
    }
    __syncthreads();
    #pragma unroll
    for (int i=0;i<4;i++){
      int c = i*256 + tid;
      *(s16x8*)(lA + c*8) = va[i];
    }
    #pragma unroll
    for (int j=0;j<4;j++){
      int id = j*256 + tid;
      int e  = id >> 4;
      int dc = (id & 15) * 8;
      #pragma unroll
      for (int u=0; u<8; u++){
        int d = dc + u;
        lB[(d*8 + ((e>>3) ^ (d & 7)))*8 + (e & 7)] = (u16)vt[j][u];
      }
    }
    __syncthreads();
    #pragma unroll
    for (int kk = 0; kk < 64; kk += 32){
      s16x8 af[4], bfr[4];
      const int qf = (kk + fk) >> 3;
      #pragma unroll
      for (int mi=0; mi<4; mi++){
        int r = wr + mi*16 + fm;
        af[mi] = *(const s16x8*)(lA + (r*8 + (qf ^ (r & 7))) * 8);
      }
      #pragma unroll
      for (int ni=0; ni<4; ni++){
        int r = wc + ni*16 + fm;
        bfr[ni] = *(const s16x8*)(lB + (r*8 + (qf ^ (r & 7))) * 8);
      }
      #pragma unroll
      for (int mi=0; mi<4; mi++)
        #pragma unroll
        for (int ni=0; ni<4; ni++)
          acc[mi][ni] = __builtin_amdgcn_mfma_f32_16x16x32_bf16(af[mi], bfr[ni], acc[mi][ni], 0, 0, 0);
    }
    __syncthreads();
  }
  const int diag = (s == t);
  #pragma unroll
  for (int mi=0; mi<4; mi++){
    #pragma unroll
    for (int ni=0; ni<4; ni++){
      int d = blockIdx.y*128 + wc + ni*16 + fm;
      #pragma unroll
      for (int r=0; r<4; r++){
        int o = blockIdx.x*128 + wr + mi*16 + (lane>>4)*4 + r;
        float v = diag ? 0.0f : acc[mi][ni][r];
        WB[(long long)(s*256 + o) * 2048 + t*256 + d] = f2b(v);
      }
    }
  }
}

// cb[s*256+o] += (1/7)*( dot(bv[s,t,:], Wo[s,t,o,:]) + bo[s,t,o] )  for t != s. cb zeroed first.
// grid (64 pairs, 4 o-chunks); wave-per-row, lane-per-float4: fully coalesced.
__global__ __launch_bounds__(256) void cb_kernel(const float* bv, const float* Wo, const float* bo, float* cb){
  int z = blockIdx.x, s = z >> 3, t = z & 7;
  if (s == t) return;
  int lane = threadIdx.x & 63, w = threadIdx.x >> 6;
  float4 bvv = *(const float4*)(bv + (long long)z*256 + lane*4);
  #pragma unroll
  for (int i=0; i<16; i++){
    int row = blockIdx.y*64 + w*16 + i;
    float4 wv4 = *(const float4*)(Wo + (long long)z*65536 + (long long)row*256 + lane*4);
    float p = wv4.x*bvv.x + wv4.y*bvv.y + wv4.z*bvv.z + wv4.w*bvv.w;
    #pragma unroll
    for (int off=32; off>0; off>>=1) p += __shfl_xor(p, off);
    if (lane == 0)
      atomicAdd(&cb[s*256 + row], (p + bo[(long long)z*256 + row]) * (1.0f/7.0f));
  }
}

// out[b,:] = (1/8) sum_m fused[m,b,:] * scores[m,b]
__global__ __launch_bounds__(256) void final_gate(const u16* fused, const float* scores, float* out){
  int b = blockIdx.x;
  int tid = threadIdx.x;
  float sc[8];
  #pragma unroll
  for (int m=0; m<8; m++) sc[m] = scores[(long long)m*BB + b];
  float acc = 0.0f;
  #pragma unroll
  for (int m=0; m<8; m++)
    acc += b2f(fused[((long long)m*BB + b)*256 + tid]) * sc[m];
  out[(long long)b*256 + tid] = acc * 0.125f;
}

extern "C" void kernel_launch(void* const* d_in, const int* in_sizes, int n_in,
                              void* d_out, int out_size, void* d_ws, size_t ws_size,
                              hipStream_t stream){
  const float* x   = (const float*)d_in[0];
  const float* q   = (const float*)d_in[1];
  const float* Wv  = (const float*)d_in[2];
  const float* bv  = (const float*)d_in[3];
  const float* Wo  = (const float*)d_in[4];
  const float* bo  = (const float*)d_in[5];
  const float* W1  = (const float*)d_in[6];
  const float* b1  = (const float*)d_in[7];
  const float* W2  = (const float*)d_in[8];
  const float* b2  = (const float*)d_in[9];
  const float* Wc1 = (const float*)d_in[10];
  const float* bc1 = (const float*)d_in[11];
  const float* wc2 = (const float*)d_in[12];
  const float* bc2 = (const float*)d_in[13];

  char* ws = (char*)d_ws;
  u16*   xb    = (u16*)(ws + 0LL);            // 32MB; dead after stage3 -> fused
  u16*   qb    = (u16*)(ws + 33554432LL);     // 4MB
  u16*   cross = (u16*)(ws + 37748736LL);     // 32MB
  u16*   hid   = (u16*)(ws + 71303168LL);     // 32MB
  u16*   WB    = (u16*)(ws + 104857600LL);    // 8MB; dead after stage2 -> qctx+scores
  u16*   W1b   = (u16*)(ws + 113246208LL);    // 2MB
  u16*   W2b   = (u16*)(ws + 115343360LL);    // 1MB
  u16*   Wc1b  = (u16*)(ws + 116391936LL);    // 256KB
  u16*   b1b   = (u16*)(ws + 116654080LL);    // 4KB
  u16*   b2b   = (u16*)(ws + 116658176LL);    // 4KB
  u16*   bc1b  = (u16*)(ws + 116662272LL);    // 512B
  u16*   wc2b  = (u16*)(ws + 116662784LL);    // 512B
  float* bc2f  = (float*)(ws + 116663296LL);  // 64B (fp32 copy via cbias path)
  float* cb    = (float*)(ws + 116663424LL);  // 8KB
  u16*   fused = xb;
  u16*   qctx  = WB;                                   // 4MB (dead WB)
  float* scores = (float*)(ws + 104857600LL + 4194304LL); // 256KB (dead WB upper half)

  ConvArgs ca{};
  ca.src[0]=x;   ca.dst[0]=xb;   ca.n[0]=MMOD*BB*DD;
  ca.src[1]=q;   ca.dst[1]=qb;   ca.n[1]=BB*DD;
  ca.src[2]=W1;  ca.dst[2]=W1b;  ca.n[2]=MMOD*DD*2*DD;
  ca.src[3]=W2;  ca.dst[3]=W2b;  ca.n[3]=MMOD*DD*DD;
  ca.src[4]=Wc1; ca.dst[4]=Wc1b; ca.n[4]=DD*2*DD;
  ca.src[5]=b1;  ca.dst[5]=b1b;  ca.n[5]=MMOD*DD;
  ca.src[6]=b2;  ca.dst[6]=b2b;  ca.n[6]=MMOD*DD;
  ca.src[7]=bc1; ca.dst[7]=bc1b; ca.n[7]=DD;
  ca.src[8]=wc2; ca.dst[8]=wc2b; ca.n[8]=DD;
  ca.src[9]=bc2; ca.dst[9]=bc1b; ca.n[9]=0;   // unused slot (bc2 handled below)
  convert_kernel<<<1024, 256, 0, stream>>>(ca);
  hipMemcpyAsync(bc2f, bc2, sizeof(float), hipMemcpyDeviceToDevice, stream);

  hipMemsetAsync(cb, 0, 2048*sizeof(float), stream);
  build_wb<<<dim3(2,2,64), 256, 0, stream>>>(Wo, Wv, WB);
  cb_kernel<<<dim3(64,4), 256, 0, stream>>>(bv, Wo, bo, cb);

  const long long BD = (long long)BB * DD;

  // Stage 2 (256^2 8-phase): cross[s,b,o] = (1/7) sum_k xb'[b,k] * WB[(s,o),k] + cb
  GArgs g2{};
  g2.A = xb; g2.a_z = 0; g2.a_piece = BD; g2.lda = 256; g2.A2 = 0; g2.a2_z = 0;
  g2.B = WB; g2.b_z = 0; g2.ldb = 2048;
  g2.C = cross; g2.c_z = 0; g2.c_npiece = BD; g2.ldc = 256;
  g2.bias = 0; g2.bias_z = 0; g2.cbias = cb; g2.addm = 0; g2.wc2 = 0; g2.scores = 0;
  g2.scale = 1.0f/7.0f; g2.K = 2048; g2.relu = 0;
  gemm_8ph<<<dim3(32,8,1), 512, 0, stream>>>(g2);

  // Stage 5a (thin): qctx = qb @ Wc1[:, :256]^T   (into dead WB)
  GArgs g5a{};
  g5a.A = qb; g5a.a_z = 0; g5a.a_piece = 0; g5a.lda = 256; g5a.A2 = 0; g5a.a2_z = 0;
  g5a.B = Wc1b; g5a.b_z = 0; g5a.ldb = 512;
  g5a.C = qctx; g5a.c_z = 0; g5a.c_npiece = 0; g5a.ldc = 256;
  g5a.bias = 0; g5a.bias_z = 0; g5a.cbias = 0; g5a.addm = 0; g5a.wc2 = 0; g5a.scores = 0;
  g5a.scale = 1.0f; g5a.K = 256; g5a.relu = 0;
  gemm_thin<<<dim3(128,1,1), 256, 0, stream>>>(g5a);

  // Stage 3 (thin): hid[m] = relu([xb[m] | cross[m]] @ W1[m]^T + b1[m])
  GArgs g3{};
  g3.A = xb; g3.a_z = BD; g3.a_piece = 0; g3.lda = 256; g3.A2 = cross; g3.a2_z = BD;
  g3.B = W1b; g3.b_z = (long long)DD*2*DD; g3.ldb = 512;
  g3.C = hid; g3.c_z = BD; g3.c_npiece = 0; g3.ldc = 256;
  g3.bias = b1b; g3.bias_z = 256; g3.cbias = 0; g3.addm = 0; g3.wc2 = 0; g3.scores = 0;
  g3.scale = 1.0f; g3.K = 512; g3.relu = 1;
  gemm_thin<<<dim3(128,1,8), 256, 0, stream>>>(g3);

  // Stage 4 (thin): fused[m] = hid[m] @ W2[m]^T + b2[m]   (overwrites dead xb)
  GArgs g4{};
  g4.A = hid; g4.a_z = BD; g4.a_piece = 0; g4.lda = 256; g4.A2 = 0; g4.a2_z = 0;
  g4.B = W2b; g4.b_z = (long long)DD*DD; g4.ldb = 256;
  g4.C = fused; g4.c_z = BD; g4.c_npiece = 0; g4.ldc = 256;
  g4.bias = b2b; g4.bias_z = 256; g4.cbias = 0; g4.addm = 0; g4.wc2 = 0; g4.scores = 0;
  g4.scale = 1.0f; g4.K = 256; g4.relu = 0;
  gemm_thin<<<dim3(128,1,8), 256, 0, stream>>>(g4);

  // Stage 5b (score): scores[m,b] = sigmoid(wc2 . relu(fused[m] @ Wc1[:,256:]^T + qctx + bc1) + bc2)
  GArgs g5b{};
  g5b.A = fused; g5b.a_z = BD; g5b.a_piece = 0; g5b.lda = 256; g5b.A2 = 0; g5b.a2_z = 0;
  g5b.B = Wc1b + 256; g5b.b_z = 0; g5b.ldb = 512;
  g5b.C = 0; g5b.c_z = 0; g5b.c_npiece = 0; g5b.ldc = 0;
  g5b.bias = bc1b; g5b.bias_z = 0; g5b.cbias = bc2f; g5b.addm = qctx;
  g5b.wc2 = wc2b; g5b.scores = scores;
  g5b.scale = 1.0f; g5b.K = 256; g5b.relu = 1;
  gemm_score<<<dim3(128,1,8), 256, 0, stream>>>(g5b);

  final_gate<<<dim3(BB), 256, 0, stream>>>(fused, scores, (float*)d_out);

  (void)in_sizes; (void)n_in; (void)out_size; (void)ws_size;
}

// Round 2
// 354.325 us; speedup vs baseline: 1.0290x; 1.0290x over previous
//
#include <hip/hip_runtime.h>

#define MMOD 8
#define BB 8192
#define DD 256

typedef unsigned short u16;
typedef __attribute__((ext_vector_type(8))) short s16x8;
typedef __attribute__((ext_vector_type(4))) float f32x4;
typedef __attribute__((ext_vector_type(8))) unsigned short u16x8;

typedef __attribute__((address_space(3))) unsigned short lds_u16;
typedef __attribute__((address_space(1))) const unsigned short gl_u16;

__device__ __forceinline__ float b2f(u16 u){ union{unsigned i; float f;} x; x.i=((unsigned)u)<<16; return x.f; }
__device__ __forceinline__ u16 f2b(float f){ union{float f; unsigned i;} x; x.f=f; unsigned r = x.i + 0x7FFF + ((x.i>>16)&1u); return (u16)(r>>16); }

// async global->LDS: per-lane src address, LDS dest = wave-uniform base + lane*16B
__device__ __forceinline__ void async_cp16(const u16* g, u16* l){
  __builtin_amdgcn_global_load_lds((gl_u16*)g, (lds_u16*)l, 16, 0, 0);
}

// ---------------- fp32 -> bf16 conversion ----------------
struct ConvArgs {
  const float* src[10];
  u16*         dst[10];
  int          n[10];
};
__global__ void convert_kernel(ConvArgs a){
  const long long stride = (long long)gridDim.x * blockDim.x;
  const long long base   = (long long)blockIdx.x * blockDim.x + threadIdx.x;
  for (int s = 0; s < 10; s++){
    const int n  = a.n[s];
    const int n8 = n >> 3;
    const float* sp = a.src[s];
    u16* dst = a.dst[s];
    for (long long i = base; i < n8; i += stride){
      float4 lo = ((const float4*)sp)[i*2];
      float4 hi = ((const float4*)sp)[i*2+1];
      u16x8 p;
      p[0]=f2b(lo.x); p[1]=f2b(lo.y); p[2]=f2b(lo.z); p[3]=f2b(lo.w);
      p[4]=f2b(hi.x); p[5]=f2b(hi.y); p[6]=f2b(hi.z); p[7]=f2b(hi.w);
      *(u16x8*)(dst + (i<<3)) = p;
    }
    for (long long i = ((long long)n8<<3) + base; i < n; i += stride)
      dst[i] = f2b(sp[i]);
  }
}

__device__ __forceinline__ s16x8 load8_f32(const float* p, long long idx){
  float4 lo = *(const float4*)(p + idx);
  float4 hi = *(const float4*)(p + idx + 4);
  s16x8 r;
  r[0]=(short)f2b(lo.x); r[1]=(short)f2b(lo.y); r[2]=(short)f2b(lo.z); r[3]=(short)f2b(lo.w);
  r[4]=(short)f2b(hi.x); r[5]=(short)f2b(hi.y); r[6]=(short)f2b(hi.z); r[7]=(short)f2b(hi.w);
  return r;
}

struct GArgs {
  const u16* A;  long long a_z; long long a_piece; int lda;  // A + z*a_z + (k>>8)*a_piece + b*lda + (k&255)
  const u16* A2; long long a2_z;                             // if non-null: base for k>=256
  const u16* B;  long long b_z; int ldb;                     // B + z*b_z + n*ldb + k   ([N,K] layout)
  u16*       C;  long long c_z; long long c_npiece; int ldc; // C + z*c_z + (n>>8)*c_npiece + b*ldc + (n&255)
  const u16* bias; long long bias_z;   // bf16 bias[n] (per z), optional
  const float* cbias;                  // fp32 bias[global n], optional
  const u16* addm;                     // bf16 addend [b,256] (shared across z), optional
  const u16* wc2;                      // score kernel: bf16 [256]
  float*     scores;                   // score kernel: [z*8192 + b]
  float scale;
  int K;
  int relu;
};

// ---------- 256x256 4-phase/K-tile pipelined GEMM (stage 2) ----------
// BM=BN=256, BK=64, 8 waves (2M x 4N), 512 threads, 128KB LDS double-buffered.
// VALU-free inner loop: t-loop unrolled x2 (c literal), all ds_read addresses are
// precomputed per-lane bases + compile-time immediate offsets.
// A-frag reads pipelined one phase ahead (af[2] slots) -> LDS drain hides under MFMA.
// One raw s_barrier per phase; vmcnt(4) once per K-tile (never 0 in steady state).
// Staging ring: phase0/1 stage A(t+1)->buf c^1; phase2/3 stage B(t+2)->buf c.
__global__ __launch_bounds__(512, 2) void gemm_8ph(GArgs g){
  alignas(16) __shared__ char L[131072]; // [buf(2)] x [A 32KB | B 32KB], row=128B swizzled
  const int tid  = threadIdx.x;
  const int lane = tid & 63;
  const int w    = tid >> 6;        // 0..7

  const int wr  = w >> 2;           // 0..1 : 128-row block
  const int wcn = w & 3;            // 0..3 : 64-col block
  const int fm  = lane & 15;
  const int fq  = lane >> 4;        // 0..3

  const long long arow0 = (long long)blockIdx.x * 256;
  const long long nrow0 = (long long)blockIdx.y * 256;

  // ---- read-address precompute (bytes). frag(R,qf): SEC + R*128 + ((qf^(R&7))*16),
  // R = U + fm (U mult of 16) -> lane part: fm*128 + ((qf^(fm&7))*16), qf = kk*4+fq.
  const int lp0 = fm*128 + (((0*4+fq) ^ (fm&7))*16);
  const int lp1 = fm*128 + (((1*4+fq) ^ (fm&7))*16);
  const int vA00 =          wr*16384 + lp0;   // buf0, kk0
  const int vA01 =          wr*16384 + lp1;   // buf0, kk1
  const int vA10 = 65536 +  wr*16384 + lp0;   // buf1, kk0
  const int vA11 = 65536 +  wr*16384 + lp1;
  const int vB00 =          32768 + wcn*8192 + lp0;
  const int vB01 =          32768 + wcn*8192 + lp1;
  const int vB10 = 65536 +  32768 + wcn*8192 + lp0;
  const int vB11 = 65536 +  32768 + wcn*8192 + lp1;

  // ---- staging geometry: 512 threads x 16B = 64 rows/instr; 2 instrs per 128-row half.
  const int r0  = tid >> 3;          // 0..63
  const int r1  = r0 + 64;
  const int cs  = tid & 7;
  const int gc0 = cs ^ (r0 & 7);     // pre-swizzled global column chunk
  const int gc1 = cs ^ (r1 & 7);
  const int laA0 = r0*256  + gc0*8;  // u16 units (lda=256)
  const int laA1 = r1*256  + gc1*8;
  const int laB0 = r0*2048 + gc0*8;  // u16 units (ldb=2048)
  const int laB1 = r1*2048 + gc1*8;

  const u16* Az = g.A;
  const u16* Bz = g.B;

#define STAGE_A(c, k0s, h) do{ \
    const u16* s_ = Az + (long long)((k0s) >> 8) * g.a_piece + ((k0s) & 255) + (arow0 + (h)*128) * 256; \
    char* d_ = L + (c)*65536 + (h)*16384 + w*1024; \
    async_cp16(s_ + laA0, (u16*)d_); \
    async_cp16(s_ + laA1, (u16*)(d_ + 8192)); \
  }while(0)
#define STAGE_B(c, k0s, h) do{ \
    const u16* s_ = Bz + (k0s) + (nrow0 + (h)*128) * 2048; \
    char* d_ = L + (c)*65536 + 32768 + (h)*16384 + w*1024; \
    async_cp16(s_ + laB0, (u16*)d_); \
    async_cp16(s_ + laB1, (u16*)(d_ + 8192)); \
  }while(0)

  s16x8 af[2][2][2]; // [slot][j][kk]
  s16x8 bf[4][2];    // [ni][kk], held across the whole K-tile

#define RD_A(vb0, vb1, slot, qq) do{ \
    af[slot][0][0] = *(const s16x8*)(L + (vb0) + ((qq)*2+0)*2048); \
    af[slot][0][1] = *(const s16x8*)(L + (vb1) + ((qq)*2+0)*2048); \
    af[slot][1][0] = *(const s16x8*)(L + (vb0) + ((qq)*2+1)*2048); \
    af[slot][1][1] = *(const s16x8*)(L + (vb1) + ((qq)*2+1)*2048); \
  }while(0)
#define RD_B(vb0, vb1) do{ \
    bf[0][0] = *(const s16x8*)(L + (vb0) + 0*2048); \
    bf[0][1] = *(const s16x8*)(L + (vb1) + 0*2048); \
    bf[1][0] = *(const s16x8*)(L + (vb0) + 1*2048); \
    bf[1][1] = *(const s16x8*)(L + (vb1) + 1*2048); \
    bf[2][0] = *(const s16x8*)(L + (vb0) + 2*2048); \
    bf[2][1] = *(const s16x8*)(L + (vb1) + 2*2048); \
    bf[3][0] = *(const s16x8*)(L + (vb0) + 3*2048); \
    bf[3][1] = *(const s16x8*)(L + (vb1) + 3*2048); \
  }while(0)

#define MFMA_Q(qq, slot) do{ \
    __builtin_amdgcn_s_setprio(1); \
    _Pragma("unroll") \
    for (int kk = 0; kk < 2; kk++) \
      _Pragma("unroll") \
      for (int j = 0; j < 2; j++) \
        _Pragma("unroll") \
        for (int ni = 0; ni < 4; ni++) \
          acc[(qq)*2+j][ni] = __builtin_amdgcn_mfma_f32_16x16x32_bf16(af[slot][j][kk], bf[ni][kk], acc[(qq)*2+j][ni], 0, 0, 0); \
    __builtin_amdgcn_s_setprio(0); \
  }while(0)

  f32x4 acc[8][4];
  #pragma unroll
  for (int i=0;i<8;i++)
    #pragma unroll
    for (int j=0;j<4;j++)
      #pragma unroll
      for (int r=0;r<4;r++) acc[i][j][r] = 0.0f;

  const int T = g.K >> 6;

  // prologue: A(0),B(0) -> buf0; B(1) -> buf1. Wait A(0)+B(0) (leave B(1)'s 4 in flight).
  STAGE_A(0, 0, 0);  STAGE_A(0, 0, 1);
  STAGE_B(0, 0, 0);  STAGE_B(0, 0, 1);
  STAGE_B(1, 64, 0); STAGE_B(1, 64, 1);
  asm volatile("s_waitcnt vmcnt(4)" ::: "memory");
  __builtin_amdgcn_s_barrier();

#define TILE(c, vAk0, vAk1, vBk0, vBk1, t) do{ \
    const int kt = (t) << 6; \
    const int more1 = (t) + 1 < T; \
    const int more2 = (t) + 2 < T; \
    /* phase 0: stage A(t+1).h0 -> c^1; read B(8) + A slot0(q0) + prefetch A slot1(q1) */ \
    if (more1) STAGE_A((c)^1, kt+64, 0); \
    RD_B(vBk0, vBk1); \
    RD_A(vAk0, vAk1, 0, 0); \
    RD_A(vAk0, vAk1, 1, 1); \
    MFMA_Q(0, 0); \
    __builtin_amdgcn_s_barrier(); \
    /* phase 1: stage A(t+1).h1; prefetch A slot0(q2) */ \
    if (more1) STAGE_A((c)^1, kt+64, 1); \
    RD_A(vAk0, vAk1, 0, 2); \
    MFMA_Q(1, 1); \
    __builtin_amdgcn_s_barrier(); \
    /* phase 2: stage B(t+2).h0 -> c (B slots free: all waves past q0 barrier) */ \
    if (more2) STAGE_B((c), kt+128, 0); \
    RD_A(vAk0, vAk1, 1, 3); \
    MFMA_Q(2, 0); \
    __builtin_amdgcn_s_barrier(); \
    /* phase 3: stage B(t+2).h1; counted vmcnt -> A(t+1),B(t+1) landed, B(t+2) in flight */ \
    if (more2) STAGE_B((c), kt+128, 1); \
    MFMA_Q(3, 1); \
    if (more2)      asm volatile("s_waitcnt vmcnt(4)" ::: "memory"); \
    else if (more1) asm volatile("s_waitcnt vmcnt(0)" ::: "memory"); \
    __builtin_amdgcn_s_barrier(); \
  }while(0)

  for (int t = 0; t < T; t += 2){
    TILE(0, vA00, vA01, vB00, vB01, t);
    TILE(1, vA10, vA11, vB10, vB11, t+1);
  }

  u16* Cb = g.C + 0;
  const u16* biasp = g.bias;
  #pragma unroll
  for (int mi = 0; mi < 8; mi++){
    #pragma unroll
    for (int ni = 0; ni < 4; ni++){
      const int n = (int)nrow0 + wcn * 64 + ni * 16 + fm;
      float bb = 0.0f;
      if (g.cbias) bb = g.cbias[n];
      else if (biasp) bb = b2f(biasp[n]);
      const long long cn = ((long long)(n >> 8)) * g.c_npiece + (n & 255);
      #pragma unroll
      for (int r = 0; r < 4; r++){
        const long long b = arow0 + wr * 128 + mi * 16 + fq * 4 + r;
        float v = acc[mi][ni][r] * g.scale + bb;
        if (g.relu) v = v > 0.0f ? v : 0.0f;
        Cb[cn + b * (long long)g.ldc] = f2b(v);
      }
    }
  }
#undef STAGE_A
#undef STAGE_B
#undef RD_A
#undef RD_B
#undef MFMA_Q
#undef TILE
}

// ---------- thin full-N tile: 64 rows x 256 cols, BK=64 ----------
// wave w owns rows [w*16, w*16+16), all 256 n-cols (16 n-tiles). LDS 40KB -> 4 blocks/CU.
__global__ __launch_bounds__(256, 4) void gemm_thin(GArgs g){
  alignas(16) __shared__ u16 lA[64*64];
  alignas(16) __shared__ u16 lB[256*64];
  const int tid  = threadIdx.x;
  const int lane = tid & 63;
  const int w    = tid >> 6;
  const int z    = blockIdx.z;

  const u16* Bbase = g.B + (long long)z * g.b_z;

  f32x4 acc[16];
  #pragma unroll
  for (int j=0;j<16;j++)
    #pragma unroll
    for (int r=0;r<4;r++) acc[j][r] = 0.0f;

  const int fm = lane & 15;
  const int fk = (lane >> 4) * 8;
  const long long arow0 = (long long)blockIdx.x * 64;

  const int sr = lane >> 3;
  const int sq = (lane & 7) ^ sr;

  for (int k0 = 0; k0 < g.K; k0 += 64){
    const u16* Abase0 = (g.A2 && k0 >= 256) ? (g.A2 + (long long)z * g.a2_z)
                                            : (g.A  + (long long)z * g.a_z);
    const u16* At = Abase0 + (long long)(k0 >> 8) * g.a_piece + (k0 & 255);
    const u16* Bt = Bbase + k0;
    __syncthreads();
    #pragma unroll
    for (int i=0;i<2;i++){
      int r = i*32 + w*8 + sr;
      async_cp16(At + (arow0 + r) * (long long)g.lda + sq*8, lA + (i*256 + w*64) * 8);
    }
    #pragma unroll
    for (int i=0;i<8;i++){
      int r = i*32 + w*8 + sr;
      async_cp16(Bt + (long long)r * g.ldb + sq*8, lB + (i*256 + w*64) * 8);
    }
    __syncthreads();
    #pragma unroll
    for (int kk = 0; kk < 64; kk += 32){
      const int qf = (kk + fk) >> 3;
      int ra = w*16 + fm;
      s16x8 af = *(const s16x8*)(lA + (ra*8 + (qf ^ (ra & 7))) * 8);
      #pragma unroll
      for (int ni=0; ni<16; ni++){
        int r = ni*16 + fm;
        s16x8 bfr = *(const s16x8*)(lB + (r*8 + (qf ^ (r & 7))) * 8);
        acc[ni] = __builtin_amdgcn_mfma_f32_16x16x32_bf16(af, bfr, acc[ni], 0, 0, 0);
      }
    }
  }

  u16* Cb = g.C + (long long)z * g.c_z;
  const u16* biasp = g.bias ? g.bias + (long long)z * g.bias_z : (const u16*)0;
  #pragma unroll
  for (int ni=0; ni<16; ni++){
    int n = ni*16 + fm;
    float bb = 0.0f;
    if (g.cbias) bb = g.cbias[n];
    else if (biasp) bb = b2f(biasp[n]);
    #pragma unroll
    for (int r=0; r<4; r++){
      long long b = arow0 + w*16 + (lane>>4)*4 + r;
      float v = acc[ni][r] * g.scale + bb;
      if (g.addm) v += b2f(g.addm[b*256 + n]);
      if (g.relu) v = v > 0.0f ? v : 0.0f;
      Cb[b * (long long)g.ldc + n] = f2b(v);
    }
  }
}

// ---------- stage5b fused: ch in regs -> wc2 dot -> sigmoid -> scores only ----------
__global__ __launch_bounds__(256, 4) void gemm_score(GArgs g){
  alignas(16) __shared__ u16 lA[64*64];
  alignas(16) __shared__ u16 lB[256*64];
  const int tid  = threadIdx.x;
  const int lane = tid & 63;
  const int w    = tid >> 6;
  const int z    = blockIdx.z;

  const u16* Bbase = g.B;

  f32x4 acc[16];
  #pragma unroll
  for (int j=0;j<16;j++)
    #pragma unroll
    for (int r=0;r<4;r++) acc[j][r] = 0.0f;

  const int fm = lane & 15;
  const int fk = (lane >> 4) * 8;
  const long long arow0 = (long long)blockIdx.x * 64;

  const int sr = lane >> 3;
  const int sq = (lane & 7) ^ sr;

  for (int k0 = 0; k0 < g.K; k0 += 64){
    const u16* At = g.A + (long long)z * g.a_z + k0;
    const u16* Bt = Bbase + k0;
    __syncthreads();
    #pragma unroll
    for (int i=0;i<2;i++){
      int r = i*32 + w*8 + sr;
      async_cp16(At + (arow0 + r) * (long long)g.lda + sq*8, lA + (i*256 + w*64) * 8);
    }
    #pragma unroll
    for (int i=0;i<8;i++){
      int r = i*32 + w*8 + sr;
      async_cp16(Bt + (long long)r * g.ldb + sq*8, lB + (i*256 + w*64) * 8);
    }
    __syncthreads();
    #pragma unroll
    for (int kk = 0; kk < 64; kk += 32){
      const int qf = (kk + fk) >> 3;
      int ra = w*16 + fm;
      s16x8 af = *(const s16x8*)(lA + (ra*8 + (qf ^ (ra & 7))) * 8);
      #pragma unroll
      for (int ni=0; ni<16; ni++){
        int r = ni*16 + fm;
        s16x8 bfr = *(const s16x8*)(lB + (r*8 + (qf ^ (r & 7))) * 8);
        acc[ni] = __builtin_amdgcn_mfma_f32_16x16x32_bf16(af, bfr, acc[ni], 0, 0, 0);
      }
    }
  }

  // epilogue: ch = relu(acc + qctx + bc1); p[r] = sum_n ch*wc2[n]; score = sigmoid(p + bc2)
  float p[4] = {0.f, 0.f, 0.f, 0.f};
  #pragma unroll
  for (int ni=0; ni<16; ni++){
    int n = ni*16 + fm;
    float bb = b2f(g.bias[n]);
    float wcv = b2f(g.wc2[n]);
    #pragma unroll
    for (int r=0; r<4; r++){
      long long b = arow0 + w*16 + (lane>>4)*4 + r;
      float v = acc[ni][r] + bb + b2f(g.addm[b*256 + n]);
      v = v > 0.0f ? v : 0.0f;
      p[r] += v * wcv;
    }
  }
  // reduce across the 16 lanes of the quad (fm = low 4 bits)
  #pragma unroll
  for (int r=0; r<4; r++){
    #pragma unroll
    for (int off=1; off<16; off<<=1) p[r] += __shfl_xor(p[r], off);
  }
  if (fm == 0){
    float bc2f = g.cbias[0];
    #pragma unroll
    for (int r=0; r<4; r++){
      long long b = arow0 + w*16 + (lane>>4)*4 + r;
      g.scores[(long long)z*BB + b] = 1.0f / (1.0f + __expf(-(p[r] + bc2f)));
    }
  }
}

// WB[n=(s*256+o)][k=(t*256+d)] = sum_e Wo[s,t,o,e]*Wv[s,t,e,d], zeroed on s==t diagonal.
__global__ __launch_bounds__(256, 2) void build_wb(const float* Wo, const float* Wv, u16* WB){
  alignas(16) __shared__ u16 lA[128*64];
  alignas(16) __shared__ u16 lB[128*64];
  const int tid  = threadIdx.x;
  const int lane = tid & 63;
  const int w    = tid >> 6;
  const int z = blockIdx.z, s = z >> 3, t = z & 7;
  const long long zoff = (long long)z * 65536;

  f32x4 acc[4][4];
  #pragma unroll
  for (int i=0;i<4;i++)
    #pragma unroll
    for (int j=0;j<4;j++)
      #pragma unroll
      for (int r=0;r<4;r++) acc[i][j][r] = 0.0f;

  const int wr = (w >> 1) * 64, wc = (w & 1) * 64;
  const int fm = lane & 15;
  const int fk = (lane >> 4) * 8;

  int srow[4], sq[4];
  #pragma unroll
  for (int i=0;i<4;i++){
    int c = i*256 + tid;
    srow[i] = c >> 3;
    sq[i]   = (c & 7) ^ (srow[i] & 7);
  }

  for (int k0 = 0; k0 < 256; k0 += 64){
    s16x8 va[4], vt[4];
    #pragma unroll
    for (int i=0;i<4;i++){
      long long aidx = zoff + (long long)(blockIdx.x*128 + srow[i]) * 256 + k0 + sq[i]*8;
      va[i] = load8_f32(Wo, aidx);
    }
    #pragma unroll
    for (int j=0;j<4;j++){
      int id = j*256 + tid;
      int e  = id >> 4;
      int dc = (id & 15) * 8;
      long long bidx = zoff + (long long)(k0 + e) * 256 + blockIdx.y*128 + dc;
      vt[j] = load8_f32(Wv, bidx);
    }
    __syncthreads();
    #pragma unroll
    for (int i=0;i<4;i++){
      int c = i*256 + tid;
      *(s16x8*)(lA + c*8) = va[i];
    }
    #pragma unroll
    for (int j=0;j<4;j++){
      int id = j*256 + tid;
      int e  = id >> 4;
      int dc = (id & 15) * 8;
      #pragma unroll
      for (int u=0; u<8; u++){
        int d = dc + u;
        lB[(d*8 + ((e>>3) ^ (d & 7)))*8 + (e & 7)] = (u16)vt[j][u];
      }
    }
    __syncthreads();
    #pragma unroll
    for (int kk = 0; kk < 64; kk += 32){
      s16x8 af[4], bfr[4];
      const int qf = (kk + fk) >> 3;
      #pragma unroll
      for (int mi=0; mi<4; mi++){
        int r = wr + mi*16 + fm;
        af[mi] = *(const s16x8*)(lA + (r*8 + (qf ^ (r & 7))) * 8);
      }
      #pragma unroll
      for (int ni=0; ni<4; ni++){
        int r = wc + ni*16 + fm;
        bfr[ni] = *(const s16x8*)(lB + (r*8 + (qf ^ (r & 7))) * 8);
      }
      #pragma unroll
      for (int mi=0; mi<4; mi++)
        #pragma unroll
        for (int ni=0; ni<4; ni++)
          acc[mi][ni] = __builtin_amdgcn_mfma_f32_16x16x32_bf16(af[mi], bfr[ni], acc[mi][ni], 0, 0, 0);
    }
    __syncthreads();
  }
  const int diag = (s == t);
  #pragma unroll
  for (int mi=0; mi<4; mi++){
    #pragma unroll
    for (int ni=0; ni<4; ni++){
      int d = blockIdx.y*128 + wc + ni*16 + fm;
      #pragma unroll
      for (int r=0; r<4; r++){
        int o = blockIdx.x*128 + wr + mi*16 + (lane>>4)*4 + r;
        float v = diag ? 0.0f : acc[mi][ni][r];
        WB[(long long)(s*256 + o) * 2048 + t*256 + d] = f2b(v);
      }
    }
  }
}

// cb[s*256+o] += (1/7)*( dot(bv[s,t,:], Wo[s,t,o,:]) + bo[s,t,o] )  for t != s. cb zeroed first.
__global__ __launch_bounds__(256) void cb_kernel(const float* bv, const float* Wo, const float* bo, float* cb){
  int z = blockIdx.x, s = z >> 3, t = z & 7;
  if (s == t) return;
  int lane = threadIdx.x & 63, w = threadIdx.x >> 6;
  float4 bvv = *(const float4*)(bv + (long long)z*256 + lane*4);
  #pragma unroll
  for (int i=0; i<16; i++){
    int row = blockIdx.y*64 + w*16 + i;
    float4 wv4 = *(const float4*)(Wo + (long long)z*65536 + (long long)row*256 + lane*4);
    float p = wv4.x*bvv.x + wv4.y*bvv.y + wv4.z*bvv.z + wv4.w*bvv.w;
    #pragma unroll
    for (int off=32; off>0; off>>=1) p += __shfl_xor(p, off);
    if (lane == 0)
      atomicAdd(&cb[s*256 + row], (p + bo[(long long)z*256 + row]) * (1.0f/7.0f));
  }
}

// out[b,:] = (1/8) sum_m fused[m,b,:] * scores[m,b]
__global__ __launch_bounds__(256) void final_gate(const u16* fused, const float* scores, float* out){
  int b = blockIdx.x;
  int tid = threadIdx.x;
  float sc[8];
  #pragma unroll
  for (int m=0; m<8; m++) sc[m] = scores[(long long)m*BB + b];
  float acc = 0.0f;
  #pragma unroll
  for (int m=0; m<8; m++)
    acc += b2f(fused[((long long)m*BB + b)*256 + tid]) * sc[m];
  out[(long long)b*256 + tid] = acc * 0.125f;
}

extern "C" void kernel_launch(void* const* d_in, const int* in_sizes, int n_in,
                              void* d_out, int out_size, void* d_ws, size_t ws_size,
                              hipStream_t stream){
  const float* x   = (const float*)d_in[0];
  const float* q   = (const float*)d_in[1];
  const float* Wv  = (const float*)d_in[2];
  const float* bv  = (const float*)d_in[3];
  const float* Wo  = (const float*)d_in[4];
  const float* bo  = (const float*)d_in[5];
  const float* W1  = (const float*)d_in[6];
  const float* b1  = (const float*)d_in[7];
  const float* W2  = (const float*)d_in[8];
  const float* b2  = (const float*)d_in[9];
  const float* Wc1 = (const float*)d_in[10];
  const float* bc1 = (const float*)d_in[11];
  const float* wc2 = (const float*)d_in[12];
  const float* bc2 = (const float*)d_in[13];

  char* ws = (char*)d_ws;
  u16*   xb    = (u16*)(ws + 0LL);            // 32MB; dead after stage3 -> fused
  u16*   qb    = (u16*)(ws + 33554432LL);     // 4MB
  u16*   cross = (u16*)(ws + 37748736LL);     // 32MB
  u16*   hid   = (u16*)(ws + 71303168LL);     // 32MB
  u16*   WB    = (u16*)(ws + 104857600LL);    // 8MB; dead after stage2 -> qctx+scores
  u16*   W1b   = (u16*)(ws + 113246208LL);    // 2MB
  u16*   W2b   = (u16*)(ws + 115343360LL);    // 1MB
  u16*   Wc1b  = (u16*)(ws + 116391936LL);    // 256KB
  u16*   b1b   = (u16*)(ws + 116654080LL);    // 4KB
  u16*   b2b   = (u16*)(ws + 116658176LL);    // 4KB
  u16*   bc1b  = (u16*)(ws + 116662272LL);    // 512B
  u16*   wc2b  = (u16*)(ws + 116662784LL);    // 512B
  float* bc2f  = (float*)(ws + 116663296LL);  // 64B (fp32 copy via cbias path)
  float* cb    = (float*)(ws + 116663424LL);  // 8KB
  u16*   fused = xb;
  u16*   qctx  = WB;                                   // 4MB (dead WB)
  float* scores = (float*)(ws + 104857600LL + 4194304LL); // 256KB (dead WB upper half)

  ConvArgs ca{};
  ca.src[0]=x;   ca.dst[0]=xb;   ca.n[0]=MMOD*BB*DD;
  ca.src[1]=q;   ca.dst[1]=qb;   ca.n[1]=BB*DD;
  ca.src[2]=W1;  ca.dst[2]=W1b;  ca.n[2]=MMOD*DD*2*DD;
  ca.src[3]=W2;  ca.dst[3]=W2b;  ca.n[3]=MMOD*DD*DD;
  ca.src[4]=Wc1; ca.dst[4]=Wc1b; ca.n[4]=DD*2*DD;
  ca.src[5]=b1;  ca.dst[5]=b1b;  ca.n[5]=MMOD*DD;
  ca.src[6]=b2;  ca.dst[6]=b2b;  ca.n[6]=MMOD*DD;
  ca.src[7]=bc1; ca.dst[7]=bc1b; ca.n[7]=DD;
  ca.src[8]=wc2; ca.dst[8]=wc2b; ca.n[8]=DD;
  ca.src[9]=bc2; ca.dst[9]=bc1b; ca.n[9]=0;   // unused slot (bc2 handled below)
  convert_kernel<<<1024, 256, 0, stream>>>(ca);
  hipMemcpyAsync(bc2f, bc2, sizeof(float), hipMemcpyDeviceToDevice, stream);

  hipMemsetAsync(cb, 0, 2048*sizeof(float), stream);
  build_wb<<<dim3(2,2,64), 256, 0, stream>>>(Wo, Wv, WB);
  cb_kernel<<<dim3(64,4), 256, 0, stream>>>(bv, Wo, bo, cb);

  const long long BD = (long long)BB * DD;

  // Stage 2 (256^2 pipelined): cross[s,b,o] = (1/7) sum_k xb'[b,k] * WB[(s,o),k] + cb
  GArgs g2{};
  g2.A = xb; g2.a_z = 0; g2.a_piece = BD; g2.lda = 256; g2.A2 = 0; g2.a2_z = 0;
  g2.B = WB; g2.b_z = 0; g2.ldb = 2048;
  g2.C = cross; g2.c_z = 0; g2.c_npiece = BD; g2.ldc = 256;
  g2.bias = 0; g2.bias_z = 0; g2.cbias = cb; g2.addm = 0; g2.wc2 = 0; g2.scores = 0;
  g2.scale = 1.0f/7.0f; g2.K = 2048; g2.relu = 0;
  gemm_8ph<<<dim3(32,8,1), 512, 0, stream>>>(g2);

  // Stage 5a (thin): qctx = qb @ Wc1[:, :256]^T   (into dead WB)
  GArgs g5a{};
  g5a.A = qb; g5a.a_z = 0; g5a.a_piece = 0; g5a.lda = 256; g5a.A2 = 0; g5a.a2_z = 0;
  g5a.B = Wc1b; g5a.b_z = 0; g5a.ldb = 512;
  g5a.C = qctx; g5a.c_z = 0; g5a.c_npiece = 0; g5a.ldc = 256;
  g5a.bias = 0; g5a.bias_z = 0; g5a.cbias = 0; g5a.addm = 0; g5a.wc2 = 0; g5a.scores = 0;
  g5a.scale = 1.0f; g5a.K = 256; g5a.relu = 0;
  gemm_thin<<<dim3(128,1,1), 256, 0, stream>>>(g5a);

  // Stage 3 (thin): hid[m] = relu([xb[m] | cross[m]] @ W1[m]^T + b1[m])
  GArgs g3{};
  g3.A = xb; g3.a_z = BD; g3.a_piece = 0; g3.lda = 256; g3.A2 = cross; g3.a2_z = BD;
  g3.B = W1b; g3.b_z = (long long)DD*2*DD; g3.ldb = 512;
  g3.C = hid; g3.c_z = BD; g3.c_npiece = 0; g3.ldc = 256;
  g3.bias = b1b; g3.bias_z = 256; g3.cbias = 0; g3.addm = 0; g3.wc2 = 0; g3.scores = 0;
  g3.scale = 1.0f; g3.K = 512; g3.relu = 1;
  gemm_thin<<<dim3(128,1,8), 256, 0, stream>>>(g3);

  // Stage 4 (thin): fused[m] = hid[m] @ W2[m]^T + b2[m]   (overwrites dead xb)
  GArgs g4{};
  g4.A = hid; g4.a_z = BD; g4.a_piece = 0; g4.lda = 256; g4.A2 = 0; g4.a2_z = 0;
  g4.B = W2b; g4.b_z = (long long)DD*DD; g4.ldb = 256;
  g4.C = fused; g4.c_z = BD; g4.c_npiece = 0; g4.ldc = 256;
  g4.bias = b2b; g4.bias_z = 256; g4.cbias = 0; g4.addm = 0; g4.wc2 = 0; g4.scores = 0;
  g4.scale = 1.0f; g4.K = 256; g4.relu = 0;
  gemm_thin<<<dim3(128,1,8), 256, 0, stream>>>(g4);

  // Stage 5b (score): scores[m,b] = sigmoid(wc2 . relu(fused[m] @ Wc1[:,256:]^T + qctx + bc1) + bc2)
  GArgs g5b{};
  g5b.A = fused; g5b.a_z = BD; g5b.a_piece = 0; g5b.lda = 256; g5b.A2 = 0; g5b.a2_z = 0;
  g5b.B = Wc1b + 256; g5b.b_z = 0; g5b.ldb = 512;
  g5b.C = 0; g5b.c_z = 0; g5b.c_npiece = 0; g5b.ldc = 0;
  g5b.bias = bc1b; g5b.bias_z = 0; g5b.cbias = bc2f; g5b.addm = qctx;
  g5b.wc2 = wc2b; g5b.scores = scores;
  g5b.scale = 1.0f; g5b.K = 256; g5b.relu = 1;
  gemm_score<<<dim3(128,1,8), 256, 0, stream>>>(g5b);

  final_gate<<<dim3(BB), 256, 0, stream>>>(fused, scores, (float*)d_out);

  (void)in_sizes; (void)n_in; (void)out_size; (void)ws_size;
}

// Round 3
// 349.598 us; speedup vs baseline: 1.0429x; 1.0135x over previous
//
#include <hip/hip_runtime.h>

#define MMOD 8
#define BB 8192
#define DD 256

typedef unsigned short u16;
typedef __attribute__((ext_vector_type(8))) short s16x8;
typedef __attribute__((ext_vector_type(4))) float f32x4;
typedef __attribute__((ext_vector_type(8))) unsigned short u16x8;
typedef __attribute__((ext_vector_type(4))) unsigned short u16x4;
typedef __attribute__((ext_vector_type(4))) short s16x4;

typedef __attribute__((address_space(3))) unsigned short lds_u16;
typedef __attribute__((address_space(1))) const unsigned short gl_u16;

__device__ __forceinline__ float b2f(u16 u){ union{unsigned i; float f;} x; x.i=((unsigned)u)<<16; return x.f; }
__device__ __forceinline__ u16 f2b(float f){ union{float f; unsigned i;} x; x.f=f; unsigned r = x.i + 0x7FFF + ((x.i>>16)&1u); return (u16)(r>>16); }

// async global->LDS: per-lane src address, LDS dest = wave-uniform base + lane*16B
__device__ __forceinline__ void async_cp16(const u16* g, u16* l){
  __builtin_amdgcn_global_load_lds((gl_u16*)g, (lds_u16*)l, 16, 0, 0);
}

// ---------------- fp32 -> bf16 conversion ----------------
struct ConvArgs {
  const float* src[10];
  u16*         dst[10];
  int          n[10];
};
__global__ void convert_kernel(ConvArgs a){
  const long long stride = (long long)gridDim.x * blockDim.x;
  const long long base   = (long long)blockIdx.x * blockDim.x + threadIdx.x;
  for (int s = 0; s < 10; s++){
    const int n  = a.n[s];
    const int n8 = n >> 3;
    const float* sp = a.src[s];
    u16* dst = a.dst[s];
    for (long long i = base; i < n8; i += stride){
      float4 lo = ((const float4*)sp)[i*2];
      float4 hi = ((const float4*)sp)[i*2+1];
      u16x8 p;
      p[0]=f2b(lo.x); p[1]=f2b(lo.y); p[2]=f2b(lo.z); p[3]=f2b(lo.w);
      p[4]=f2b(hi.x); p[5]=f2b(hi.y); p[6]=f2b(hi.z); p[7]=f2b(hi.w);
      *(u16x8*)(dst + (i<<3)) = p;
    }
    for (long long i = ((long long)n8<<3) + base; i < n; i += stride)
      dst[i] = f2b(sp[i]);
  }
}

__device__ __forceinline__ s16x8 load8_f32(const float* p, long long idx){
  float4 lo = *(const float4*)(p + idx);
  float4 hi = *(const float4*)(p + idx + 4);
  s16x8 r;
  r[0]=(short)f2b(lo.x); r[1]=(short)f2b(lo.y); r[2]=(short)f2b(lo.z); r[3]=(short)f2b(lo.w);
  r[4]=(short)f2b(hi.x); r[5]=(short)f2b(hi.y); r[6]=(short)f2b(hi.z); r[7]=(short)f2b(hi.w);
  return r;
}

struct GArgs {
  const u16* A;  long long a_z; long long a_piece; int lda;  // A + z*a_z + (k>>8)*a_piece + b*lda + (k&255)
  const u16* A2; long long a2_z;                             // if non-null: base for k>=256
  const u16* B;  long long b_z; int ldb;                     // B + z*b_z + n*ldb + k   ([N,K] layout)
  u16*       C;  long long c_z; long long c_npiece; int ldc; // C + z*c_z + (n>>8)*c_npiece + b*ldc + (n&255)
  const u16* bias; long long bias_z;   // bf16 bias[n] (per z), optional
  const float* cbias;                  // fp32 bias[global n], optional
  const u16* addm;                     // bf16 addend [b,256] (shared across z), optional
  const u16* wc2;                      // score kernel: bf16 [256]
  float*     scores;                   // score kernel: [z*8192 + b]
  float scale;
  int K;
  int relu;
};

// ---------- 256x256 8-phase pipelined GEMM (stage 2) — round-1 proven version ----------
// BM=BN=256, BK=64, 8 waves (2M x 4N), 512 threads, 128KB LDS (2 bufs x (A 32KB + B 32KB)).
// Per K-tile t, 4 phases (phase q computes m-quadrant {2q,2q+1} x all 4 n-frags x K=64 = 16 MFMA):
// reads-before-barrier, 12/4/4/4 read distribution, two raw s_barriers per phase,
// counted vmcnt(4) once per K-tile (never 0 in steady state).
__global__ __launch_bounds__(512, 2) void gemm_8ph(GArgs g){
  alignas(16) __shared__ u16 L[65536]; // [buf(2)][A/B(2)][256 rows * 64 cols]
  const int tid  = threadIdx.x;
  const int lane = tid & 63;
  const int w    = tid >> 6;        // 0..7
  const int z    = blockIdx.z;

  const int wr  = w >> 2;           // 0..1 : 128-row block
  const int wcn = w & 3;            // 0..3 : 64-col block
  const int fm  = lane & 15;
  const int fq  = lane >> 4;        // 0..3

  const long long arow0 = (long long)blockIdx.x * 256;
  const long long nrow0 = (long long)blockIdx.y * 256;

  // staging geometry: thread covers slots tid (rows 0..63 of half) and tid+512 (rows 64..127)
  const int r0  = tid >> 3;
  const int r1  = r0 + 64;
  const int cs  = tid & 7;
  const int gc0 = cs ^ (r0 & 7);    // swizzle: LDS(r,cs) = global(r, cs^(r&7))
  const int gc1 = cs ^ (r1 & 7);
  const int ldst0 = (w * 64) * 8;        // wave-uniform LDS base (u16 units), i=0
  const int ldst1 = (512 + w * 64) * 8;  // i=1

  const u16* Az = g.A + (long long)z * g.a_z;
  const u16* Bz = g.B + (long long)z * g.b_z;

#define STAGE_A8(c, k0s, h) do{ \
    const u16* gb_ = Az + (long long)((k0s) >> 8) * g.a_piece + ((k0s) & 255); \
    const long long gr_ = arow0 + (h) * 128; \
    u16* lb_ = L + ((c) * 2 + 0) * 16384 + (h) * 8192; \
    async_cp16(gb_ + (gr_ + r0) * (long long)g.lda + gc0 * 8, lb_ + ldst0); \
    async_cp16(gb_ + (gr_ + r1) * (long long)g.lda + gc1 * 8, lb_ + ldst1); \
  }while(0)
#define STAGE_B8(c, k0s, h) do{ \
    const u16* gb_ = Bz + (k0s); \
    const long long gr_ = nrow0 + (h) * 128; \
    u16* lb_ = L + ((c) * 2 + 1) * 16384 + (h) * 8192; \
    async_cp16(gb_ + (gr_ + r0) * (long long)g.ldb + gc0 * 8, lb_ + ldst0); \
    async_cp16(gb_ + (gr_ + r1) * (long long)g.ldb + gc1 * 8, lb_ + ldst1); \
  }while(0)

  f32x4 acc[8][4];
  #pragma unroll
  for (int i=0;i<8;i++)
    #pragma unroll
    for (int j=0;j<4;j++)
      #pragma unroll
      for (int r=0;r<4;r++) acc[i][j][r] = 0.0f;

  const int T = g.K >> 6;

  // prologue: A(0), B(0), B(1) -> allow B(1) (2 halves = 4 loads) in flight
  STAGE_A8(0, 0, 0);  STAGE_A8(0, 0, 1);
  STAGE_B8(0, 0, 0);  STAGE_B8(0, 0, 1);
  STAGE_B8(1, 64, 0); STAGE_B8(1, 64, 1);
  asm volatile("s_waitcnt vmcnt(4)" ::: "memory");
  __builtin_amdgcn_s_barrier();

  int c = 0;
  for (int t = 0; t < T; ++t, c ^= 1){
    const int k0 = t << 6;
    const u16* lA = L + (c * 2 + 0) * 16384;
    const u16* lB = L + (c * 2 + 1) * 16384;
    s16x8 bf[4][2];
    #pragma unroll
    for (int q = 0; q < 4; ++q){
      if (q == 0 && t + 1 < T) STAGE_A8(c ^ 1, k0 + 64, 0);
      if (q == 1 && t + 1 < T) STAGE_A8(c ^ 1, k0 + 64, 1);
      if (q == 2 && t + 2 < T) STAGE_B8(c,     k0 + 128, 0);
      if (q == 3 && t + 2 < T) STAGE_B8(c,     k0 + 128, 1);
      if (q == 0){
        #pragma unroll
        for (int ni = 0; ni < 4; ni++){
          const int R = wcn * 64 + ni * 16 + fm;
          #pragma unroll
          for (int kk = 0; kk < 2; kk++){
            const int qf = kk * 4 + fq;
            bf[ni][kk] = *(const s16x8*)(lB + R * 64 + ((qf ^ (R & 7)) << 3));
          }
        }
      }
      s16x8 af[2][2];
      #pragma unroll
      for (int j = 0; j < 2; j++){
        const int R = wr * 128 + (q * 2 + j) * 16 + fm;
        #pragma unroll
        for (int kk = 0; kk < 2; kk++){
          const int qf = kk * 4 + fq;
          af[j][kk] = *(const s16x8*)(lA + R * 64 + ((qf ^ (R & 7)) << 3));
        }
      }
      __builtin_amdgcn_s_barrier();
      __builtin_amdgcn_s_setprio(1);
      #pragma unroll
      for (int kk = 0; kk < 2; kk++)
        #pragma unroll
        for (int j = 0; j < 2; j++)
          #pragma unroll
          for (int ni = 0; ni < 4; ni++)
            acc[q*2+j][ni] = __builtin_amdgcn_mfma_f32_16x16x32_bf16(af[j][kk], bf[ni][kk], acc[q*2+j][ni], 0, 0, 0);
      __builtin_amdgcn_s_setprio(0);
      if (q == 3){
        if (t + 2 < T)      asm volatile("s_waitcnt vmcnt(4)" ::: "memory");
        else if (t + 1 < T) asm volatile("s_waitcnt vmcnt(0)" ::: "memory");
      }
      __builtin_amdgcn_s_barrier();
    }
  }

  u16* Cb = g.C + (long long)z * g.c_z;
  const u16* biasp = g.bias ? g.bias + (long long)z * g.bias_z : (const u16*)0;
  #pragma unroll
  for (int mi = 0; mi < 8; mi++){
    #pragma unroll
    for (int ni = 0; ni < 4; ni++){
      const int n = (int)nrow0 + wcn * 64 + ni * 16 + fm;
      float bb = 0.0f;
      if (g.cbias) bb = g.cbias[n];
      else if (biasp) bb = b2f(biasp[n]);
      const long long cn = ((long long)(n >> 8)) * g.c_npiece + (n & 255);
      #pragma unroll
      for (int r = 0; r < 4; r++){
        const long long b = arow0 + wr * 128 + mi * 16 + fq * 4 + r;
        float v = acc[mi][ni][r] * g.scale + bb;
        if (g.relu) v = v > 0.0f ? v : 0.0f;
        Cb[cn + b * (long long)g.ldc] = f2b(v);
      }
    }
  }
#undef STAGE_A8
#undef STAGE_B8
}

// ---------- thin full-N tile: 64 rows x 256 cols, BK=64 ----------
// wave w owns rows [w*16, w*16+16), all 256 n-cols (16 n-tiles). LDS 40KB -> 4 blocks/CU.
__global__ __launch_bounds__(256, 4) void gemm_thin(GArgs g){
  alignas(16) __shared__ u16 lA[64*64];
  alignas(16) __shared__ u16 lB[256*64];
  const int tid  = threadIdx.x;
  const int lane = tid & 63;
  const int w    = tid >> 6;
  const int z    = blockIdx.z;

  const u16* Bbase = g.B + (long long)z * g.b_z;

  f32x4 acc[16];
  #pragma unroll
  for (int j=0;j<16;j++)
    #pragma unroll
    for (int r=0;r<4;r++) acc[j][r] = 0.0f;

  const int fm = lane & 15;
  const int fk = (lane >> 4) * 8;
  const long long arow0 = (long long)blockIdx.x * 64;

  const int sr = lane >> 3;
  const int sq = (lane & 7) ^ sr;

  for (int k0 = 0; k0 < g.K; k0 += 64){
    const u16* Abase0 = (g.A2 && k0 >= 256) ? (g.A2 + (long long)z * g.a2_z)
                                            : (g.A  + (long long)z * g.a_z);
    const u16* At = Abase0 + (long long)(k0 >> 8) * g.a_piece + (k0 & 255);
    const u16* Bt = Bbase + k0;
    __syncthreads();
    #pragma unroll
    for (int i=0;i<2;i++){
      int r = i*32 + w*8 + sr;
      async_cp16(At + (arow0 + r) * (long long)g.lda + sq*8, lA + (i*256 + w*64) * 8);
    }
    #pragma unroll
    for (int i=0;i<8;i++){
      int r = i*32 + w*8 + sr;
      async_cp16(Bt + (long long)r * g.ldb + sq*8, lB + (i*256 + w*64) * 8);
    }
    __syncthreads();
    #pragma unroll
    for (int kk = 0; kk < 64; kk += 32){
      const int qf = (kk + fk) >> 3;
      int ra = w*16 + fm;
      s16x8 af = *(const s16x8*)(lA + (ra*8 + (qf ^ (ra & 7))) * 8);
      #pragma unroll
      for (int ni=0; ni<16; ni++){
        int r = ni*16 + fm;
        s16x8 bfr = *(const s16x8*)(lB + (r*8 + (qf ^ (r & 7))) * 8);
        acc[ni] = __builtin_amdgcn_mfma_f32_16x16x32_bf16(af, bfr, acc[ni], 0, 0, 0);
      }
    }
  }

  u16* Cb = g.C + (long long)z * g.c_z;
  const u16* biasp = g.bias ? g.bias + (long long)z * g.bias_z : (const u16*)0;
  #pragma unroll
  for (int ni=0; ni<16; ni++){
    int n = ni*16 + fm;
    float bb = 0.0f;
    if (g.cbias) bb = g.cbias[n];
    else if (biasp) bb = b2f(biasp[n]);
    #pragma unroll
    for (int r=0; r<4; r++){
      long long b = arow0 + w*16 + (lane>>4)*4 + r;
      float v = acc[ni][r] * g.scale + bb;
      if (g.addm) v += b2f(g.addm[b*256 + n]);
      if (g.relu) v = v > 0.0f ? v : 0.0f;
      Cb[b * (long long)g.ldc + n] = f2b(v);
    }
  }
}

// ---------- fused stages 3+4: hid = relu([x|cross]@W1^T + b1) kept in LDS,
//            fused = hid@W2^T + b2 written to global. ----------
// 4 waves, 64 b-rows/block. Phase A uses SWAPPED mfma(W1,x) so each lane holds
// hid[d = ni*16+fq*4+r][b = w*16+fm]: 4 consecutive d -> packed ds_write_b64
// into swizzled lH[64 b][256 d]. Phase B reads A-frags from lH (own-wave rows only).
// LDS: lB 32KB + lH 32KB (lA overlaid on lH) = 64KB -> 2 blocks/CU.
struct S34Args {
  const u16* X;   // [z*BD + b*256 + k]
  const u16* CR;  // cross, same layout
  const u16* W1;  // [z*131072 + d*512 + k]
  const u16* W2;  // [z*65536 + o*256 + d]
  const u16* b1;  // [z*256 + d]
  const u16* b2;  // [z*256 + o]
  u16*       F;   // fused out, [z*BD + b*256 + o]
};
__global__ __launch_bounds__(256, 2) void gemm_s34(S34Args a){
  alignas(16) __shared__ u16 lB[256*64];   // 32KB: W1 k-tile (phase A) / W2 k-tile (phase B)
  alignas(16) __shared__ u16 lH[64*256];   // 32KB: hid^ tile; first 8KB doubles as lA in phase A
  u16* lA = lH;

  const int tid  = threadIdx.x;
  const int lane = tid & 63;
  const int w    = tid >> 6;
  const int z    = blockIdx.z;

  const int fm = lane & 15;
  const int fq = lane >> 4;
  const long long arow0 = (long long)blockIdx.x * 64;
  const long long BD = (long long)BB * DD;

  const int sr = lane >> 3;
  const int sq = (lane & 7) ^ sr;

  const u16* Xz  = a.X  + (long long)z * BD;
  const u16* CRz = a.CR + (long long)z * BD;
  const u16* W1z = a.W1 + (long long)z * 131072;
  const u16* W2z = a.W2 + (long long)z * 65536;

  // ---------------- phase A: hid (swapped operands) ----------------
  f32x4 acc[16];
  #pragma unroll
  for (int j=0;j<16;j++)
    #pragma unroll
    for (int r=0;r<4;r++) acc[j][r] = 0.0f;

  for (int k0 = 0; k0 < 512; k0 += 64){
    const u16* At = (k0 < 256) ? (Xz + k0) : (CRz + (k0 - 256));
    const u16* Bt = W1z + k0;
    __syncthreads();
    #pragma unroll
    for (int i=0;i<2;i++){
      int r = i*32 + w*8 + sr;
      async_cp16(At + (arow0 + r) * 256 + sq*8, lA + (i*256 + w*64) * 8);
    }
    #pragma unroll
    for (int i=0;i<8;i++){
      int r = i*32 + w*8 + sr;
      async_cp16(Bt + (long long)r * 512 + sq*8, lB + (i*256 + w*64) * 8);
    }
    __syncthreads();
    #pragma unroll
    for (int kk = 0; kk < 64; kk += 32){
      const int qf = (kk >> 3) + fq;
      int ra = w*16 + fm;
      s16x8 af = *(const s16x8*)(lA + (ra*8 + (qf ^ (ra & 7))) * 8);
      #pragma unroll
      for (int ni=0; ni<16; ni++){
        int r = ni*16 + fm;
        s16x8 bfr = *(const s16x8*)(lB + (r*8 + (qf ^ (r & 7))) * 8);
        // swapped: lane holds hid[d = ni*16+fq*4+rr][b = w*16+fm]
        acc[ni] = __builtin_amdgcn_mfma_f32_16x16x32_bf16(bfr, af, acc[ni], 0, 0, 0);
      }
    }
  }

  // all waves done reading lA (overlaid on lH) before pack-writes
  __syncthreads();

  // pack relu(hid + b1) -> lH[b][d], swizzled chunks (chunk c of 8 u16; c low3 ^= b&7)
  {
    const int b = w*16 + fm;
    #pragma unroll
    for (int ni=0; ni<16; ni++){
      s16x4 b1v = *(const s16x4*)(a.b1 + (long long)z*256 + ni*16 + fq*4);
      u16x4 pk;
      #pragma unroll
      for (int r=0; r<4; r++){
        float v = acc[ni][r] + b2f((u16)b1v[r]);
        v = v > 0.0f ? v : 0.0f;
        pk[r] = f2b(v);
      }
      const int c = ni*2 + (fq >> 1);              // 16B-chunk index 0..31
      const int csw = (c & ~7) | ((c & 7) ^ (b & 7));
      *(u16x4*)(lH + b*256 + csw*8 + (fq & 1)*4) = pk;
    }
  }

  // ---------------- phase B: fused = hid @ W2^T + b2 ----------------
  f32x4 acc2[16];
  #pragma unroll
  for (int j=0;j<16;j++)
    #pragma unroll
    for (int r=0;r<4;r++) acc2[j][r] = 0.0f;

  for (int k0 = 0; k0 < 256; k0 += 64){
    const u16* Bt = W2z + k0;
    __syncthreads();
    #pragma unroll
    for (int i=0;i<8;i++){
      int r = i*32 + w*8 + sr;
      async_cp16(Bt + (long long)r * 256 + sq*8, lB + (i*256 + w*64) * 8);
    }
    __syncthreads();
    #pragma unroll
    for (int kk = 0; kk < 64; kk += 32){
      const int ra = w*16 + fm;
      const int qa = ((k0 + kk) >> 3) + fq;        // 0..31 chunk in lH row
      const int qsw = (qa & ~7) | ((qa & 7) ^ (ra & 7));
      s16x8 af = *(const s16x8*)(lH + ra*256 + qsw*8);
      const int qf = (kk >> 3) + fq;               // 0..7 chunk in lB row
      #pragma unroll
      for (int ni=0; ni<16; ni++){
        int r = ni*16 + fm;
        s16x8 bfr = *(const s16x8*)(lB + (r*8 + (qf ^ (r & 7))) * 8);
        acc2[ni] = __builtin_amdgcn_mfma_f32_16x16x32_bf16(af, bfr, acc2[ni], 0, 0, 0);
      }
    }
  }

  u16* Fz = a.F + (long long)z * BD;
  #pragma unroll
  for (int ni=0; ni<16; ni++){
    int o = ni*16 + fm;
    float bb = b2f(a.b2[(long long)z*256 + o]);
    #pragma unroll
    for (int r=0; r<4; r++){
      long long b = arow0 + w*16 + fq*4 + r;
      Fz[b * 256 + o] = f2b(acc2[ni][r] + bb);
    }
  }
}

// ---------- stage5b fused: ch in regs -> wc2 dot -> sigmoid -> scores only ----------
__global__ __launch_bounds__(256, 4) void gemm_score(GArgs g){
  alignas(16) __shared__ u16 lA[64*64];
  alignas(16) __shared__ u16 lB[256*64];
  const int tid  = threadIdx.x;
  const int lane = tid & 63;
  const int w    = tid >> 6;
  const int z    = blockIdx.z;

  const u16* Bbase = g.B;

  f32x4 acc[16];
  #pragma unroll
  for (int j=0;j<16;j++)
    #pragma unroll
    for (int r=0;r<4;r++) acc[j][r] = 0.0f;

  const int fm = lane & 15;
  const int fk = (lane >> 4) * 8;
  const long long arow0 = (long long)blockIdx.x * 64;

  const int sr = lane >> 3;
  const int sq = (lane & 7) ^ sr;

  for (int k0 = 0; k0 < g.K; k0 += 64){
    const u16* At = g.A + (long long)z * g.a_z + k0;
    const u16* Bt = Bbase + k0;
    __syncthreads();
    #pragma unroll
    for (int i=0;i<2;i++){
      int r = i*32 + w*8 + sr;
      async_cp16(At + (arow0 + r) * (long long)g.lda + sq*8, lA + (i*256 + w*64) * 8);
    }
    #pragma unroll
    for (int i=0;i<8;i++){
      int r = i*32 + w*8 + sr;
      async_cp16(Bt + (long long)r * g.ldb + sq*8, lB + (i*256 + w*64) * 8);
    }
    __syncthreads();
    #pragma unroll
    for (int kk = 0; kk < 64; kk += 32){
      const int qf = (kk + fk) >> 3;
      int ra = w*16 + fm;
      s16x8 af = *(const s16x8*)(lA + (ra*8 + (qf ^ (ra & 7))) * 8);
      #pragma unroll
      for (int ni=0; ni<16; ni++){
        int r = ni*16 + fm;
        s16x8 bfr = *(const s16x8*)(lB + (r*8 + (qf ^ (r & 7))) * 8);
        acc[ni] = __builtin_amdgcn_mfma_f32_16x16x32_bf16(af, bfr, acc[ni], 0, 0, 0);
      }
    }
  }

  // epilogue: ch = relu(acc + qctx + bc1); p[r] = sum_n ch*wc2[n]; score = sigmoid(p + bc2)
  float p[4] = {0.f, 0.f, 0.f, 0.f};
  #pragma unroll
  for (int ni=0; ni<16; ni++){
    int n = ni*16 + fm;
    float bb = b2f(g.bias[n]);
    float wcv = b2f(g.wc2[n]);
    #pragma unroll
    for (int r=0; r<4; r++){
      long long b = arow0 + w*16 + (lane>>4)*4 + r;
      float v = acc[ni][r] + bb + b2f(g.addm[b*256 + n]);
      v = v > 0.0f ? v : 0.0f;
      p[r] += v * wcv;
    }
  }
  // reduce across the 16 lanes of the quad (fm = low 4 bits)
  #pragma unroll
  for (int r=0; r<4; r++){
    #pragma unroll
    for (int off=1; off<16; off<<=1) p[r] += __shfl_xor(p[r], off);
  }
  if (fm == 0){
    float bc2f = g.cbias[0];
    #pragma unroll
    for (int r=0; r<4; r++){
      long long b = arow0 + w*16 + (lane>>4)*4 + r;
      g.scores[(long long)z*BB + b] = 1.0f / (1.0f + __expf(-(p[r] + bc2f)));
    }
  }
}

// WB[n=(s*256+o)][k=(t*256+d)] = sum_e Wo[s,t,o,e]*Wv[s,t,e,d], zeroed on s==t diagonal.
__global__ __launch_bounds__(256, 2) void build_wb(const float* Wo, const float* Wv, u16* WB){
  alignas(16) __shared__ u16 lA[128*64];
  alignas(16) __shared__ u16 lB[128*64];
  const int tid  = threadIdx.x;
  const int lane = tid & 63;
  const int w    = tid >> 6;
  const int z = blockIdx.z, s = z >> 3, t = z & 7;
  const long long zoff = (long long)z * 65536;

  f32x4 acc[4][4];
  #pragma unroll
  for (int i=0;i<4;i++)
    #pragma unroll
    for (int j=0;j<4;j++)
      #pragma unroll
      for (int r=0;r<4;r++) acc[i][j][r] = 0.0f;

  const int wr = (w >> 1) * 64, wc = (w & 1) * 64;
  const int fm = lane & 15;
  const int fk = (lane >> 4) * 8;

  int srow[4], sq[4];
  #pragma unroll
  for (int i=0;i<4;i++){
    int c = i*256 + tid;
    srow[i] = c >> 3;
    sq[i]   = (c & 7) ^ (srow[i] & 7);
  }

  for (int k0 = 0; k0 < 256; k0 += 64){
    s16x8 va[4], vt[4];
    #pragma unroll
    for (int i=0;i<4;i++){
      long long aidx = zoff + (long long)(blockIdx.x*128 + srow[i]) * 256 + k0 + sq[i]*8;
      va[i] = load8_f32(Wo, aidx);
    }
    #pragma unroll
    for (int j=0;j<4;j++){
      int id = j*256 + tid;
      int e  = id >> 4;
      int dc = (id & 15) * 8;
      long long bidx = zoff + (long long)(k0 + e) * 256 + blockIdx.y*128 + dc;
      vt[j] = load8_f32(Wv, bidx);
    }
    __syncthreads();
    #pragma unroll
    for (int i=0;i<4;i++){
      int c = i*256 + tid;
      *(s16x8*)(lA + c*8) = va[i];
    }
    #pragma unroll
    for (int j=0;j<4;j++){
      int id = j*256 + tid;
      int e  = id >> 4;
      int dc = (id & 15) * 8;
      #pragma unroll
      for (int u=0; u<8; u++){
        int d = dc + u;
        lB[(d*8 + ((e>>3) ^ (d & 7)))*8 + (e & 7)] = (u16)vt[j][u];
      }
    }
    __syncthreads();
    #pragma unroll
    for (int kk = 0; kk < 64; kk += 32){
      s16x8 af[4], bfr[4];
      const int qf = (kk + fk) >> 3;
      #pragma unroll
      for (int mi=0; mi<4; mi++){
        int r = wr + mi*16 + fm;
        af[mi] = *(const s16x8*)(lA + (r*8 + (qf ^ (r & 7))) * 8);
      }
      #pragma unroll
      for (int ni=0; ni<4; ni++){
        int r = wc + ni*16 + fm;
        bfr[ni] = *(const s16x8*)(lB + (r*8 + (qf ^ (r & 7))) * 8);
      }
      #pragma unroll
      for (int mi=0; mi<4; mi++)
        #pragma unroll
        for (int ni=0; ni<4; ni++)
          acc[mi][ni] = __builtin_amdgcn_mfma_f32_16x16x32_bf16(af[mi], bfr[ni], acc[mi][ni], 0, 0, 0);
    }
    __syncthreads();
  }
  const int diag = (s == t);
  #pragma unroll
  for (int mi=0; mi<4; mi++){
    #pragma unroll
    for (int ni=0; ni<4; ni++){
      int d = blockIdx.y*128 + wc + ni*16 + fm;
      #pragma unroll
      for (int r=0; r<4; r++){
        int o = blockIdx.x*128 + wr + mi*16 + (lane>>4)*4 + r;
        float v = diag ? 0.0f : acc[mi][ni][r];
        WB[(long long)(s*256 + o) * 2048 + t*256 + d] = f2b(v);
      }
    }
  }
}

// cb[s*256+o] += (1/7)*( dot(bv[s,t,:], Wo[s,t,o,:]) + bo[s,t,o] )  for t != s. cb zeroed first.
__global__ __launch_bounds__(256) void cb_kernel(const float* bv, const float* Wo, const float* bo, float* cb){
  int z = blockIdx.x, s = z >> 3, t = z & 7;
  if (s == t) return;
  int lane = threadIdx.x & 63, w = threadIdx.x >> 6;
  float4 bvv = *(const float4*)(bv + (long long)z*256 + lane*4);
  #pragma unroll
  for (int i=0; i<16; i++){
    int row = blockIdx.y*64 + w*16 + i;
    float4 wv4 = *(const float4*)(Wo + (long long)z*65536 + (long long)row*256 + lane*4);
    float p = wv4.x*bvv.x + wv4.y*bvv.y + wv4.z*bvv.z + wv4.w*bvv.w;
    #pragma unroll
    for (int off=32; off>0; off>>=1) p += __shfl_xor(p, off);
    if (lane == 0)
      atomicAdd(&cb[s*256 + row], (p + bo[(long long)z*256 + row]) * (1.0f/7.0f));
  }
}

// out[b,:] = (1/8) sum_m fused[m,b,:] * scores[m,b]
__global__ __launch_bounds__(256) void final_gate(const u16* fused, const float* scores, float* out){
  int b = blockIdx.x;
  int tid = threadIdx.x;
  float sc[8];
  #pragma unroll
  for (int m=0; m<8; m++) sc[m] = scores[(long long)m*BB + b];
  float acc = 0.0f;
  #pragma unroll
  for (int m=0; m<8; m++)
    acc += b2f(fused[((long long)m*BB + b)*256 + tid]) * sc[m];
  out[(long long)b*256 + tid] = acc * 0.125f;
}

extern "C" void kernel_launch(void* const* d_in, const int* in_sizes, int n_in,
                              void* d_out, int out_size, void* d_ws, size_t ws_size,
                              hipStream_t stream){
  const float* x   = (const float*)d_in[0];
  const float* q   = (const float*)d_in[1];
  const float* Wv  = (const float*)d_in[2];
  const float* bv  = (const float*)d_in[3];
  const float* Wo  = (const float*)d_in[4];
  const float* bo  = (const float*)d_in[5];
  const float* W1  = (const float*)d_in[6];
  const float* b1  = (const float*)d_in[7];
  const float* W2  = (const float*)d_in[8];
  const float* b2  = (const float*)d_in[9];
  const float* Wc1 = (const float*)d_in[10];
  const float* bc1 = (const float*)d_in[11];
  const float* wc2 = (const float*)d_in[12];
  const float* bc2 = (const float*)d_in[13];

  char* ws = (char*)d_ws;
  u16*   xb    = (u16*)(ws + 0LL);            // 32MB; dead after stage3 -> fused
  u16*   qb    = (u16*)(ws + 33554432LL);     // 4MB
  u16*   cross = (u16*)(ws + 37748736LL);     // 32MB
  u16*   WB    = (u16*)(ws + 104857600LL);    // 8MB; dead after stage2 -> qctx+scores
  u16*   W1b   = (u16*)(ws + 113246208LL);    // 2MB
  u16*   W2b   = (u16*)(ws + 115343360LL);    // 1MB
  u16*   Wc1b  = (u16*)(ws + 116391936LL);    // 256KB
  u16*   b1b   = (u16*)(ws + 116654080LL);    // 4KB
  u16*   b2b   = (u16*)(ws + 116658176LL);    // 4KB
  u16*   bc1b  = (u16*)(ws + 116662272LL);    // 512B
  u16*   wc2b  = (u16*)(ws + 116662784LL);    // 512B
  float* bc2f  = (float*)(ws + 116663296LL);  // 64B (fp32 copy via cbias path)
  float* cb    = (float*)(ws + 116663424LL);  // 8KB
  u16*   fused = xb;
  u16*   qctx  = WB;                                   // 4MB (dead WB)
  float* scores = (float*)(ws + 104857600LL + 4194304LL); // 256KB (dead WB upper half)

  ConvArgs ca{};
  ca.src[0]=x;   ca.dst[0]=xb;   ca.n[0]=MMOD*BB*DD;
  ca.src[1]=q;   ca.dst[1]=qb;   ca.n[1]=BB*DD;
  ca.src[2]=W1;  ca.dst[2]=W1b;  ca.n[2]=MMOD*DD*2*DD;
  ca.src[3]=W2;  ca.dst[3]=W2b;  ca.n[3]=MMOD*DD*DD;
  ca.src[4]=Wc1; ca.dst[4]=Wc1b; ca.n[4]=DD*2*DD;
  ca.src[5]=b1;  ca.dst[5]=b1b;  ca.n[5]=MMOD*DD;
  ca.src[6]=b2;  ca.dst[6]=b2b;  ca.n[6]=MMOD*DD;
  ca.src[7]=bc1; ca.dst[7]=bc1b; ca.n[7]=DD;
  ca.src[8]=wc2; ca.dst[8]=wc2b; ca.n[8]=DD;
  ca.src[9]=bc2; ca.dst[9]=bc1b; ca.n[9]=0;   // unused slot (bc2 handled below)
  convert_kernel<<<1024, 256, 0, stream>>>(ca);
  hipMemcpyAsync(bc2f, bc2, sizeof(float), hipMemcpyDeviceToDevice, stream);

  hipMemsetAsync(cb, 0, 2048*sizeof(float), stream);
  build_wb<<<dim3(2,2,64), 256, 0, stream>>>(Wo, Wv, WB);
  cb_kernel<<<dim3(64,4), 256, 0, stream>>>(bv, Wo, bo, cb);

  const long long BD = (long long)BB * DD;

  // Stage 2 (256^2 8-phase): cross[s,b,o] = (1/7) sum_k xb'[b,k] * WB[(s,o),k] + cb
  GArgs g2{};
  g2.A = xb; g2.a_z = 0; g2.a_piece = BD; g2.lda = 256; g2.A2 = 0; g2.a2_z = 0;
  g2.B = WB; g2.b_z = 0; g2.ldb = 2048;
  g2.C = cross; g2.c_z = 0; g2.c_npiece = BD; g2.ldc = 256;
  g2.bias = 0; g2.bias_z = 0; g2.cbias = cb; g2.addm = 0; g2.wc2 = 0; g2.scores = 0;
  g2.scale = 1.0f/7.0f; g2.K = 2048; g2.relu = 0;
  gemm_8ph<<<dim3(32,8,1), 512, 0, stream>>>(g2);

  // Stage 5a (thin): qctx = qb @ Wc1[:, :256]^T   (into dead WB)
  GArgs g5a{};
  g5a.A = qb; g5a.a_z = 0; g5a.a_piece = 0; g5a.lda = 256; g5a.A2 = 0; g5a.a2_z = 0;
  g5a.B = Wc1b; g5a.b_z = 0; g5a.ldb = 512;
  g5a.C = qctx; g5a.c_z = 0; g5a.c_npiece = 0; g5a.ldc = 256;
  g5a.bias = 0; g5a.bias_z = 0; g5a.cbias = 0; g5a.addm = 0; g5a.wc2 = 0; g5a.scores = 0;
  g5a.scale = 1.0f; g5a.K = 256; g5a.relu = 0;
  gemm_thin<<<dim3(128,1,1), 256, 0, stream>>>(g5a);

  // Stages 3+4 fused: fused[m] = relu([xb[m]|cross[m]]@W1[m]^T + b1[m]) @ W2[m]^T + b2[m]
  S34Args s34{};
  s34.X = xb; s34.CR = cross; s34.W1 = W1b; s34.W2 = W2b;
  s34.b1 = b1b; s34.b2 = b2b; s34.F = fused;
  gemm_s34<<<dim3(128,1,8), 256, 0, stream>>>(s34);

  // Stage 5b (score): scores[m,b] = sigmoid(wc2 . relu(fused[m] @ Wc1[:,256:]^T + qctx + bc1) + bc2)
  GArgs g5b{};
  g5b.A = fused; g5b.a_z = BD; g5b.a_piece = 0; g5b.lda = 256; g5b.A2 = 0; g5b.a2_z = 0;
  g5b.B = Wc1b + 256; g5b.b_z = 0; g5b.ldb = 512;
  g5b.C = 0; g5b.c_z = 0; g5b.c_npiece = 0; g5b.ldc = 0;
  g5b.bias = bc1b; g5b.bias_z = 0; g5b.cbias = bc2f; g5b.addm = qctx;
  g5b.wc2 = wc2b; g5b.scores = scores;
  g5b.scale = 1.0f; g5b.K = 256; g5b.relu = 1;
  gemm_score<<<dim3(128,1,8), 256, 0, stream>>>(g5b);

  final_gate<<<dim3(BB), 256, 0, stream>>>(fused, scores, (float*)d_out);

  (void)in_sizes; (void)n_in; (void)out_size; (void)ws_size;
}

// Round 4
// 337.935 us; speedup vs baseline: 1.0789x; 1.0345x over previous
//
#include <hip/hip_runtime.h>

#define MMOD 8
#define BB 8192
#define DD 256

typedef unsigned short u16;
typedef __attribute__((ext_vector_type(8))) short s16x8;
typedef __attribute__((ext_vector_type(4))) float f32x4;
typedef __attribute__((ext_vector_type(8))) unsigned short u16x8;
typedef __attribute__((ext_vector_type(4))) unsigned short u16x4;
typedef __attribute__((ext_vector_type(4))) short s16x4;

typedef __attribute__((address_space(3))) unsigned short lds_u16;
typedef __attribute__((address_space(1))) const unsigned short gl_u16;

__device__ __forceinline__ float b2f(u16 u){ union{unsigned i; float f;} x; x.i=((unsigned)u)<<16; return x.f; }
__device__ __forceinline__ u16 f2b(float f){ union{float f; unsigned i;} x; x.f=f; unsigned r = x.i + 0x7FFF + ((x.i>>16)&1u); return (u16)(r>>16); }

// async global->LDS: per-lane src address, LDS dest = wave-uniform base + lane*16B
__device__ __forceinline__ void async_cp16(const u16* g, u16* l){
  __builtin_amdgcn_global_load_lds((gl_u16*)g, (lds_u16*)l, 16, 0, 0);
}

// ---------------- fp32 -> bf16 conversion ----------------
struct ConvArgs {
  const float* src[10];
  u16*         dst[10];
  int          n[10];
};
__global__ void convert_kernel(ConvArgs a){
  const long long stride = (long long)gridDim.x * blockDim.x;
  const long long base   = (long long)blockIdx.x * blockDim.x + threadIdx.x;
  for (int s = 0; s < 10; s++){
    const int n  = a.n[s];
    const int n8 = n >> 3;
    const float* sp = a.src[s];
    u16* dst = a.dst[s];
    for (long long i = base; i < n8; i += stride){
      float4 lo = ((const float4*)sp)[i*2];
      float4 hi = ((const float4*)sp)[i*2+1];
      u16x8 p;
      p[0]=f2b(lo.x); p[1]=f2b(lo.y); p[2]=f2b(lo.z); p[3]=f2b(lo.w);
      p[4]=f2b(hi.x); p[5]=f2b(hi.y); p[6]=f2b(hi.z); p[7]=f2b(hi.w);
      *(u16x8*)(dst + (i<<3)) = p;
    }
    for (long long i = ((long long)n8<<3) + base; i < n; i += stride)
      dst[i] = f2b(sp[i]);
  }
}

__device__ __forceinline__ s16x8 load8_f32(const float* p, long long idx){
  float4 lo = *(const float4*)(p + idx);
  float4 hi = *(const float4*)(p + idx + 4);
  s16x8 r;
  r[0]=(short)f2b(lo.x); r[1]=(short)f2b(lo.y); r[2]=(short)f2b(lo.z); r[3]=(short)f2b(lo.w);
  r[4]=(short)f2b(hi.x); r[5]=(short)f2b(hi.y); r[6]=(short)f2b(hi.z); r[7]=(short)f2b(hi.w);
  return r;
}

struct GArgs {
  const u16* A;  long long a_z; long long a_piece; int lda;  // A + z*a_z + (k>>8)*a_piece + b*lda + (k&255)
  const u16* A2; long long a2_z;                             // if non-null: base for k>=256
  const u16* B;  long long b_z; int ldb;                     // B + z*b_z + n*ldb + k   ([N,K] layout)
  u16*       C;  long long c_z; long long c_npiece; int ldc; // C + z*c_z + (n>>8)*c_npiece + b*ldc + (n&255)
  const u16* bias; long long bias_z;   // bf16 bias[n] (per z), optional
  const float* cbias;                  // fp32 bias[global n], optional
  float scale;
  int K;
  int relu;
};

// ---------- 256x256 8-phase pipelined GEMM (stage 2) — round-1 proven version ----------
// BM=BN=256, BK=64, 8 waves (2M x 4N), 512 threads, 128KB LDS (2 bufs x (A 32KB + B 32KB)).
// Per K-tile t, 4 phases (phase q computes m-quadrant {2q,2q+1} x all 4 n-frags x K=64 = 16 MFMA):
// reads-before-barrier, 12/4/4/4 read distribution, two raw s_barriers per phase,
// counted vmcnt(4) once per K-tile (never 0 in steady state).
__global__ __launch_bounds__(512, 2) void gemm_8ph(GArgs g){
  alignas(16) __shared__ u16 L[65536]; // [buf(2)][A/B(2)][256 rows * 64 cols]
  const int tid  = threadIdx.x;
  const int lane = tid & 63;
  const int w    = tid >> 6;        // 0..7
  const int z    = blockIdx.z;

  const int wr  = w >> 2;           // 0..1 : 128-row block
  const int wcn = w & 3;            // 0..3 : 64-col block
  const int fm  = lane & 15;
  const int fq  = lane >> 4;        // 0..3

  const long long arow0 = (long long)blockIdx.x * 256;
  const long long nrow0 = (long long)blockIdx.y * 256;

  // staging geometry: thread covers slots tid (rows 0..63 of half) and tid+512 (rows 64..127)
  const int r0  = tid >> 3;
  const int r1  = r0 + 64;
  const int cs  = tid & 7;
  const int gc0 = cs ^ (r0 & 7);    // swizzle: LDS(r,cs) = global(r, cs^(r&7))
  const int gc1 = cs ^ (r1 & 7);
  const int ldst0 = (w * 64) * 8;        // wave-uniform LDS base (u16 units), i=0
  const int ldst1 = (512 + w * 64) * 8;  // i=1

  const u16* Az = g.A + (long long)z * g.a_z;
  const u16* Bz = g.B + (long long)z * g.b_z;

#define STAGE_A8(c, k0s, h) do{ \
    const u16* gb_ = Az + (long long)((k0s) >> 8) * g.a_piece + ((k0s) & 255); \
    const long long gr_ = arow0 + (h) * 128; \
    u16* lb_ = L + ((c) * 2 + 0) * 16384 + (h) * 8192; \
    async_cp16(gb_ + (gr_ + r0) * (long long)g.lda + gc0 * 8, lb_ + ldst0); \
    async_cp16(gb_ + (gr_ + r1) * (long long)g.lda + gc1 * 8, lb_ + ldst1); \
  }while(0)
#define STAGE_B8(c, k0s, h) do{ \
    const u16* gb_ = Bz + (k0s); \
    const long long gr_ = nrow0 + (h) * 128; \
    u16* lb_ = L + ((c) * 2 + 1) * 16384 + (h) * 8192; \
    async_cp16(gb_ + (gr_ + r0) * (long long)g.ldb + gc0 * 8, lb_ + ldst0); \
    async_cp16(gb_ + (gr_ + r1) * (long long)g.ldb + gc1 * 8, lb_ + ldst1); \
  }while(0)

  f32x4 acc[8][4];
  #pragma unroll
  for (int i=0;i<8;i++)
    #pragma unroll
    for (int j=0;j<4;j++)
      #pragma unroll
      for (int r=0;r<4;r++) acc[i][j][r] = 0.0f;

  const int T = g.K >> 6;

  // prologue: A(0), B(0), B(1) -> allow B(1) (2 halves = 4 loads) in flight
  STAGE_A8(0, 0, 0);  STAGE_A8(0, 0, 1);
  STAGE_B8(0, 0, 0);  STAGE_B8(0, 0, 1);
  STAGE_B8(1, 64, 0); STAGE_B8(1, 64, 1);
  asm volatile("s_waitcnt vmcnt(4)" ::: "memory");
  __builtin_amdgcn_s_barrier();

  int c = 0;
  for (int t = 0; t < T; ++t, c ^= 1){
    const int k0 = t << 6;
    const u16* lA = L + (c * 2 + 0) * 16384;
    const u16* lB = L + (c * 2 + 1) * 16384;
    s16x8 bf[4][2];
    #pragma unroll
    for (int q = 0; q < 4; ++q){
      if (q == 0 && t + 1 < T) STAGE_A8(c ^ 1, k0 + 64, 0);
      if (q == 1 && t + 1 < T) STAGE_A8(c ^ 1, k0 + 64, 1);
      if (q == 2 && t + 2 < T) STAGE_B8(c,     k0 + 128, 0);
      if (q == 3 && t + 2 < T) STAGE_B8(c,     k0 + 128, 1);
      if (q == 0){
        #pragma unroll
        for (int ni = 0; ni < 4; ni++){
          const int R = wcn * 64 + ni * 16 + fm;
          #pragma unroll
          for (int kk = 0; kk < 2; kk++){
            const int qf = kk * 4 + fq;
            bf[ni][kk] = *(const s16x8*)(lB + R * 64 + ((qf ^ (R & 7)) << 3));
          }
        }
      }
      s16x8 af[2][2];
      #pragma unroll
      for (int j = 0; j < 2; j++){
        const int R = wr * 128 + (q * 2 + j) * 16 + fm;
        #pragma unroll
        for (int kk = 0; kk < 2; kk++){
          const int qf = kk * 4 + fq;
          af[j][kk] = *(const s16x8*)(lA + R * 64 + ((qf ^ (R & 7)) << 3));
        }
      }
      __builtin_amdgcn_s_barrier();
      __builtin_amdgcn_s_setprio(1);
      #pragma unroll
      for (int kk = 0; kk < 2; kk++)
        #pragma unroll
        for (int j = 0; j < 2; j++)
          #pragma unroll
          for (int ni = 0; ni < 4; ni++)
            acc[q*2+j][ni] = __builtin_amdgcn_mfma_f32_16x16x32_bf16(af[j][kk], bf[ni][kk], acc[q*2+j][ni], 0, 0, 0);
      __builtin_amdgcn_s_setprio(0);
      if (q == 3){
        if (t + 2 < T)      asm volatile("s_waitcnt vmcnt(4)" ::: "memory");
        else if (t + 1 < T) asm volatile("s_waitcnt vmcnt(0)" ::: "memory");
      }
      __builtin_amdgcn_s_barrier();
    }
  }

  u16* Cb = g.C + (long long)z * g.c_z;
  const u16* biasp = g.bias ? g.bias + (long long)z * g.bias_z : (const u16*)0;
  #pragma unroll
  for (int mi = 0; mi < 8; mi++){
    #pragma unroll
    for (int ni = 0; ni < 4; ni++){
      const int n = (int)nrow0 + wcn * 64 + ni * 16 + fm;
      float bb = 0.0f;
      if (g.cbias) bb = g.cbias[n];
      else if (biasp) bb = b2f(biasp[n]);
      const long long cn = ((long long)(n >> 8)) * g.c_npiece + (n & 255);
      #pragma unroll
      for (int r = 0; r < 4; r++){
        const long long b = arow0 + wr * 128 + mi * 16 + fq * 4 + r;
        float v = acc[mi][ni][r] * g.scale + bb;
        if (g.relu) v = v > 0.0f ? v : 0.0f;
        Cb[cn + b * (long long)g.ldc] = f2b(v);
      }
    }
  }
#undef STAGE_A8
#undef STAGE_B8
}

// ---------- thin full-N tile: 64 rows x 256 cols, BK=64 ----------
__global__ __launch_bounds__(256, 4) void gemm_thin(GArgs g){
  alignas(16) __shared__ u16 lA[64*64];
  alignas(16) __shared__ u16 lB[256*64];
  const int tid  = threadIdx.x;
  const int lane = tid & 63;
  const int w    = tid >> 6;
  const int z    = blockIdx.z;

  const u16* Bbase = g.B + (long long)z * g.b_z;

  f32x4 acc[16];
  #pragma unroll
  for (int j=0;j<16;j++)
    #pragma unroll
    for (int r=0;r<4;r++) acc[j][r] = 0.0f;

  const int fm = lane & 15;
  const int fk = (lane >> 4) * 8;
  const long long arow0 = (long long)blockIdx.x * 64;

  const int sr = lane >> 3;
  const int sq = (lane & 7) ^ sr;

  for (int k0 = 0; k0 < g.K; k0 += 64){
    const u16* Abase0 = (g.A2 && k0 >= 256) ? (g.A2 + (long long)z * g.a2_z)
                                            : (g.A  + (long long)z * g.a_z);
    const u16* At = Abase0 + (long long)(k0 >> 8) * g.a_piece + (k0 & 255);
    const u16* Bt = Bbase + k0;
    __syncthreads();
    #pragma unroll
    for (int i=0;i<2;i++){
      int r = i*32 + w*8 + sr;
      async_cp16(At + (arow0 + r) * (long long)g.lda + sq*8, lA + (i*256 + w*64) * 8);
    }
    #pragma unroll
    for (int i=0;i<8;i++){
      int r = i*32 + w*8 + sr;
      async_cp16(Bt + (long long)r * g.ldb + sq*8, lB + (i*256 + w*64) * 8);
    }
    __syncthreads();
    #pragma unroll
    for (int kk = 0; kk < 64; kk += 32){
      const int qf = (kk + fk) >> 3;
      int ra = w*16 + fm;
      s16x8 af = *(const s16x8*)(lA + (ra*8 + (qf ^ (ra & 7))) * 8);
      #pragma unroll
      for (int ni=0; ni<16; ni++){
        int r = ni*16 + fm;
        s16x8 bfr = *(const s16x8*)(lB + (r*8 + (qf ^ (r & 7))) * 8);
        acc[ni] = __builtin_amdgcn_mfma_f32_16x16x32_bf16(af, bfr, acc[ni], 0, 0, 0);
      }
    }
  }

  u16* Cb = g.C + (long long)z * g.c_z;
  const u16* biasp = g.bias ? g.bias + (long long)z * g.bias_z : (const u16*)0;
  #pragma unroll
  for (int ni=0; ni<16; ni++){
    int n = ni*16 + fm;
    float bb = 0.0f;
    if (g.cbias) bb = g.cbias[n];
    else if (biasp) bb = b2f(biasp[n]);
    #pragma unroll
    for (int r=0; r<4; r++){
      long long b = arow0 + w*16 + (lane>>4)*4 + r;
      float v = acc[ni][r] * g.scale + bb;
      if (g.relu) v = v > 0.0f ? v : 0.0f;
      Cb[b * (long long)g.ldc + n] = f2b(v);
    }
  }
}

// ---------- fused stages 3+4+5b: hid -> fused -> score, one kernel ----------
// 4 waves, 64 b-rows/block, z = modality.
// Phase A (K=512, swapped mfma(W1,x)): lane holds hid[d=ni*16+fq*4+r][b=w*16+fm];
//   pack relu(hid+b1) -> lH[64 b][256 d] (swizzled u16x4 writes, wave-own rows).
// Phase B (K=256, swapped mfma(W2,hid)): lane holds fused[o=ni*16+fq*4+r][b=w*16+fm];
//   write fused+b2 to global (u16x4) AND pack into lH (hid dead) for phase C.
// Phase C (K=256, standard mfma(fused,Wc1h)): ch[b][d'] in regs -> relu(+qctx+bc1),
//   dot wc2, shfl-reduce over fm, sigmoid -> scores[z*BB+b].
// LDS: lB 32KB (W1/W2/Wc1h k-tiles) + lH 32KB (hid, then fused; first 8KB doubles as lA).
struct S34Args {
  const u16* X;    // [z*BD + b*256 + k]
  const u16* CR;   // cross, same layout
  const u16* W1;   // [z*131072 + d*512 + k]
  const u16* W2;   // [z*65536 + o*256 + d]
  const u16* Wc1h; // [d'*512 + 256 + o] i.e. base already offset, ld=512
  const u16* b1;   // [z*256 + d]
  const u16* b2;   // [z*256 + o]
  const u16* bc1;  // [256]
  const u16* wc2;  // [256]
  const u16* qctx; // [b*256 + d']
  const float* bc2f;
  float*     scores; // [z*BB + b]
  u16*       F;    // fused out, [z*BD + b*256 + o]
};
__global__ __launch_bounds__(256, 2) void gemm_s345(S34Args a){
  alignas(16) __shared__ u16 lB[256*64];   // 32KB: weight k-tile for all phases
  alignas(16) __shared__ u16 lH[64*256];   // 32KB: hid / fused tile; first 8KB doubles as lA
  u16* lA = lH;

  const int tid  = threadIdx.x;
  const int lane = tid & 63;
  const int w    = tid >> 6;
  const int z    = blockIdx.z;

  const int fm = lane & 15;
  const int fq = lane >> 4;
  const long long arow0 = (long long)blockIdx.x * 64;
  const long long BD = (long long)BB * DD;

  const int sr = lane >> 3;
  const int sq = (lane & 7) ^ sr;

  const u16* Xz  = a.X  + (long long)z * BD;
  const u16* CRz = a.CR + (long long)z * BD;
  const u16* W1z = a.W1 + (long long)z * 131072;
  const u16* W2z = a.W2 + (long long)z * 65536;

  // ---------------- phase A: hid (swapped operands) ----------------
  f32x4 acc[16];
  #pragma unroll
  for (int j=0;j<16;j++)
    #pragma unroll
    for (int r=0;r<4;r++) acc[j][r] = 0.0f;

  for (int k0 = 0; k0 < 512; k0 += 64){
    const u16* At = (k0 < 256) ? (Xz + k0) : (CRz + (k0 - 256));
    const u16* Bt = W1z + k0;
    __syncthreads();
    #pragma unroll
    for (int i=0;i<2;i++){
      int r = i*32 + w*8 + sr;
      async_cp16(At + (arow0 + r) * 256 + sq*8, lA + (i*256 + w*64) * 8);
    }
    #pragma unroll
    for (int i=0;i<8;i++){
      int r = i*32 + w*8 + sr;
      async_cp16(Bt + (long long)r * 512 + sq*8, lB + (i*256 + w*64) * 8);
    }
    __syncthreads();
    #pragma unroll
    for (int kk = 0; kk < 64; kk += 32){
      const int qf = (kk >> 3) + fq;
      int ra = w*16 + fm;
      s16x8 af = *(const s16x8*)(lA + (ra*8 + (qf ^ (ra & 7))) * 8);
      #pragma unroll
      for (int ni=0; ni<16; ni++){
        int r = ni*16 + fm;
        s16x8 bfr = *(const s16x8*)(lB + (r*8 + (qf ^ (r & 7))) * 8);
        // swapped: lane holds hid[d = ni*16+fq*4+rr][b = w*16+fm]
        acc[ni] = __builtin_amdgcn_mfma_f32_16x16x32_bf16(bfr, af, acc[ni], 0, 0, 0);
      }
    }
  }

  // all waves done reading lA (overlaid on lH) before pack-writes
  __syncthreads();

  // pack relu(hid + b1) -> lH[b][d], swizzled chunks (16B chunk c; c low3 ^= b&7)
  {
    const int b = w*16 + fm;
    #pragma unroll
    for (int ni=0; ni<16; ni++){
      s16x4 b1v = *(const s16x4*)(a.b1 + (long long)z*256 + ni*16 + fq*4);
      u16x4 pk;
      #pragma unroll
      for (int r=0; r<4; r++){
        float v = acc[ni][r] + b2f((u16)b1v[r]);
        v = v > 0.0f ? v : 0.0f;
        pk[r] = f2b(v);
      }
      const int c = ni*2 + (fq >> 1);              // 16B-chunk index 0..31
      const int csw = (c & ~7) | ((c & 7) ^ (b & 7));
      *(u16x4*)(lH + b*256 + csw*8 + (fq & 1)*4) = pk;
    }
  }

  // ---------------- phase B: fused = hid @ W2^T + b2 (swapped operands) ----------------
  f32x4 acc2[16];
  #pragma unroll
  for (int j=0;j<16;j++)
    #pragma unroll
    for (int r=0;r<4;r++) acc2[j][r] = 0.0f;

  for (int k0 = 0; k0 < 256; k0 += 64){
    const u16* Bt = W2z + k0;
    __syncthreads();
    #pragma unroll
    for (int i=0;i<8;i++){
      int r = i*32 + w*8 + sr;
      async_cp16(Bt + (long long)r * 256 + sq*8, lB + (i*256 + w*64) * 8);
    }
    __syncthreads();
    #pragma unroll
    for (int kk = 0; kk < 64; kk += 32){
      const int ra = w*16 + fm;
      const int qa = ((k0 + kk) >> 3) + fq;        // 0..31 chunk in lH row
      const int qsw = (qa & ~7) | ((qa & 7) ^ (ra & 7));
      s16x8 af = *(const s16x8*)(lH + ra*256 + qsw*8);
      const int qf = (kk >> 3) + fq;               // 0..7 chunk in lB row
      #pragma unroll
      for (int ni=0; ni<16; ni++){
        int r = ni*16 + fm;
        s16x8 bfr = *(const s16x8*)(lB + (r*8 + (qf ^ (r & 7))) * 8);
        // swapped: lane holds fused[o = ni*16+fq*4+rr][b = w*16+fm]
        acc2[ni] = __builtin_amdgcn_mfma_f32_16x16x32_bf16(bfr, af, acc2[ni], 0, 0, 0);
      }
    }
  }

  // all waves done reading lH (hid) before overwriting with fused
  __syncthreads();

  // fused + b2 -> global (u16x4) AND pack into lH[b][o] (same swizzle as phase A pack)
  {
    const int b = w*16 + fm;
    u16* Fz = a.F + (long long)z * BD;
    #pragma unroll
    for (int ni=0; ni<16; ni++){
      s16x4 b2v = *(const s16x4*)(a.b2 + (long long)z*256 + ni*16 + fq*4);
      u16x4 pk;
      #pragma unroll
      for (int r=0; r<4; r++)
        pk[r] = f2b(acc2[ni][r] + b2f((u16)b2v[r]));
      *(u16x4*)(Fz + (arow0 + b)*256 + ni*16 + fq*4) = pk;
      const int c = ni*2 + (fq >> 1);
      const int csw = (c & ~7) | ((c & 7) ^ (b & 7));
      *(u16x4*)(lH + b*256 + csw*8 + (fq & 1)*4) = pk;
    }
  }

  // ---------------- phase C: ch = fused @ Wc1h^T (standard operands) ----------------
  f32x4 acc3[16];
  #pragma unroll
  for (int j=0;j<16;j++)
    #pragma unroll
    for (int r=0;r<4;r++) acc3[j][r] = 0.0f;

  for (int k0 = 0; k0 < 256; k0 += 64){
    const u16* Bt = a.Wc1h + k0;
    __syncthreads();
    #pragma unroll
    for (int i=0;i<8;i++){
      int r = i*32 + w*8 + sr;
      async_cp16(Bt + (long long)r * 512 + sq*8, lB + (i*256 + w*64) * 8);
    }
    __syncthreads();
    #pragma unroll
    for (int kk = 0; kk < 64; kk += 32){
      const int ra = w*16 + fm;
      const int qa = ((k0 + kk) >> 3) + fq;
      const int qsw = (qa & ~7) | ((qa & 7) ^ (ra & 7));
      s16x8 af = *(const s16x8*)(lH + ra*256 + qsw*8);
      const int qf = (kk >> 3) + fq;
      #pragma unroll
      for (int ni=0; ni<16; ni++){
        int r = ni*16 + fm;
        s16x8 bfr = *(const s16x8*)(lB + (r*8 + (qf ^ (r & 7))) * 8);
        acc3[ni] = __builtin_amdgcn_mfma_f32_16x16x32_bf16(af, bfr, acc3[ni], 0, 0, 0);
      }
    }
  }

  // score epilogue: relu(ch + qctx + bc1) . wc2 -> sigmoid -> scores
  float p[4] = {0.f, 0.f, 0.f, 0.f};
  #pragma unroll
  for (int ni=0; ni<16; ni++){
    int n = ni*16 + fm;
    float bb = b2f(a.bc1[n]);
    float wcv = b2f(a.wc2[n]);
    #pragma unroll
    for (int r=0; r<4; r++){
      long long b = arow0 + w*16 + fq*4 + r;
      float v = acc3[ni][r] + bb + b2f(a.qctx[b*256 + n]);
      v = v > 0.0f ? v : 0.0f;
      p[r] += v * wcv;
    }
  }
  #pragma unroll
  for (int r=0; r<4; r++){
    #pragma unroll
    for (int off=1; off<16; off<<=1) p[r] += __shfl_xor(p[r], off);
  }
  if (fm == 0){
    float bc2v = a.bc2f[0];
    #pragma unroll
    for (int r=0; r<4; r++){
      long long b = arow0 + w*16 + fq*4 + r;
      a.scores[(long long)z*BB + b] = 1.0f / (1.0f + __expf(-(p[r] + bc2v)));
    }
  }
}

// WB[n=(s*256+o)][k=(t*256+d)] = sum_e Wo[s,t,o,e]*Wv[s,t,e,d], zeroed on s==t diagonal.
__global__ __launch_bounds__(256, 2) void build_wb(const float* Wo, const float* Wv, u16* WB){
  alignas(16) __shared__ u16 lA[128*64];
  alignas(16) __shared__ u16 lB[128*64];
  const int tid  = threadIdx.x;
  const int lane = tid & 63;
  const int w    = tid >> 6;
  const int z = blockIdx.z, s = z >> 3, t = z & 7;
  const long long zoff = (long long)z * 65536;

  f32x4 acc[4][4];
  #pragma unroll
  for (int i=0;i<4;i++)
    #pragma unroll
    for (int j=0;j<4;j++)
      #pragma unroll
      for (int r=0;r<4;r++) acc[i][j][r] = 0.0f;

  const int wr = (w >> 1) * 64, wc = (w & 1) * 64;
  const int fm = lane & 15;
  const int fk = (lane >> 4) * 8;

  int srow[4], sq[4];
  #pragma unroll
  for (int i=0;i<4;i++){
    int c = i*256 + tid;
    srow[i] = c >> 3;
    sq[i]   = (c & 7) ^ (srow[i] & 7);
  }

  for (int k0 = 0; k0 < 256; k0 += 64){
    s16x8 va[4], vt[4];
    #pragma unroll
    for (int i=0;i<4;i++){
      long long aidx = zoff + (long long)(blockIdx.x*128 + srow[i]) * 256 + k0 + sq[i]*8;
      va[i] = load8_f32(Wo, aidx);
    }
    #pragma unroll
    for (int j=0;j<4;j++){
      int id = j*256 + tid;
      int e  = id >> 4;
      int dc = (id & 15) * 8;
      long long bidx = zoff + (long long)(k0 + e) * 256 + blockIdx.y*128 + dc;
      vt[j] = load8_f32(Wv, bidx);
    }
    __syncthreads();
    #pragma unroll
    for (int i=0;i<4;i++){
      int c = i*256 + tid;
      *(s16x8*)(lA + c*8) = va[i];
    }
    #pragma unroll
    for (int j=0;j<4;j++){
      int id = j*256 + tid;
      int e  = id >> 4;
      int dc = (id & 15) * 8;
      #pragma unroll
      for (int u=0; u<8; u++){
        int d = dc + u;
        lB[(d*8 + ((e>>3) ^ (d & 7)))*8 + (e & 7)] = (u16)vt[j][u];
      }
    }
    __syncthreads();
    #pragma unroll
    for (int kk = 0; kk < 64; kk += 32){
      s16x8 af[4], bfr[4];
      const int qf = (kk + fk) >> 3;
      #pragma unroll
      for (int mi=0; mi<4; mi++){
        int r = wr + mi*16 + fm;
        af[mi] = *(const s16x8*)(lA + (r*8 + (qf ^ (r & 7))) * 8);
      }
      #pragma unroll
      for (int ni=0; ni<4; ni++){
        int r = wc + ni*16 + fm;
        bfr[ni] = *(const s16x8*)(lB + (r*8 + (qf ^ (r & 7))) * 8);
      }
      #pragma unroll
      for (int mi=0; mi<4; mi++)
        #pragma unroll
        for (int ni=0; ni<4; ni++)
          acc[mi][ni] = __builtin_amdgcn_mfma_f32_16x16x32_bf16(af[mi], bfr[ni], acc[mi][ni], 0, 0, 0);
    }
    __syncthreads();
  }
  const int diag = (s == t);
  #pragma unroll
  for (int mi=0; mi<4; mi++){
    #pragma unroll
    for (int ni=0; ni<4; ni++){
      int d = blockIdx.y*128 + wc + ni*16 + fm;
      #pragma unroll
      for (int r=0; r<4; r++){
        int o = blockIdx.x*128 + wr + mi*16 + (lane>>4)*4 + r;
        float v = diag ? 0.0f : acc[mi][ni][r];
        WB[(long long)(s*256 + o) * 2048 + t*256 + d] = f2b(v);
      }
    }
  }
}

// cb[s*256+o] += (1/7)*( dot(bv[s,t,:], Wo[s,t,o,:]) + bo[s,t,o] )  for t != s. cb zeroed first.
__global__ __launch_bounds__(256) void cb_kernel(const float* bv, const float* Wo, const float* bo, float* cb){
  int z = blockIdx.x, s = z >> 3, t = z & 7;
  if (s == t) return;
  int lane = threadIdx.x & 63, w = threadIdx.x >> 6;
  float4 bvv = *(const float4*)(bv + (long long)z*256 + lane*4);
  #pragma unroll
  for (int i=0; i<16; i++){
    int row = blockIdx.y*64 + w*16 + i;
    float4 wv4 = *(const float4*)(Wo + (long long)z*65536 + (long long)row*256 + lane*4);
    float p = wv4.x*bvv.x + wv4.y*bvv.y + wv4.z*bvv.z + wv4.w*bvv.w;
    #pragma unroll
    for (int off=32; off>0; off>>=1) p += __shfl_xor(p, off);
    if (lane == 0)
      atomicAdd(&cb[s*256 + row], (p + bo[(long long)z*256 + row]) * (1.0f/7.0f));
  }
}

// out[b,:] = (1/8) sum_m fused[m,b,:] * scores[m,b]
__global__ __launch_bounds__(256) void final_gate(const u16* fused, const float* scores, float* out){
  int b = blockIdx.x;
  int tid = threadIdx.x;
  float sc[8];
  #pragma unroll
  for (int m=0; m<8; m++) sc[m] = scores[(long long)m*BB + b];
  float acc = 0.0f;
  #pragma unroll
  for (int m=0; m<8; m++)
    acc += b2f(fused[((long long)m*BB + b)*256 + tid]) * sc[m];
  out[(long long)b*256 + tid] = acc * 0.125f;
}

extern "C" void kernel_launch(void* const* d_in, const int* in_sizes, int n_in,
                              void* d_out, int out_size, void* d_ws, size_t ws_size,
                              hipStream_t stream){
  const float* x   = (const float*)d_in[0];
  const float* q   = (const float*)d_in[1];
  const float* Wv  = (const float*)d_in[2];
  const float* bv  = (const float*)d_in[3];
  const float* Wo  = (const float*)d_in[4];
  const float* bo  = (const float*)d_in[5];
  const float* W1  = (const float*)d_in[6];
  const float* b1  = (const float*)d_in[7];
  const float* W2  = (const float*)d_in[8];
  const float* b2  = (const float*)d_in[9];
  const float* Wc1 = (const float*)d_in[10];
  const float* bc1 = (const float*)d_in[11];
  const float* wc2 = (const float*)d_in[12];
  const float* bc2 = (const float*)d_in[13];

  char* ws = (char*)d_ws;
  u16*   xb    = (u16*)(ws + 0LL);            // 32MB; dead after s345 phase A -> fused
  u16*   qb    = (u16*)(ws + 33554432LL);     // 4MB
  u16*   cross = (u16*)(ws + 37748736LL);     // 32MB
  u16*   WB    = (u16*)(ws + 104857600LL);    // 8MB; dead after stage2 -> qctx+scores
  u16*   W1b   = (u16*)(ws + 113246208LL);    // 2MB
  u16*   W2b   = (u16*)(ws + 115343360LL);    // 1MB
  u16*   Wc1b  = (u16*)(ws + 116391936LL);    // 256KB
  u16*   b1b   = (u16*)(ws + 116654080LL);    // 4KB
  u16*   b2b   = (u16*)(ws + 116658176LL);    // 4KB
  u16*   bc1b  = (u16*)(ws + 116662272LL);    // 512B
  u16*   wc2b  = (u16*)(ws + 116662784LL);    // 512B
  float* bc2f  = (float*)(ws + 116663296LL);  // 64B (fp32 copy)
  float* cb    = (float*)(ws + 116663424LL);  // 8KB
  u16*   fused = xb;
  u16*   qctx  = WB;                                   // 4MB (dead WB)
  float* scores = (float*)(ws + 104857600LL + 4194304LL); // 256KB (dead WB upper half)

  ConvArgs ca{};
  ca.src[0]=x;   ca.dst[0]=xb;   ca.n[0]=MMOD*BB*DD;
  ca.src[1]=q;   ca.dst[1]=qb;   ca.n[1]=BB*DD;
  ca.src[2]=W1;  ca.dst[2]=W1b;  ca.n[2]=MMOD*DD*2*DD;
  ca.src[3]=W2;  ca.dst[3]=W2b;  ca.n[3]=MMOD*DD*DD;
  ca.src[4]=Wc1; ca.dst[4]=Wc1b; ca.n[4]=DD*2*DD;
  ca.src[5]=b1;  ca.dst[5]=b1b;  ca.n[5]=MMOD*DD;
  ca.src[6]=b2;  ca.dst[6]=b2b;  ca.n[6]=MMOD*DD;
  ca.src[7]=bc1; ca.dst[7]=bc1b; ca.n[7]=DD;
  ca.src[8]=wc2; ca.dst[8]=wc2b; ca.n[8]=DD;
  ca.src[9]=bc2; ca.dst[9]=bc1b; ca.n[9]=0;   // unused slot (bc2 handled below)
  convert_kernel<<<1024, 256, 0, stream>>>(ca);
  hipMemcpyAsync(bc2f, bc2, sizeof(float), hipMemcpyDeviceToDevice, stream);

  hipMemsetAsync(cb, 0, 2048*sizeof(float), stream);
  build_wb<<<dim3(2,2,64), 256, 0, stream>>>(Wo, Wv, WB);
  cb_kernel<<<dim3(64,4), 256, 0, stream>>>(bv, Wo, bo, cb);

  const long long BD = (long long)BB * DD;

  // Stage 2 (256^2 8-phase): cross[s,b,o] = (1/7) sum_k xb'[b,k] * WB[(s,o),k] + cb
  GArgs g2{};
  g2.A = xb; g2.a_z = 0; g2.a_piece = BD; g2.lda = 256; g2.A2 = 0; g2.a2_z = 0;
  g2.B = WB; g2.b_z = 0; g2.ldb = 2048;
  g2.C = cross; g2.c_z = 0; g2.c_npiece = BD; g2.ldc = 256;
  g2.bias = 0; g2.bias_z = 0; g2.cbias = cb;
  g2.scale = 1.0f/7.0f; g2.K = 2048; g2.relu = 0;
  gemm_8ph<<<dim3(32,8,1), 512, 0, stream>>>(g2);

  // Stage 5a (thin): qctx = qb @ Wc1[:, :256]^T   (into dead WB)
  GArgs g5a{};
  g5a.A = qb; g5a.a_z = 0; g5a.a_piece = 0; g5a.lda = 256; g5a.A2 = 0; g5a.a2_z = 0;
  g5a.B = Wc1b; g5a.b_z = 0; g5a.ldb = 512;
  g5a.C = qctx; g5a.c_z = 0; g5a.c_npiece = 0; g5a.ldc = 256;
  g5a.bias = 0; g5a.bias_z = 0; g5a.cbias = 0;
  g5a.scale = 1.0f; g5a.K = 256; g5a.relu = 0;
  gemm_thin<<<dim3(128,1,1), 256, 0, stream>>>(g5a);

  // Stages 3+4+5b fused
  S34Args s34{};
  s34.X = xb; s34.CR = cross; s34.W1 = W1b; s34.W2 = W2b; s34.Wc1h = Wc1b + 256;
  s34.b1 = b1b; s34.b2 = b2b; s34.bc1 = bc1b; s34.wc2 = wc2b;
  s34.qctx = qctx; s34.bc2f = bc2f; s34.scores = scores; s34.F = fused;
  gemm_s345<<<dim3(128,1,8), 256, 0, stream>>>(s34);

  final_gate<<<dim3(BB), 256, 0, stream>>>(fused, scores, (float*)d_out);

  (void)in_sizes; (void)n_in; (void)out_size; (void)ws_size;
}

// Round 5
// 328.135 us; speedup vs baseline: 1.1111x; 1.0299x over previous
//
#include <hip/hip_runtime.h>

#define MMOD 8
#define BB 8192
#define DD 256

typedef unsigned short u16;
typedef __attribute__((ext_vector_type(8))) short s16x8;
typedef __attribute__((ext_vector_type(4))) float f32x4;
typedef __attribute__((ext_vector_type(8))) unsigned short u16x8;
typedef __attribute__((ext_vector_type(4))) unsigned short u16x4;
typedef __attribute__((ext_vector_type(4))) short s16x4;

typedef __attribute__((address_space(3))) unsigned short lds_u16;
typedef __attribute__((address_space(1))) const unsigned short gl_u16;

__device__ __forceinline__ float b2f(u16 u){ union{unsigned i; float f;} x; x.i=((unsigned)u)<<16; return x.f; }
__device__ __forceinline__ u16 f2b(float f){ union{float f; unsigned i;} x; x.f=f; unsigned r = x.i + 0x7FFF + ((x.i>>16)&1u); return (u16)(r>>16); }

// async global->LDS: per-lane src address, LDS dest = wave-uniform base + lane*16B
__device__ __forceinline__ void async_cp16(const u16* g, u16* l){
  __builtin_amdgcn_global_load_lds((gl_u16*)g, (lds_u16*)l, 16, 0, 0);
}

// ---------------- fp32 -> bf16 conversion (+ cb zero + bc2 copy) ----------------
struct ConvArgs {
  const float* src[10];
  u16*         dst[10];
  int          n[10];
  float*       cbz;    // zero 2048 floats
  const float* bc2;    // copy 1 float
  float*       bc2f;
};
__global__ void convert_kernel(ConvArgs a){
  const long long stride = (long long)gridDim.x * blockDim.x;
  const long long base   = (long long)blockIdx.x * blockDim.x + threadIdx.x;
  if (base < 2048) a.cbz[base] = 0.0f;
  if (base == 0)   a.bc2f[0] = a.bc2[0];
  for (int s = 0; s < 10; s++){
    const int n  = a.n[s];
    const int n8 = n >> 3;
    const float* sp = a.src[s];
    u16* dst = a.dst[s];
    for (long long i = base; i < n8; i += stride){
      float4 lo = ((const float4*)sp)[i*2];
      float4 hi = ((const float4*)sp)[i*2+1];
      u16x8 p;
      p[0]=f2b(lo.x); p[1]=f2b(lo.y); p[2]=f2b(lo.z); p[3]=f2b(lo.w);
      p[4]=f2b(hi.x); p[5]=f2b(hi.y); p[6]=f2b(hi.z); p[7]=f2b(hi.w);
      *(u16x8*)(dst + (i<<3)) = p;
    }
    for (long long i = ((long long)n8<<3) + base; i < n; i += stride)
      dst[i] = f2b(sp[i]);
  }
}

__device__ __forceinline__ s16x8 load8_f32(const float* p, long long idx){
  float4 lo = *(const float4*)(p + idx);
  float4 hi = *(const float4*)(p + idx + 4);
  s16x8 r;
  r[0]=(short)f2b(lo.x); r[1]=(short)f2b(lo.y); r[2]=(short)f2b(lo.z); r[3]=(short)f2b(lo.w);
  r[4]=(short)f2b(hi.x); r[5]=(short)f2b(hi.y); r[6]=(short)f2b(hi.z); r[7]=(short)f2b(hi.w);
  return r;
}

struct GArgs {
  const u16* A;  long long a_z; long long a_piece; int lda;  // A + z*a_z + (k>>8)*a_piece + b*lda + (k&255)
  const u16* A2; long long a2_z;                             // if non-null: base for k>=256
  const u16* B;  long long b_z; int ldb;                     // B + z*b_z + n*ldb + k   ([N,K] layout)
  u16*       C;  long long c_z; long long c_npiece; int ldc; // C + z*c_z + (n>>8)*c_npiece + b*ldc + (n&255)
  const u16* bias; long long bias_z;   // bf16 bias[n] (per z), optional
  const float* cbias;                  // fp32 bias[global n], optional
  float scale;
  int K;
  int relu;
};

// ---------- 256x256 8-phase pipelined GEMM, STAGE-2 SPECIALIZED ----------
// Identical schedule to the round-1/3 proven version (reads-before-barrier, 12/4/4/4
// distribution, two raw s_barriers/phase, vmcnt(4) once per K-tile), but:
//  - t-loop unrolled x2 so the LDS buffer index is a compile-time literal
//  - all strides hardcoded (lda=256, ldb=2048, ldc=256, a_piece=c_npiece=BB*256)
// -> staging + ds_read addresses are loop-invariant registers (kills in-loop VALU).
__global__ __launch_bounds__(512, 2) void gemm_8ph(GArgs g){
  alignas(16) __shared__ u16 L[65536]; // [buf(2)][A/B(2)][256 rows * 64 cols]
  const int tid  = threadIdx.x;
  const int lane = tid & 63;
  const int w    = tid >> 6;        // 0..7

  const int wr  = w >> 2;           // 0..1 : 128-row block
  const int wcn = w & 3;            // 0..3 : 64-col block
  const int fm  = lane & 15;
  const int fq  = lane >> 4;        // 0..3

  const long long arow0 = (long long)blockIdx.x * 256;
  const long long nrow0 = (long long)blockIdx.y * 256;

  // staging geometry: thread covers rows r0 (0..63 of half) and r1 = r0+64
  const int r0  = tid >> 3;
  const int r1  = r0 + 64;
  const int cs  = tid & 7;
  const int gc0 = cs ^ (r0 & 7);    // swizzle: LDS(r,cs) = global(r, cs^(r&7))
  const int gc1 = cs ^ (r1 & 7);
  const int ldst0 = (w * 64) * 8;        // wave-uniform LDS base (u16 units)
  const int ldst1 = (512 + w * 64) * 8;

  const u16* Az = g.A;
  const u16* Bz = g.B;

  // per-lane global offsets (u16 units), loop-invariant
  const long long gA0 = (arow0 + r0) * 256  + gc0 * 8;
  const long long gA1 = (arow0 + r1) * 256  + gc1 * 8;
  const long long gB0 = (nrow0 + r0) * 2048 + gc0 * 8;
  const long long gB1 = (nrow0 + r1) * 2048 + gc1 * 8;

#define STAGE_A8(c, k0s, h) do{ \
    const u16* gb_ = Az + (long long)((k0s) >> 8) * 2097152LL + ((k0s) & 255) + (long long)(h) * 32768LL; \
    u16* lb_ = L + ((c) * 2 + 0) * 16384 + (h) * 8192; \
    async_cp16(gb_ + gA0, lb_ + ldst0); \
    async_cp16(gb_ + gA1, lb_ + ldst1); \
  }while(0)
#define STAGE_B8(c, k0s, h) do{ \
    const u16* gb_ = Bz + (k0s) + (long long)(h) * 262144LL; \
    u16* lb_ = L + ((c) * 2 + 1) * 16384 + (h) * 8192; \
    async_cp16(gb_ + gB0, lb_ + ldst0); \
    async_cp16(gb_ + gB1, lb_ + ldst1); \
  }while(0)

  f32x4 acc[8][4];
  #pragma unroll
  for (int i=0;i<8;i++)
    #pragma unroll
    for (int j=0;j<4;j++)
      #pragma unroll
      for (int r=0;r<4;r++) acc[i][j][r] = 0.0f;

  const int T = g.K >> 6;   // 32

  // prologue: A(0), B(0), B(1) -> allow B(1) (2 halves = 4 loads) in flight
  STAGE_A8(0, 0, 0);  STAGE_A8(0, 0, 1);
  STAGE_B8(0, 0, 0);  STAGE_B8(0, 0, 1);
  STAGE_B8(1, 64, 0); STAGE_B8(1, 64, 1);
  asm volatile("s_waitcnt vmcnt(4)" ::: "memory");
  __builtin_amdgcn_s_barrier();

#define TILE8(cc, t) do{ \
    const int k0_ = (t) << 6; \
    const u16* lA_ = L + ((cc) * 2 + 0) * 16384; \
    const u16* lB_ = L + ((cc) * 2 + 1) * 16384; \
    s16x8 bf[4][2]; \
    _Pragma("unroll") \
    for (int q = 0; q < 4; ++q){ \
      if (q == 0 && (t) + 1 < T) STAGE_A8((cc) ^ 1, k0_ + 64, 0); \
      if (q == 1 && (t) + 1 < T) STAGE_A8((cc) ^ 1, k0_ + 64, 1); \
      if (q == 2 && (t) + 2 < T) STAGE_B8((cc),     k0_ + 128, 0); \
      if (q == 3 && (t) + 2 < T) STAGE_B8((cc),     k0_ + 128, 1); \
      if (q == 0){ \
        _Pragma("unroll") \
        for (int ni = 0; ni < 4; ni++){ \
          const int R = wcn * 64 + ni * 16 + fm; \
          _Pragma("unroll") \
          for (int kk = 0; kk < 2; kk++){ \
            const int qf = kk * 4 + fq; \
            bf[ni][kk] = *(const s16x8*)(lB_ + R * 64 + ((qf ^ (R & 7)) << 3)); \
          } \
        } \
      } \
      s16x8 af[2][2]; \
      _Pragma("unroll") \
      for (int j = 0; j < 2; j++){ \
        const int R = wr * 128 + (q * 2 + j) * 16 + fm; \
        _Pragma("unroll") \
        for (int kk = 0; kk < 2; kk++){ \
          const int qf = kk * 4 + fq; \
          af[j][kk] = *(const s16x8*)(lA_ + R * 64 + ((qf ^ (R & 7)) << 3)); \
        } \
      } \
      __builtin_amdgcn_s_barrier(); \
      __builtin_amdgcn_s_setprio(1); \
      _Pragma("unroll") \
      for (int kk = 0; kk < 2; kk++) \
        _Pragma("unroll") \
        for (int j = 0; j < 2; j++) \
          _Pragma("unroll") \
          for (int ni = 0; ni < 4; ni++) \
            acc[q*2+j][ni] = __builtin_amdgcn_mfma_f32_16x16x32_bf16(af[j][kk], bf[ni][kk], acc[q*2+j][ni], 0, 0, 0); \
      __builtin_amdgcn_s_setprio(0); \
      if (q == 3){ \
        if ((t) + 2 < T)      asm volatile("s_waitcnt vmcnt(4)" ::: "memory"); \
        else if ((t) + 1 < T) asm volatile("s_waitcnt vmcnt(0)" ::: "memory"); \
      } \
      __builtin_amdgcn_s_barrier(); \
    } \
  }while(0)

  for (int t = 0; t < T; t += 2){
    TILE8(0, t);
    TILE8(1, t + 1);
  }

  u16* Cb = g.C;
  #pragma unroll
  for (int mi = 0; mi < 8; mi++){
    #pragma unroll
    for (int ni = 0; ni < 4; ni++){
      const int n = (int)nrow0 + wcn * 64 + ni * 16 + fm;
      float bb = g.cbias ? g.cbias[n] : 0.0f;
      const long long cn = ((long long)(n >> 8)) * 2097152LL + (n & 255);
      #pragma unroll
      for (int r = 0; r < 4; r++){
        const long long b = arow0 + wr * 128 + mi * 16 + fq * 4 + r;
        float v = acc[mi][ni][r] * g.scale + bb;
        Cb[cn + b * 256] = f2b(v);
      }
    }
  }
#undef STAGE_A8
#undef STAGE_B8
#undef TILE8
}

// ---------- thin full-N tile: 64 rows x 256 cols, BK=64 ----------
__global__ __launch_bounds__(256, 4) void gemm_thin(GArgs g){
  alignas(16) __shared__ u16 lA[64*64];
  alignas(16) __shared__ u16 lB[256*64];
  const int tid  = threadIdx.x;
  const int lane = tid & 63;
  const int w    = tid >> 6;
  const int z    = blockIdx.z;

  const u16* Bbase = g.B + (long long)z * g.b_z;

  f32x4 acc[16];
  #pragma unroll
  for (int j=0;j<16;j++)
    #pragma unroll
    for (int r=0;r<4;r++) acc[j][r] = 0.0f;

  const int fm = lane & 15;
  const int fk = (lane >> 4) * 8;
  const long long arow0 = (long long)blockIdx.x * 64;

  const int sr = lane >> 3;
  const int sq = (lane & 7) ^ sr;

  for (int k0 = 0; k0 < g.K; k0 += 64){
    const u16* Abase0 = (g.A2 && k0 >= 256) ? (g.A2 + (long long)z * g.a2_z)
                                            : (g.A  + (long long)z * g.a_z);
    const u16* At = Abase0 + (long long)(k0 >> 8) * g.a_piece + (k0 & 255);
    const u16* Bt = Bbase + k0;
    __syncthreads();
    #pragma unroll
    for (int i=0;i<2;i++){
      int r = i*32 + w*8 + sr;
      async_cp16(At + (arow0 + r) * (long long)g.lda + sq*8, lA + (i*256 + w*64) * 8);
    }
    #pragma unroll
    for (int i=0;i<8;i++){
      int r = i*32 + w*8 + sr;
      async_cp16(Bt + (long long)r * g.ldb + sq*8, lB + (i*256 + w*64) * 8);
    }
    __syncthreads();
    #pragma unroll
    for (int kk = 0; kk < 64; kk += 32){
      const int qf = (kk + fk) >> 3;
      int ra = w*16 + fm;
      s16x8 af = *(const s16x8*)(lA + (ra*8 + (qf ^ (ra & 7))) * 8);
      #pragma unroll
      for (int ni=0; ni<16; ni++){
        int r = ni*16 + fm;
        s16x8 bfr = *(const s16x8*)(lB + (r*8 + (qf ^ (r & 7))) * 8);
        acc[ni] = __builtin_amdgcn_mfma_f32_16x16x32_bf16(af, bfr, acc[ni], 0, 0, 0);
      }
    }
  }

  u16* Cb = g.C + (long long)z * g.c_z;
  const u16* biasp = g.bias ? g.bias + (long long)z * g.bias_z : (const u16*)0;
  #pragma unroll
  for (int ni=0; ni<16; ni++){
    int n = ni*16 + fm;
    float bb = 0.0f;
    if (g.cbias) bb = g.cbias[n];
    else if (biasp) bb = b2f(biasp[n]);
    #pragma unroll
    for (int r=0; r<4; r++){
      long long b = arow0 + w*16 + (lane>>4)*4 + r;
      float v = acc[ni][r] * g.scale + bb;
      if (g.relu) v = v > 0.0f ? v : 0.0f;
      Cb[b * (long long)g.ldc + n] = f2b(v);
    }
  }
}

// ---------- fused stages 3+4+5b: hid -> fused -> score, one kernel ----------
struct S34Args {
  const u16* X;    // [z*BD + b*256 + k]
  const u16* CR;   // cross, same layout
  const u16* W1;   // [z*131072 + d*512 + k]
  const u16* W2;   // [z*65536 + o*256 + d]
  const u16* Wc1h; // [d'*512 + 256 + o]
  const u16* b1;   // [z*256 + d]
  const u16* b2;   // [z*256 + o]
  const u16* bc1;  // [256]
  const u16* wc2;  // [256]
  const u16* qctx; // [b*256 + d']
  const float* bc2f;
  float*     scores; // [z*BB + b]
  u16*       F;    // fused out, [z*BD + b*256 + o]
};
__global__ __launch_bounds__(256, 2) void gemm_s345(S34Args a){
  alignas(16) __shared__ u16 lB[256*64];   // 32KB: weight k-tile for all phases
  alignas(16) __shared__ u16 lH[64*256];   // 32KB: hid / fused tile; first 8KB doubles as lA
  u16* lA = lH;

  const int tid  = threadIdx.x;
  const int lane = tid & 63;
  const int w    = tid >> 6;
  const int z    = blockIdx.z;

  const int fm = lane & 15;
  const int fq = lane >> 4;
  const long long arow0 = (long long)blockIdx.x * 64;
  const long long BD = (long long)BB * DD;

  const int sr = lane >> 3;
  const int sq = (lane & 7) ^ sr;

  const u16* Xz  = a.X  + (long long)z * BD;
  const u16* CRz = a.CR + (long long)z * BD;
  const u16* W1z = a.W1 + (long long)z * 131072;
  const u16* W2z = a.W2 + (long long)z * 65536;

  // ---------------- phase A: hid (swapped operands) ----------------
  f32x4 acc[16];
  #pragma unroll
  for (int j=0;j<16;j++)
    #pragma unroll
    for (int r=0;r<4;r++) acc[j][r] = 0.0f;

  for (int k0 = 0; k0 < 512; k0 += 64){
    const u16* At = (k0 < 256) ? (Xz + k0) : (CRz + (k0 - 256));
    const u16* Bt = W1z + k0;
    __syncthreads();
    #pragma unroll
    for (int i=0;i<2;i++){
      int r = i*32 + w*8 + sr;
      async_cp16(At + (arow0 + r) * 256 + sq*8, lA + (i*256 + w*64) * 8);
    }
    #pragma unroll
    for (int i=0;i<8;i++){
      int r = i*32 + w*8 + sr;
      async_cp16(Bt + (long long)r * 512 + sq*8, lB + (i*256 + w*64) * 8);
    }
    __syncthreads();
    #pragma unroll
    for (int kk = 0; kk < 64; kk += 32){
      const int qf = (kk >> 3) + fq;
      int ra = w*16 + fm;
      s16x8 af = *(const s16x8*)(lA + (ra*8 + (qf ^ (ra & 7))) * 8);
      #pragma unroll
      for (int ni=0; ni<16; ni++){
        int r = ni*16 + fm;
        s16x8 bfr = *(const s16x8*)(lB + (r*8 + (qf ^ (r & 7))) * 8);
        // swapped: lane holds hid[d = ni*16+fq*4+rr][b = w*16+fm]
        acc[ni] = __builtin_amdgcn_mfma_f32_16x16x32_bf16(bfr, af, acc[ni], 0, 0, 0);
      }
    }
  }

  __syncthreads();

  // pack relu(hid + b1) -> lH[b][d], swizzled chunks (16B chunk c; c low3 ^= b&7)
  {
    const int b = w*16 + fm;
    #pragma unroll
    for (int ni=0; ni<16; ni++){
      s16x4 b1v = *(const s16x4*)(a.b1 + (long long)z*256 + ni*16 + fq*4);
      u16x4 pk;
      #pragma unroll
      for (int r=0; r<4; r++){
        float v = acc[ni][r] + b2f((u16)b1v[r]);
        v = v > 0.0f ? v : 0.0f;
        pk[r] = f2b(v);
      }
      const int c = ni*2 + (fq >> 1);              // 16B-chunk index 0..31
      const int csw = (c & ~7) | ((c & 7) ^ (b & 7));
      *(u16x4*)(lH + b*256 + csw*8 + (fq & 1)*4) = pk;
    }
  }

  // ---------------- phase B: fused = hid @ W2^T + b2 (swapped operands) ----------------
  f32x4 acc2[16];
  #pragma unroll
  for (int j=0;j<16;j++)
    #pragma unroll
    for (int r=0;r<4;r++) acc2[j][r] = 0.0f;

  for (int k0 = 0; k0 < 256; k0 += 64){
    const u16* Bt = W2z + k0;
    __syncthreads();
    #pragma unroll
    for (int i=0;i<8;i++){
      int r = i*32 + w*8 + sr;
      async_cp16(Bt + (long long)r * 256 + sq*8, lB + (i*256 + w*64) * 8);
    }
    __syncthreads();
    #pragma unroll
    for (int kk = 0; kk < 64; kk += 32){
      const int ra = w*16 + fm;
      const int qa = ((k0 + kk) >> 3) + fq;        // 0..31 chunk in lH row
      const int qsw = (qa & ~7) | ((qa & 7) ^ (ra & 7));
      s16x8 af = *(const s16x8*)(lH + ra*256 + qsw*8);
      const int qf = (kk >> 3) + fq;               // 0..7 chunk in lB row
      #pragma unroll
      for (int ni=0; ni<16; ni++){
        int r = ni*16 + fm;
        s16x8 bfr = *(const s16x8*)(lB + (r*8 + (qf ^ (r & 7))) * 8);
        // swapped: lane holds fused[o = ni*16+fq*4+rr][b = w*16+fm]
        acc2[ni] = __builtin_amdgcn_mfma_f32_16x16x32_bf16(bfr, af, acc2[ni], 0, 0, 0);
      }
    }
  }

  __syncthreads();

  // fused + b2 -> global (u16x4) AND pack into lH[b][o] (same swizzle as phase A pack)
  {
    const int b = w*16 + fm;
    u16* Fz = a.F + (long long)z * BD;
    #pragma unroll
    for (int ni=0; ni<16; ni++){
      s16x4 b2v = *(const s16x4*)(a.b2 + (long long)z*256 + ni*16 + fq*4);
      u16x4 pk;
      #pragma unroll
      for (int r=0; r<4; r++)
        pk[r] = f2b(acc2[ni][r] + b2f((u16)b2v[r]));
      *(u16x4*)(Fz + (arow0 + b)*256 + ni*16 + fq*4) = pk;
      const int c = ni*2 + (fq >> 1);
      const int csw = (c & ~7) | ((c & 7) ^ (b & 7));
      *(u16x4*)(lH + b*256 + csw*8 + (fq & 1)*4) = pk;
    }
  }

  // ---------------- phase C: ch = fused @ Wc1h^T (standard operands) ----------------
  f32x4 acc3[16];
  #pragma unroll
  for (int j=0;j<16;j++)
    #pragma unroll
    for (int r=0;r<4;r++) acc3[j][r] = 0.0f;

  for (int k0 = 0; k0 < 256; k0 += 64){
    const u16* Bt = a.Wc1h + k0;
    __syncthreads();
    #pragma unroll
    for (int i=0;i<8;i++){
      int r = i*32 + w*8 + sr;
      async_cp16(Bt + (long long)r * 512 + sq*8, lB + (i*256 + w*64) * 8);
    }
    __syncthreads();
    #pragma unroll
    for (int kk = 0; kk < 64; kk += 32){
      const int ra = w*16 + fm;
      const int qa = ((k0 + kk) >> 3) + fq;
      const int qsw = (qa & ~7) | ((qa & 7) ^ (ra & 7));
      s16x8 af = *(const s16x8*)(lH + ra*256 + qsw*8);
      const int qf = (kk >> 3) + fq;
      #pragma unroll
      for (int ni=0; ni<16; ni++){
        int r = ni*16 + fm;
        s16x8 bfr = *(const s16x8*)(lB + (r*8 + (qf ^ (r & 7))) * 8);
        acc3[ni] = __builtin_amdgcn_mfma_f32_16x16x32_bf16(af, bfr, acc3[ni], 0, 0, 0);
      }
    }
  }

  // score epilogue: relu(ch + qctx + bc1) . wc2 -> sigmoid -> scores
  float p[4] = {0.f, 0.f, 0.f, 0.f};
  #pragma unroll
  for (int ni=0; ni<16; ni++){
    int n = ni*16 + fm;
    float bb = b2f(a.bc1[n]);
    float wcv = b2f(a.wc2[n]);
    #pragma unroll
    for (int r=0; r<4; r++){
      long long b = arow0 + w*16 + fq*4 + r;
      float v = acc3[ni][r] + bb + b2f(a.qctx[b*256 + n]);
      v = v > 0.0f ? v : 0.0f;
      p[r] += v * wcv;
    }
  }
  #pragma unroll
  for (int r=0; r<4; r++){
    #pragma unroll
    for (int off=1; off<16; off<<=1) p[r] += __shfl_xor(p[r], off);
  }
  if (fm == 0){
    float bc2v = a.bc2f[0];
    #pragma unroll
    for (int r=0; r<4; r++){
      long long b = arow0 + w*16 + fq*4 + r;
      a.scores[(long long)z*BB + b] = 1.0f / (1.0f + __expf(-(p[r] + bc2v)));
    }
  }
}

// WB[n=(s*256+o)][k=(t*256+d)] = sum_e Wo[s,t,o,e]*Wv[s,t,e,d], zeroed on s==t diagonal.
__global__ __launch_bounds__(256, 2) void build_wb(const float* Wo, const float* Wv, u16* WB){
  alignas(16) __shared__ u16 lA[128*64];
  alignas(16) __shared__ u16 lB[128*64];
  const int tid  = threadIdx.x;
  const int lane = tid & 63;
  const int w    = tid >> 6;
  const int z = blockIdx.z, s = z >> 3, t = z & 7;
  const long long zoff = (long long)z * 65536;

  f32x4 acc[4][4];
  #pragma unroll
  for (int i=0;i<4;i++)
    #pragma unroll
    for (int j=0;j<4;j++)
      #pragma unroll
      for (int r=0;r<4;r++) acc[i][j][r] = 0.0f;

  const int wr = (w >> 1) * 64, wc = (w & 1) * 64;
  const int fm = lane & 15;
  const int fk = (lane >> 4) * 8;

  int srow[4], sq[4];
  #pragma unroll
  for (int i=0;i<4;i++){
    int c = i*256 + tid;
    srow[i] = c >> 3;
    sq[i]   = (c & 7) ^ (srow[i] & 7);
  }

  for (int k0 = 0; k0 < 256; k0 += 64){
    s16x8 va[4], vt[4];
    #pragma unroll
    for (int i=0;i<4;i++){
      long long aidx = zoff + (long long)(blockIdx.x*128 + srow[i]) * 256 + k0 + sq[i]*8;
      va[i] = load8_f32(Wo, aidx);
    }
    #pragma unroll
    for (int j=0;j<4;j++){
      int id = j*256 + tid;
      int e  = id >> 4;
      int dc = (id & 15) * 8;
      long long bidx = zoff + (long long)(k0 + e) * 256 + blockIdx.y*128 + dc;
      vt[j] = load8_f32(Wv, bidx);
    }
    __syncthreads();
    #pragma unroll
    for (int i=0;i<4;i++){
      int c = i*256 + tid;
      *(s16x8*)(lA + c*8) = va[i];
    }
    #pragma unroll
    for (int j=0;j<4;j++){
      int id = j*256 + tid;
      int e  = id >> 4;
      int dc = (id & 15) * 8;
      #pragma unroll
      for (int u=0; u<8; u++){
        int d = dc + u;
        lB[(d*8 + ((e>>3) ^ (d & 7)))*8 + (e & 7)] = (u16)vt[j][u];
      }
    }
    __syncthreads();
    #pragma unroll
    for (int kk = 0; kk < 64; kk += 32){
      s16x8 af[4], bfr[4];
      const int qf = (kk + fk) >> 3;
      #pragma unroll
      for (int mi=0; mi<4; mi++){
        int r = wr + mi*16 + fm;
        af[mi] = *(const s16x8*)(lA + (r*8 + (qf ^ (r & 7))) * 8);
      }
      #pragma unroll
      for (int ni=0; ni<4; ni++){
        int r = wc + ni*16 + fm;
        bfr[ni] = *(const s16x8*)(lB + (r*8 + (qf ^ (r & 7))) * 8);
      }
      #pragma unroll
      for (int mi=0; mi<4; mi++)
        #pragma unroll
        for (int ni=0; ni<4; ni++)
          acc[mi][ni] = __builtin_amdgcn_mfma_f32_16x16x32_bf16(af[mi], bfr[ni], acc[mi][ni], 0, 0, 0);
    }
    __syncthreads();
  }
  const int diag = (s == t);
  #pragma unroll
  for (int mi=0; mi<4; mi++){
    #pragma unroll
    for (int ni=0; ni<4; ni++){
      int d = blockIdx.y*128 + wc + ni*16 + fm;
      #pragma unroll
      for (int r=0; r<4; r++){
        int o = blockIdx.x*128 + wr + mi*16 + (lane>>4)*4 + r;
        float v = diag ? 0.0f : acc[mi][ni][r];
        WB[(long long)(s*256 + o) * 2048 + t*256 + d] = f2b(v);
      }
    }
  }
}

// cb[s*256+o] += (1/7)*( dot(bv[s,t,:], Wo[s,t,o,:]) + bo[s,t,o] )  for t != s. cb zeroed by convert.
__global__ __launch_bounds__(256) void cb_kernel(const float* bv, const float* Wo, const float* bo, float* cb){
  int z = blockIdx.x, s = z >> 3, t = z & 7;
  if (s == t) return;
  int lane = threadIdx.x & 63, w = threadIdx.x >> 6;
  float4 bvv = *(const float4*)(bv + (long long)z*256 + lane*4);
  #pragma unroll
  for (int i=0; i<16; i++){
    int row = blockIdx.y*64 + w*16 + i;
    float4 wv4 = *(const float4*)(Wo + (long long)z*65536 + (long long)row*256 + lane*4);
    float p = wv4.x*bvv.x + wv4.y*bvv.y + wv4.z*bvv.z + wv4.w*bvv.w;
    #pragma unroll
    for (int off=32; off>0; off>>=1) p += __shfl_xor(p, off);
    if (lane == 0)
      atomicAdd(&cb[s*256 + row], (p + bo[(long long)z*256 + row]) * (1.0f/7.0f));
  }
}

// out[b,:] = (1/8) sum_m fused[m,b,:] * scores[m,b]
__global__ __launch_bounds__(256) void final_gate(const u16* fused, const float* scores, float* out){
  int b = blockIdx.x;
  int tid = threadIdx.x;
  float sc[8];
  #pragma unroll
  for (int m=0; m<8; m++) sc[m] = scores[(long long)m*BB + b];
  float acc = 0.0f;
  #pragma unroll
  for (int m=0; m<8; m++)
    acc += b2f(fused[((long long)m*BB + b)*256 + tid]) * sc[m];
  out[(long long)b*256 + tid] = acc * 0.125f;
}

extern "C" void kernel_launch(void* const* d_in, const int* in_sizes, int n_in,
                              void* d_out, int out_size, void* d_ws, size_t ws_size,
                              hipStream_t stream){
  const float* x   = (const float*)d_in[0];
  const float* q   = (const float*)d_in[1];
  const float* Wv  = (const float*)d_in[2];
  const float* bv  = (const float*)d_in[3];
  const float* Wo  = (const float*)d_in[4];
  const float* bo  = (const float*)d_in[5];
  const float* W1  = (const float*)d_in[6];
  const float* b1  = (const float*)d_in[7];
  const float* W2  = (const float*)d_in[8];
  const float* b2  = (const float*)d_in[9];
  const float* Wc1 = (const float*)d_in[10];
  const float* bc1 = (const float*)d_in[11];
  const float* wc2 = (const float*)d_in[12];
  const float* bc2 = (const float*)d_in[13];

  char* ws = (char*)d_ws;
  u16*   xb    = (u16*)(ws + 0LL);            // 32MB; dead after s345 phase A -> fused
  u16*   qb    = (u16*)(ws + 33554432LL);     // 4MB
  u16*   cross = (u16*)(ws + 37748736LL);     // 32MB
  u16*   WB    = (u16*)(ws + 104857600LL);    // 8MB; dead after stage2 -> qctx+scores
  u16*   W1b   = (u16*)(ws + 113246208LL);    // 2MB
  u16*   W2b   = (u16*)(ws + 115343360LL);    // 1MB
  u16*   Wc1b  = (u16*)(ws + 116391936LL);    // 256KB
  u16*   b1b   = (u16*)(ws + 116654080LL);    // 4KB
  u16*   b2b   = (u16*)(ws + 116658176LL);    // 4KB
  u16*   bc1b  = (u16*)(ws + 116662272LL);    // 512B
  u16*   wc2b  = (u16*)(ws + 116662784LL);    // 512B
  float* bc2f  = (float*)(ws + 116663296LL);  // 64B (fp32 copy)
  float* cb    = (float*)(ws + 116663424LL);  // 8KB
  u16*   fused = xb;
  u16*   qctx  = WB;                                   // 4MB (dead WB)
  float* scores = (float*)(ws + 104857600LL + 4194304LL); // 256KB (dead WB upper half)

  ConvArgs ca{};
  ca.src[0]=x;   ca.dst[0]=xb;   ca.n[0]=MMOD*BB*DD;
  ca.src[1]=q;   ca.dst[1]=qb;   ca.n[1]=BB*DD;
  ca.src[2]=W1;  ca.dst[2]=W1b;  ca.n[2]=MMOD*DD*2*DD;
  ca.src[3]=W2;  ca.dst[3]=W2b;  ca.n[3]=MMOD*DD*DD;
  ca.src[4]=Wc1; ca.dst[4]=Wc1b; ca.n[4]=DD*2*DD;
  ca.src[5]=b1;  ca.dst[5]=b1b;  ca.n[5]=MMOD*DD;
  ca.src[6]=b2;  ca.dst[6]=b2b;  ca.n[6]=MMOD*DD;
  ca.src[7]=bc1; ca.dst[7]=bc1b; ca.n[7]=DD;
  ca.src[8]=wc2; ca.dst[8]=wc2b; ca.n[8]=DD;
  ca.src[9]=bc2; ca.dst[9]=bc1b; ca.n[9]=0;   // unused slot
  ca.cbz = cb; ca.bc2 = bc2; ca.bc2f = bc2f;
  convert_kernel<<<1024, 256, 0, stream>>>(ca);

  build_wb<<<dim3(2,2,64), 256, 0, stream>>>(Wo, Wv, WB);
  cb_kernel<<<dim3(64,4), 256, 0, stream>>>(bv, Wo, bo, cb);

  const long long BD = (long long)BB * DD;

  // Stage 2 (256^2 8-phase): cross[s,b,o] = (1/7) sum_k xb'[b,k] * WB[(s,o),k] + cb
  GArgs g2{};
  g2.A = xb; g2.a_z = 0; g2.a_piece = BD; g2.lda = 256; g2.A2 = 0; g2.a2_z = 0;
  g2.B = WB; g2.b_z = 0; g2.ldb = 2048;
  g2.C = cross; g2.c_z = 0; g2.c_npiece = BD; g2.ldc = 256;
  g2.bias = 0; g2.bias_z = 0; g2.cbias = cb;
  g2.scale = 1.0f/7.0f; g2.K = 2048; g2.relu = 0;
  gemm_8ph<<<dim3(32,8,1), 512, 0, stream>>>(g2);

  // Stage 5a (thin): qctx = qb @ Wc1[:, :256]^T   (into dead WB)
  GArgs g5a{};
  g5a.A = qb; g5a.a_z = 0; g5a.a_piece = 0; g5a.lda = 256; g5a.A2 = 0; g5a.a2_z = 0;
  g5a.B = Wc1b; g5a.b_z = 0; g5a.ldb = 512;
  g5a.C = qctx; g5a.c_z = 0; g5a.c_npiece = 0; g5a.ldc = 256;
  g5a.bias = 0; g5a.bias_z = 0; g5a.cbias = 0;
  g5a.scale = 1.0f; g5a.K = 256; g5a.relu = 0;
  gemm_thin<<<dim3(128,1,1), 256, 0, stream>>>(g5a);

  // Stages 3+4+5b fused
  S34Args s34{};
  s34.X = xb; s34.CR = cross; s34.W1 = W1b; s34.W2 = W2b; s34.Wc1h = Wc1b + 256;
  s34.b1 = b1b; s34.b2 = b2b; s34.bc1 = bc1b; s34.wc2 = wc2b;
  s34.qctx = qctx; s34.bc2f = bc2f; s34.scores = scores; s34.F = fused;
  gemm_s345<<<dim3(128,1,8), 256, 0, stream>>>(s34);

  final_gate<<<dim3(BB), 256, 0, stream>>>(fused, scores, (float*)d_out);

  (void)in_sizes; (void)n_in; (void)out_size; (void)ws_size;
}

// Round 6
// 316.763 us; speedup vs baseline: 1.1510x; 1.0359x over previous
//
#include <hip/hip_runtime.h>

#define MMOD 8
#define BB 8192
#define DD 256

typedef unsigned short u16;
typedef __attribute__((ext_vector_type(8))) short s16x8;
typedef __attribute__((ext_vector_type(4))) float f32x4;
typedef __attribute__((ext_vector_type(8))) unsigned short u16x8;
typedef __attribute__((ext_vector_type(4))) unsigned short u16x4;
typedef __attribute__((ext_vector_type(4))) short s16x4;

typedef __attribute__((address_space(3))) unsigned short lds_u16;
typedef __attribute__((address_space(1))) const unsigned short gl_u16;

__device__ __forceinline__ float b2f(u16 u){ union{unsigned i; float f;} x; x.i=((unsigned)u)<<16; return x.f; }
__device__ __forceinline__ u16 f2b(float f){ union{float f; unsigned i;} x; x.f=f; unsigned r = x.i + 0x7FFF + ((x.i>>16)&1u); return (u16)(r>>16); }

// async global->LDS: per-lane src address, LDS dest = wave-uniform base + lane*16B
__device__ __forceinline__ void async_cp16(const u16* g, u16* l){
  __builtin_amdgcn_global_load_lds((gl_u16*)g, (lds_u16*)l, 16, 0, 0);
}

__device__ __forceinline__ s16x8 load8_f32(const float* p, long long idx){
  float4 lo = *(const float4*)(p + idx);
  float4 hi = *(const float4*)(p + idx + 4);
  s16x8 r;
  r[0]=(short)f2b(lo.x); r[1]=(short)f2b(lo.y); r[2]=(short)f2b(lo.z); r[3]=(short)f2b(lo.w);
  r[4]=(short)f2b(hi.x); r[5]=(short)f2b(hi.y); r[6]=(short)f2b(hi.z); r[7]=(short)f2b(hi.w);
  return r;
}

// ---------------- prep: convert || build_wb || cb, one dispatch ----------------
// blocks [0,1024): fp32->bf16 conversion (+ bc2 copy)
// blocks [1024,1280): build_wb  (WB[(s,o),(t,d)] = sum_e Wo[s,t,o,e]*Wv[s,t,e,d]; diag skipped)
// blocks [1280,1312): cb (atomic-free: one block per (s, 64-row chunk), sums over t!=s)
struct PrepArgs {
  const float* src[10];
  u16*         dst[10];
  int          n[10];
  const float* bc2;
  float*       bc2f;
  const float* Wo;
  const float* Wv;
  u16*         WB;
  const float* bv;
  const float* bo;
  float*       cb;
};
__global__ __launch_bounds__(256, 3) void prep_kernel(PrepArgs a){
  alignas(16) __shared__ u16 lA[128*64];
  alignas(16) __shared__ u16 lB[128*64];
  const int tid = threadIdx.x;
  const unsigned bxg = blockIdx.x;

  if (bxg < 1024){
    // ---------------- convert ----------------
    const long long stride = 1024LL * 256LL;
    const long long base   = (long long)bxg * 256 + tid;
    if (base == 0) a.bc2f[0] = a.bc2[0];
    for (int s = 0; s < 10; s++){
      const int n  = a.n[s];
      const int n8 = n >> 3;
      const float* sp = a.src[s];
      u16* dst = a.dst[s];
      for (long long i = base; i < n8; i += stride){
        float4 lo = ((const float4*)sp)[i*2];
        float4 hi = ((const float4*)sp)[i*2+1];
        u16x8 p;
        p[0]=f2b(lo.x); p[1]=f2b(lo.y); p[2]=f2b(lo.z); p[3]=f2b(lo.w);
        p[4]=f2b(hi.x); p[5]=f2b(hi.y); p[6]=f2b(hi.z); p[7]=f2b(hi.w);
        *(u16x8*)(dst + (i<<3)) = p;
      }
      for (long long i = ((long long)n8<<3) + base; i < n; i += stride)
        dst[i] = f2b(sp[i]);
    }
  } else if (bxg < 1280){
    // ---------------- build_wb ----------------
    const int f  = (int)bxg - 1024;
    const int bwx = f & 1, bwy = (f >> 1) & 1, z = f >> 2;
    const int s = z >> 3, t = z & 7;
    if (s == t) return;   // diagonal tiles are never read by stage 2 (k-tile skip)
    const long long zoff = (long long)z * 65536;
    const int lane = tid & 63;
    const int w    = tid >> 6;

    f32x4 acc[4][4];
    #pragma unroll
    for (int i=0;i<4;i++)
      #pragma unroll
      for (int j=0;j<4;j++)
        #pragma unroll
        for (int r=0;r<4;r++) acc[i][j][r] = 0.0f;

    const int wr = (w >> 1) * 64, wc = (w & 1) * 64;
    const int fm = lane & 15;
    const int fk = (lane >> 4) * 8;

    int srow[4], sq[4];
    #pragma unroll
    for (int i=0;i<4;i++){
      int c = i*256 + tid;
      srow[i] = c >> 3;
      sq[i]   = (c & 7) ^ (srow[i] & 7);
    }

    for (int k0 = 0; k0 < 256; k0 += 64){
      s16x8 va[4], vt[4];
      #pragma unroll
      for (int i=0;i<4;i++){
        long long aidx = zoff + (long long)(bwx*128 + srow[i]) * 256 + k0 + sq[i]*8;
        va[i] = load8_f32(a.Wo, aidx);
      }
      #pragma unroll
      for (int j=0;j<4;j++){
        int id = j*256 + tid;
        int e  = id >> 4;
        int dc = (id & 15) * 8;
        long long bidx = zoff + (long long)(k0 + e) * 256 + bwy*128 + dc;
        vt[j] = load8_f32(a.Wv, bidx);
      }
      __syncthreads();
      #pragma unroll
      for (int i=0;i<4;i++){
        int c = i*256 + tid;
        *(s16x8*)(lA + c*8) = va[i];
      }
      #pragma unroll
      for (int j=0;j<4;j++){
        int id = j*256 + tid;
        int e  = id >> 4;
        int dc = (id & 15) * 8;
        #pragma unroll
        for (int u=0; u<8; u++){
          int d = dc + u;
          lB[(d*8 + ((e>>3) ^ (d & 7)))*8 + (e & 7)] = (u16)vt[j][u];
        }
      }
      __syncthreads();
      #pragma unroll
      for (int kk = 0; kk < 64; kk += 32){
        s16x8 af[4], bfr[4];
        const int qf = (kk + fk) >> 3;
        #pragma unroll
        for (int mi=0; mi<4; mi++){
          int r = wr + mi*16 + fm;
          af[mi] = *(const s16x8*)(lA + (r*8 + (qf ^ (r & 7))) * 8);
        }
        #pragma unroll
        for (int ni=0; ni<4; ni++){
          int r = wc + ni*16 + fm;
          bfr[ni] = *(const s16x8*)(lB + (r*8 + (qf ^ (r & 7))) * 8);
        }
        #pragma unroll
        for (int mi=0; mi<4; mi++)
          #pragma unroll
          for (int ni=0; ni<4; ni++)
            acc[mi][ni] = __builtin_amdgcn_mfma_f32_16x16x32_bf16(af[mi], bfr[ni], acc[mi][ni], 0, 0, 0);
      }
      __syncthreads();
    }
    #pragma unroll
    for (int mi=0; mi<4; mi++){
      #pragma unroll
      for (int ni=0; ni<4; ni++){
        int d = bwy*128 + wc + ni*16 + fm;
        #pragma unroll
        for (int r=0; r<4; r++){
          int o = bwx*128 + wr + mi*16 + (lane>>4)*4 + r;
          a.WB[(long long)(s*256 + o) * 2048 + t*256 + d] = f2b(acc[mi][ni][r]);
        }
      }
    }
  } else {
    // ---------------- cb (atomic-free) ----------------
    const int f = (int)bxg - 1280;
    const int s = f >> 2, chunk = f & 3;
    const int lane = tid & 63, wv = tid >> 6;
    float pp[16];
    #pragma unroll
    for (int i=0;i<16;i++) pp[i] = 0.0f;
    #pragma unroll
    for (int t2 = 0; t2 < 8; t2++){
      if (t2 == s) continue;
      const int z = s*8 + t2;
      float4 bvv = *(const float4*)(a.bv + (long long)z*256 + lane*4);
      #pragma unroll
      for (int i=0;i<16;i++){
        int row = chunk*64 + wv*16 + i;
        float4 w4 = *(const float4*)(a.Wo + (long long)z*65536 + (long long)row*256 + lane*4);
        pp[i] += w4.x*bvv.x + w4.y*bvv.y + w4.z*bvv.z + w4.w*bvv.w;
      }
    }
    #pragma unroll
    for (int i=0;i<16;i++){
      #pragma unroll
      for (int off=32; off>0; off>>=1) pp[i] += __shfl_xor(pp[i], off);
    }
    if (lane == 0){
      #pragma unroll
      for (int i=0;i<16;i++){
        int row = chunk*64 + wv*16 + i;
        float bos = 0.0f;
        #pragma unroll
        for (int t2=0; t2<8; t2++){
          if (t2 == s) continue;
          bos += a.bo[(long long)(s*8+t2)*256 + row];
        }
        a.cb[s*256 + row] = (pp[i] + bos) * (1.0f/7.0f);
      }
    }
  }
}

struct GArgs {
  const u16* A;  long long a_z; long long a_piece; int lda;  // A + z*a_z + (k>>8)*a_piece + b*lda + (k&255)
  const u16* A2; long long a2_z;                             // if non-null: base for k>=256
  const u16* B;  long long b_z; int ldb;                     // B + z*b_z + n*ldb + k   ([N,K] layout)
  u16*       C;  long long c_z; long long c_npiece; int ldc; // C + z*c_z + (n>>8)*c_npiece + b*ldc + (n&255)
  const u16* bias; long long bias_z;   // bf16 bias[n] (per z), optional
  const float* cbias;                  // fp32 bias[global n], optional
  float scale;
  int K;
  int relu;
};

// ---------- 256x256 8-phase pipelined GEMM, STAGE-2 SPECIALIZED ----------
// Round-1 proven schedule (reads-before-barrier, 12/4/4/4, two raw s_barriers/phase,
// vmcnt(4) once per K-tile), round-5 VALU-free addressing, PLUS:
//  - diagonal k-tile skip: block ny never multiplies WB's zeroed t==ny tiles.
//    Logical tiles j=0..27 map to physical kt = j + (j >= 4*ny ? 4 : 0).
//    Products removed are exact 0.0 -> numerics identical, 12.5% less work.
__global__ __launch_bounds__(512, 2) void gemm_8ph(GArgs g){
  alignas(16) __shared__ u16 L[65536]; // [buf(2)][A/B(2)][256 rows * 64 cols]
  const int tid  = threadIdx.x;
  const int lane = tid & 63;
  const int w    = tid >> 6;        // 0..7

  const int wr  = w >> 2;           // 0..1 : 128-row block
  const int wcn = w & 3;            // 0..3 : 64-col block
  const int fm  = lane & 15;
  const int fq  = lane >> 4;        // 0..3

  const long long arow0 = (long long)blockIdx.x * 256;
  const long long nrow0 = (long long)blockIdx.y * 256;
  const int ny4 = (int)blockIdx.y * 4;   // first diagonal k-tile index

  // staging geometry: thread covers rows r0 (0..63 of half) and r1 = r0+64
  const int r0  = tid >> 3;
  const int r1  = r0 + 64;
  const int cs  = tid & 7;
  const int gc0 = cs ^ (r0 & 7);    // swizzle: LDS(r,cs) = global(r, cs^(r&7))
  const int gc1 = cs ^ (r1 & 7);
  const int ldst0 = (w * 64) * 8;        // wave-uniform LDS base (u16 units)
  const int ldst1 = (512 + w * 64) * 8;

  const u16* Az = g.A;
  const u16* Bz = g.B;

  // per-lane global offsets (u16 units), loop-invariant
  const long long gA0 = (arow0 + r0) * 256  + gc0 * 8;
  const long long gA1 = (arow0 + r1) * 256  + gc1 * 8;
  const long long gB0 = (nrow0 + r0) * 2048 + gc0 * 8;
  const long long gB1 = (nrow0 + r1) * 2048 + gc1 * 8;

#define MAPK(j) ((((j) >= ny4) ? (j) + 4 : (j)) << 6)

#define STAGE_A8(c, k0s, h) do{ \
    const u16* gb_ = Az + (long long)((k0s) >> 8) * 2097152LL + ((k0s) & 255) + (long long)(h) * 32768LL; \
    u16* lb_ = L + ((c) * 2 + 0) * 16384 + (h) * 8192; \
    async_cp16(gb_ + gA0, lb_ + ldst0); \
    async_cp16(gb_ + gA1, lb_ + ldst1); \
  }while(0)
#define STAGE_B8(c, k0s, h) do{ \
    const u16* gb_ = Bz + (k0s) + (long long)(h) * 262144LL; \
    u16* lb_ = L + ((c) * 2 + 1) * 16384 + (h) * 8192; \
    async_cp16(gb_ + gB0, lb_ + ldst0); \
    async_cp16(gb_ + gB1, lb_ + ldst1); \
  }while(0)

  f32x4 acc[8][4];
  #pragma unroll
  for (int i=0;i<8;i++)
    #pragma unroll
    for (int j=0;j<4;j++)
      #pragma unroll
      for (int r=0;r<4;r++) acc[i][j][r] = 0.0f;

  // prologue: A(0), B(0) -> buf0; B(1) -> buf1 (leave B(1)'s 4 loads in flight)
  STAGE_A8(0, MAPK(0), 0);  STAGE_A8(0, MAPK(0), 1);
  STAGE_B8(0, MAPK(0), 0);  STAGE_B8(0, MAPK(0), 1);
  STAGE_B8(1, MAPK(1), 0);  STAGE_B8(1, MAPK(1), 1);
  asm volatile("s_waitcnt vmcnt(4)" ::: "memory");
  __builtin_amdgcn_s_barrier();

#define TILE8(cc, k0n1, k0n2, v1, v2) do{ \
    const u16* lA_ = L + ((cc) * 2 + 0) * 16384; \
    const u16* lB_ = L + ((cc) * 2 + 1) * 16384; \
    s16x8 bf[4][2]; \
    _Pragma("unroll") \
    for (int q = 0; q < 4; ++q){ \
      if (q == 0 && (v1)) STAGE_A8((cc) ^ 1, (k0n1), 0); \
      if (q == 1 && (v1)) STAGE_A8((cc) ^ 1, (k0n1), 1); \
      if (q == 2 && (v2)) STAGE_B8((cc), (k0n2), 0); \
      if (q == 3 && (v2)) STAGE_B8((cc), (k0n2), 1); \
      if (q == 0){ \
        _Pragma("unroll") \
        for (int ni = 0; ni < 4; ni++){ \
          const int R = wcn * 64 + ni * 16 + fm; \
          _Pragma("unroll") \
          for (int kk = 0; kk < 2; kk++){ \
            const int qf = kk * 4 + fq; \
            bf[ni][kk] = *(const s16x8*)(lB_ + R * 64 + ((qf ^ (R & 7)) << 3)); \
          } \
        } \
      } \
      s16x8 af[2][2]; \
      _Pragma("unroll") \
      for (int j = 0; j < 2; j++){ \
        const int R = wr * 128 + (q * 2 + j) * 16 + fm; \
        _Pragma("unroll") \
        for (int kk = 0; kk < 2; kk++){ \
          const int qf = kk * 4 + fq; \
          af[j][kk] = *(const s16x8*)(lA_ + R * 64 + ((qf ^ (R & 7)) << 3)); \
        } \
      } \
      __builtin_amdgcn_s_barrier(); \
      __builtin_amdgcn_s_setprio(1); \
      _Pragma("unroll") \
      for (int kk = 0; kk < 2; kk++) \
        _Pragma("unroll") \
        for (int j = 0; j < 2; j++) \
          _Pragma("unroll") \
          for (int ni = 0; ni < 4; ni++) \
            acc[q*2+j][ni] = __builtin_amdgcn_mfma_f32_16x16x32_bf16(af[j][kk], bf[ni][kk], acc[q*2+j][ni], 0, 0, 0); \
      __builtin_amdgcn_s_setprio(0); \
      if (q == 3){ \
        if (v2)      asm volatile("s_waitcnt vmcnt(4)" ::: "memory"); \
        else if (v1) asm volatile("s_waitcnt vmcnt(0)" ::: "memory"); \
      } \
      __builtin_amdgcn_s_barrier(); \
    } \
  }while(0)

  #pragma unroll 1
  for (int j = 0; j < 28; j += 2){
    TILE8(0, MAPK(j+1), MAPK(j+2), (j+1) < 28, (j+2) < 28);
    TILE8(1, MAPK(j+2), MAPK(j+3), (j+2) < 28, (j+3) < 28);
  }

  u16* Cb = g.C;
  #pragma unroll
  for (int mi = 0; mi < 8; mi++){
    #pragma unroll
    for (int ni = 0; ni < 4; ni++){
      const int n = (int)nrow0 + wcn * 64 + ni * 16 + fm;
      float bb = g.cbias ? g.cbias[n] : 0.0f;
      const long long cn = ((long long)(n >> 8)) * 2097152LL + (n & 255);
      #pragma unroll
      for (int r = 0; r < 4; r++){
        const long long b = arow0 + wr * 128 + mi * 16 + fq * 4 + r;
        float v = acc[mi][ni][r] * g.scale + bb;
        Cb[cn + b * 256] = f2b(v);
      }
    }
  }
#undef STAGE_A8
#undef STAGE_B8
#undef TILE8
#undef MAPK
}

// ---------- thin full-N tile: 64 rows x 256 cols, BK=64 ----------
__global__ __launch_bounds__(256, 4) void gemm_thin(GArgs g){
  alignas(16) __shared__ u16 lA[64*64];
  alignas(16) __shared__ u16 lB[256*64];
  const int tid  = threadIdx.x;
  const int lane = tid & 63;
  const int w    = tid >> 6;
  const int z    = blockIdx.z;

  const u16* Bbase = g.B + (long long)z * g.b_z;

  f32x4 acc[16];
  #pragma unroll
  for (int j=0;j<16;j++)
    #pragma unroll
    for (int r=0;r<4;r++) acc[j][r] = 0.0f;

  const int fm = lane & 15;
  const int fk = (lane >> 4) * 8;
  const long long arow0 = (long long)blockIdx.x * 64;

  const int sr = lane >> 3;
  const int sq = (lane & 7) ^ sr;

  for (int k0 = 0; k0 < g.K; k0 += 64){
    const u16* Abase0 = (g.A2 && k0 >= 256) ? (g.A2 + (long long)z * g.a2_z)
                                            : (g.A  + (long long)z * g.a_z);
    const u16* At = Abase0 + (long long)(k0 >> 8) * g.a_piece + (k0 & 255);
    const u16* Bt = Bbase + k0;
    __syncthreads();
    #pragma unroll
    for (int i=0;i<2;i++){
      int r = i*32 + w*8 + sr;
      async_cp16(At + (arow0 + r) * (long long)g.lda + sq*8, lA + (i*256 + w*64) * 8);
    }
    #pragma unroll
    for (int i=0;i<8;i++){
      int r = i*32 + w*8 + sr;
      async_cp16(Bt + (long long)r * g.ldb + sq*8, lB + (i*256 + w*64) * 8);
    }
    __syncthreads();
    #pragma unroll
    for (int kk = 0; kk < 64; kk += 32){
      const int qf = (kk + fk) >> 3;
      int ra = w*16 + fm;
      s16x8 af = *(const s16x8*)(lA + (ra*8 + (qf ^ (ra & 7))) * 8);
      #pragma unroll
      for (int ni=0; ni<16; ni++){
        int r = ni*16 + fm;
        s16x8 bfr = *(const s16x8*)(lB + (r*8 + (qf ^ (r & 7))) * 8);
        acc[ni] = __builtin_amdgcn_mfma_f32_16x16x32_bf16(af, bfr, acc[ni], 0, 0, 0);
      }
    }
  }

  u16* Cb = g.C + (long long)z * g.c_z;
  const u16* biasp = g.bias ? g.bias + (long long)z * g.bias_z : (const u16*)0;
  #pragma unroll
  for (int ni=0; ni<16; ni++){
    int n = ni*16 + fm;
    float bb = 0.0f;
    if (g.cbias) bb = g.cbias[n];
    else if (biasp) bb = b2f(biasp[n]);
    #pragma unroll
    for (int r=0; r<4; r++){
      long long b = arow0 + w*16 + (lane>>4)*4 + r;
      float v = acc[ni][r] * g.scale + bb;
      if (g.relu) v = v > 0.0f ? v : 0.0f;
      Cb[b * (long long)g.ldc + n] = f2b(v);
    }
  }
}

// ---------- fused stages 3+4+5b: hid -> fused -> score, one kernel ----------
struct S34Args {
  const u16* X;    // [z*BD + b*256 + k]
  const u16* CR;   // cross, same layout
  const u16* W1;   // [z*131072 + d*512 + k]
  const u16* W2;   // [z*65536 + o*256 + d]
  const u16* Wc1h; // [d'*512 + 256 + o]
  const u16* b1;   // [z*256 + d]
  const u16* b2;   // [z*256 + o]
  const u16* bc1;  // [256]
  const u16* wc2;  // [256]
  const u16* qctx; // [b*256 + d']
  const float* bc2f;
  float*     scores; // [z*BB + b]
  u16*       F;    // fused out, [z*BD + b*256 + o]
};
__global__ __launch_bounds__(256, 2) void gemm_s345(S34Args a){
  alignas(16) __shared__ u16 lB[256*64];   // 32KB: weight k-tile for all phases
  alignas(16) __shared__ u16 lH[64*256];   // 32KB: hid / fused tile; first 8KB doubles as lA
  u16* lA = lH;

  const int tid  = threadIdx.x;
  const int lane = tid & 63;
  const int w    = tid >> 6;
  const int z    = blockIdx.z;

  const int fm = lane & 15;
  const int fq = lane >> 4;
  const long long arow0 = (long long)blockIdx.x * 64;
  const long long BD = (long long)BB * DD;

  const int sr = lane >> 3;
  const int sq = (lane & 7) ^ sr;

  const u16* Xz  = a.X  + (long long)z * BD;
  const u16* CRz = a.CR + (long long)z * BD;
  const u16* W1z = a.W1 + (long long)z * 131072;
  const u16* W2z = a.W2 + (long long)z * 65536;

  // ---------------- phase A: hid (swapped operands) ----------------
  f32x4 acc[16];
  #pragma unroll
  for (int j=0;j<16;j++)
    #pragma unroll
    for (int r=0;r<4;r++) acc[j][r] = 0.0f;

  for (int k0 = 0; k0 < 512; k0 += 64){
    const u16* At = (k0 < 256) ? (Xz + k0) : (CRz + (k0 - 256));
    const u16* Bt = W1z + k0;
    __syncthreads();
    #pragma unroll
    for (int i=0;i<2;i++){
      int r = i*32 + w*8 + sr;
      async_cp16(At + (arow0 + r) * 256 + sq*8, lA + (i*256 + w*64) * 8);
    }
    #pragma unroll
    for (int i=0;i<8;i++){
      int r = i*32 + w*8 + sr;
      async_cp16(Bt + (long long)r * 512 + sq*8, lB + (i*256 + w*64) * 8);
    }
    __syncthreads();
    #pragma unroll
    for (int kk = 0; kk < 64; kk += 32){
      const int qf = (kk >> 3) + fq;
      int ra = w*16 + fm;
      s16x8 af = *(const s16x8*)(lA + (ra*8 + (qf ^ (ra & 7))) * 8);
      #pragma unroll
      for (int ni=0; ni<16; ni++){
        int r = ni*16 + fm;
        s16x8 bfr = *(const s16x8*)(lB + (r*8 + (qf ^ (r & 7))) * 8);
        // swapped: lane holds hid[d = ni*16+fq*4+rr][b = w*16+fm]
        acc[ni] = __builtin_amdgcn_mfma_f32_16x16x32_bf16(bfr, af, acc[ni], 0, 0, 0);
      }
    }
  }

  __syncthreads();

  // pack relu(hid + b1) -> lH[b][d], swizzled chunks (16B chunk c; c low3 ^= b&7)
  {
    const int b = w*16 + fm;
    #pragma unroll
    for (int ni=0; ni<16; ni++){
      s16x4 b1v = *(const s16x4*)(a.b1 + (long long)z*256 + ni*16 + fq*4);
      u16x4 pk;
      #pragma unroll
      for (int r=0; r<4; r++){
        float v = acc[ni][r] + b2f((u16)b1v[r]);
        v = v > 0.0f ? v : 0.0f;
        pk[r] = f2b(v);
      }
      const int c = ni*2 + (fq >> 1);              // 16B-chunk index 0..31
      const int csw = (c & ~7) | ((c & 7) ^ (b & 7));
      *(u16x4*)(lH + b*256 + csw*8 + (fq & 1)*4) = pk;
    }
  }

  // ---------------- phase B: fused = hid @ W2^T + b2 (swapped operands) ----------------
  f32x4 acc2[16];
  #pragma unroll
  for (int j=0;j<16;j++)
    #pragma unroll
    for (int r=0;r<4;r++) acc2[j][r] = 0.0f;

  for (int k0 = 0; k0 < 256; k0 += 64){
    const u16* Bt = W2z + k0;
    __syncthreads();
    #pragma unroll
    for (int i=0;i<8;i++){
      int r = i*32 + w*8 + sr;
      async_cp16(Bt + (long long)r * 256 + sq*8, lB + (i*256 + w*64) * 8);
    }
    __syncthreads();
    #pragma unroll
    for (int kk = 0; kk < 64; kk += 32){
      const int ra = w*16 + fm;
      const int qa = ((k0 + kk) >> 3) + fq;        // 0..31 chunk in lH row
      const int qsw = (qa & ~7) | ((qa & 7) ^ (ra & 7));
      s16x8 af = *(const s16x8*)(lH + ra*256 + qsw*8);
      const int qf = (kk >> 3) + fq;               // 0..7 chunk in lB row
      #pragma unroll
      for (int ni=0; ni<16; ni++){
        int r = ni*16 + fm;
        s16x8 bfr = *(const s16x8*)(lB + (r*8 + (qf ^ (r & 7))) * 8);
        // swapped: lane holds fused[o = ni*16+fq*4+rr][b = w*16+fm]
        acc2[ni] = __builtin_amdgcn_mfma_f32_16x16x32_bf16(bfr, af, acc2[ni], 0, 0, 0);
      }
    }
  }

  __syncthreads();

  // fused + b2 -> global (u16x4) AND pack into lH[b][o] (same swizzle as phase A pack)
  {
    const int b = w*16 + fm;
    u16* Fz = a.F + (long long)z * BD;
    #pragma unroll
    for (int ni=0; ni<16; ni++){
      s16x4 b2v = *(const s16x4*)(a.b2 + (long long)z*256 + ni*16 + fq*4);
      u16x4 pk;
      #pragma unroll
      for (int r=0; r<4; r++)
        pk[r] = f2b(acc2[ni][r] + b2f((u16)b2v[r]));
      *(u16x4*)(Fz + (arow0 + b)*256 + ni*16 + fq*4) = pk;
      const int c = ni*2 + (fq >> 1);
      const int csw = (c & ~7) | ((c & 7) ^ (b & 7));
      *(u16x4*)(lH + b*256 + csw*8 + (fq & 1)*4) = pk;
    }
  }

  // ---------------- phase C: ch = fused @ Wc1h^T (standard operands) ----------------
  f32x4 acc3[16];
  #pragma unroll
  for (int j=0;j<16;j++)
    #pragma unroll
    for (int r=0;r<4;r++) acc3[j][r] = 0.0f;

  for (int k0 = 0; k0 < 256; k0 += 64){
    const u16* Bt = a.Wc1h + k0;
    __syncthreads();
    #pragma unroll
    for (int i=0;i<8;i++){
      int r = i*32 + w*8 + sr;
      async_cp16(Bt + (long long)r * 512 + sq*8, lB + (i*256 + w*64) * 8);
    }
    __syncthreads();
    #pragma unroll
    for (int kk = 0; kk < 64; kk += 32){
      const int ra = w*16 + fm;
      const int qa = ((k0 + kk) >> 3) + fq;
      const int qsw = (qa & ~7) | ((qa & 7) ^ (ra & 7));
      s16x8 af = *(const s16x8*)(lH + ra*256 + qsw*8);
      const int qf = (kk >> 3) + fq;
      #pragma unroll
      for (int ni=0; ni<16; ni++){
        int r = ni*16 + fm;
        s16x8 bfr = *(const s16x8*)(lB + (r*8 + (qf ^ (r & 7))) * 8);
        acc3[ni] = __builtin_amdgcn_mfma_f32_16x16x32_bf16(af, bfr, acc3[ni], 0, 0, 0);
      }
    }
  }

  // score epilogue: relu(ch + qctx + bc1) . wc2 -> sigmoid -> scores
  float p[4] = {0.f, 0.f, 0.f, 0.f};
  #pragma unroll
  for (int ni=0; ni<16; ni++){
    int n = ni*16 + fm;
    float bb = b2f(a.bc1[n]);
    float wcv = b2f(a.wc2[n]);
    #pragma unroll
    for (int r=0; r<4; r++){
      long long b = arow0 + w*16 + fq*4 + r;
      float v = acc3[ni][r] + bb + b2f(a.qctx[b*256 + n]);
      v = v > 0.0f ? v : 0.0f;
      p[r] += v * wcv;
    }
  }
  #pragma unroll
  for (int r=0; r<4; r++){
    #pragma unroll
    for (int off=1; off<16; off<<=1) p[r] += __shfl_xor(p[r], off);
  }
  if (fm == 0){
    float bc2v = a.bc2f[0];
    #pragma unroll
    for (int r=0; r<4; r++){
      long long b = arow0 + w*16 + fq*4 + r;
      a.scores[(long long)z*BB + b] = 1.0f / (1.0f + __expf(-(p[r] + bc2v)));
    }
  }
}

// out[b,:] = (1/8) sum_m fused[m,b,:] * scores[m,b]   (grid-stride over b)
__global__ __launch_bounds__(256) void final_gate(const u16* fused, const float* scores, float* out){
  const int tid = threadIdx.x;
  for (int b = blockIdx.x; b < BB; b += gridDim.x){
    float acc = 0.0f;
    #pragma unroll
    for (int m=0; m<8; m++)
      acc += b2f(fused[((long long)m*BB + b)*256 + tid]) * scores[(long long)m*BB + b];
    out[(long long)b*256 + tid] = acc * 0.125f;
  }
}

extern "C" void kernel_launch(void* const* d_in, const int* in_sizes, int n_in,
                              void* d_out, int out_size, void* d_ws, size_t ws_size,
                              hipStream_t stream){
  const float* x   = (const float*)d_in[0];
  const float* q   = (const float*)d_in[1];
  const float* Wv  = (const float*)d_in[2];
  const float* bv  = (const float*)d_in[3];
  const float* Wo  = (const float*)d_in[4];
  const float* bo  = (const float*)d_in[5];
  const float* W1  = (const float*)d_in[6];
  const float* b1  = (const float*)d_in[7];
  const float* W2  = (const float*)d_in[8];
  const float* b2  = (const float*)d_in[9];
  const float* Wc1 = (const float*)d_in[10];
  const float* bc1 = (const float*)d_in[11];
  const float* wc2 = (const float*)d_in[12];
  const float* bc2 = (const float*)d_in[13];

  char* ws = (char*)d_ws;
  u16*   xb    = (u16*)(ws + 0LL);            // 32MB; dead after s345 phase A -> fused
  u16*   qb    = (u16*)(ws + 33554432LL);     // 4MB
  u16*   cross = (u16*)(ws + 37748736LL);     // 32MB
  u16*   WB    = (u16*)(ws + 104857600LL);    // 8MB; dead after stage2 -> qctx+scores
  u16*   W1b   = (u16*)(ws + 113246208LL);    // 2MB
  u16*   W2b   = (u16*)(ws + 115343360LL);    // 1MB
  u16*   Wc1b  = (u16*)(ws + 116391936LL);    // 256KB
  u16*   b1b   = (u16*)(ws + 116654080LL);    // 4KB
  u16*   b2b   = (u16*)(ws + 116658176LL);    // 4KB
  u16*   bc1b  = (u16*)(ws + 116662272LL);    // 512B
  u16*   wc2b  = (u16*)(ws + 116662784LL);    // 512B
  float* bc2f  = (float*)(ws + 116663296LL);  // 64B (fp32 copy)
  float* cb    = (float*)(ws + 116663424LL);  // 8KB
  u16*   fused = xb;
  u16*   qctx  = WB;                                   // 4MB (dead WB)
  float* scores = (float*)(ws + 104857600LL + 4194304LL); // 256KB (dead WB upper half)

  PrepArgs pa{};
  pa.src[0]=x;   pa.dst[0]=xb;   pa.n[0]=MMOD*BB*DD;
  pa.src[1]=q;   pa.dst[1]=qb;   pa.n[1]=BB*DD;
  pa.src[2]=W1;  pa.dst[2]=W1b;  pa.n[2]=MMOD*DD*2*DD;
  pa.src[3]=W2;  pa.dst[3]=W2b;  pa.n[3]=MMOD*DD*DD;
  pa.src[4]=Wc1; pa.dst[4]=Wc1b; pa.n[4]=DD*2*DD;
  pa.src[5]=b1;  pa.dst[5]=b1b;  pa.n[5]=MMOD*DD;
  pa.src[6]=b2;  pa.dst[6]=b2b;  pa.n[6]=MMOD*DD;
  pa.src[7]=bc1; pa.dst[7]=bc1b; pa.n[7]=DD;
  pa.src[8]=wc2; pa.dst[8]=wc2b; pa.n[8]=DD;
  pa.src[9]=bc2; pa.dst[9]=bc1b; pa.n[9]=0;   // unused slot
  pa.bc2 = bc2; pa.bc2f = bc2f;
  pa.Wo = Wo; pa.Wv = Wv; pa.WB = WB;
  pa.bv = bv; pa.bo = bo; pa.cb = cb;
  prep_kernel<<<1312, 256, 0, stream>>>(pa);

  const long long BD = (long long)BB * DD;

  // Stage 2 (256^2 8-phase, diag-skip): cross[s,b,o] = (1/7) sum_{k,t!=s} xb'[b,k]*WB[(s,o),k] + cb
  GArgs g2{};
  g2.A = xb; g2.a_z = 0; g2.a_piece = BD; g2.lda = 256; g2.A2 = 0; g2.a2_z = 0;
  g2.B = WB; g2.b_z = 0; g2.ldb = 2048;
  g2.C = cross; g2.c_z = 0; g2.c_npiece = BD; g2.ldc = 256;
  g2.bias = 0; g2.bias_z = 0; g2.cbias = cb;
  g2.scale = 1.0f/7.0f; g2.K = 2048; g2.relu = 0;
  gemm_8ph<<<dim3(32,8,1), 512, 0, stream>>>(g2);

  // Stage 5a (thin): qctx = qb @ Wc1[:, :256]^T   (into dead WB)
  GArgs g5a{};
  g5a.A = qb; g5a.a_z = 0; g5a.a_piece = 0; g5a.lda = 256; g5a.A2 = 0; g5a.a2_z = 0;
  g5a.B = Wc1b; g5a.b_z = 0; g5a.ldb = 512;
  g5a.C = qctx; g5a.c_z = 0; g5a.c_npiece = 0; g5a.ldc = 256;
  g5a.bias = 0; g5a.bias_z = 0; g5a.cbias = 0;
  g5a.scale = 1.0f; g5a.K = 256; g5a.relu = 0;
  gemm_thin<<<dim3(128,1,1), 256, 0, stream>>>(g5a);

  // Stages 3+4+5b fused
  S34Args s34{};
  s34.X = xb; s34.CR = cross; s34.W1 = W1b; s34.W2 = W2b; s34.Wc1h = Wc1b + 256;
  s34.b1 = b1b; s34.b2 = b2b; s34.bc1 = bc1b; s34.wc2 = wc2b;
  s34.qctx = qctx; s34.bc2f = bc2f; s34.scores = scores; s34.F = fused;
  gemm_s345<<<dim3(128,1,8), 256, 0, stream>>>(s34);

  final_gate<<<dim3(1024), 256, 0, stream>>>(fused, scores, (float*)d_out);

  (void)in_sizes; (void)n_in; (void)out_size; (void)ws_size;
}

// Round 7
// 301.034 us; speedup vs baseline: 1.2111x; 1.0523x over previous
//
#include <hip/hip_runtime.h>

#define MMOD 8
#define BB 8192
#define DD 256

typedef unsigned short u16;
typedef __attribute__((ext_vector_type(8))) short s16x8;
typedef __attribute__((ext_vector_type(4))) float f32x4;
typedef __attribute__((ext_vector_type(8))) unsigned short u16x8;
typedef __attribute__((ext_vector_type(4))) unsigned short u16x4;
typedef __attribute__((ext_vector_type(4))) short s16x4;

typedef __attribute__((address_space(3))) unsigned short lds_u16;
typedef __attribute__((address_space(1))) const unsigned short gl_u16;

__device__ __forceinline__ float b2f(u16 u){ union{unsigned i; float f;} x; x.i=((unsigned)u)<<16; return x.f; }
__device__ __forceinline__ u16 f2b(float f){ union{float f; unsigned i;} x; x.f=f; unsigned r = x.i + 0x7FFF + ((x.i>>16)&1u); return (u16)(r>>16); }

// async global->LDS: per-lane src address, LDS dest = wave-uniform base + lane*16B
__device__ __forceinline__ void async_cp16(const u16* g, u16* l){
  __builtin_amdgcn_global_load_lds((gl_u16*)g, (lds_u16*)l, 16, 0, 0);
}

__device__ __forceinline__ s16x8 load8_f32(const float* p, long long idx){
  float4 lo = *(const float4*)(p + idx);
  float4 hi = *(const float4*)(p + idx + 4);
  s16x8 r;
  r[0]=(short)f2b(lo.x); r[1]=(short)f2b(lo.y); r[2]=(short)f2b(lo.z); r[3]=(short)f2b(lo.w);
  r[4]=(short)f2b(hi.x); r[5]=(short)f2b(hi.y); r[6]=(short)f2b(hi.z); r[7]=(short)f2b(hi.w);
  return r;
}

// ---------------- prep: convert || build_wb || cb || qctx, one dispatch ----------------
// blocks [0,1024): fp32->bf16 conversion (+ bc2 copy)
// blocks [1024,1280): build_wb  (WB[(s,o),(t,d)] = sum_e Wo[s,t,o,e]*Wv[s,t,e,d]; diag skipped)
// blocks [1280,1312): cb (atomic-free: one block per (s, 64-row chunk), sums over t!=s)
// blocks [1312,1440): qctx = q @ Wc1[:, :256]^T  (fp32 inputs, inline bf16 conversion)
struct PrepArgs {
  const float* src[10];
  u16*         dst[10];
  int          n[10];
  const float* bc2;
  float*       bc2f;
  const float* Wo;
  const float* Wv;
  u16*         WB;
  const float* bv;
  const float* bo;
  float*       cb;
  const float* q;     // [b][256] fp32
  const float* Wc1f;  // [d'][512] fp32
  u16*         qctx;  // out [b][256] bf16
};
__global__ __launch_bounds__(256, 3) void prep_kernel(PrepArgs a){
  alignas(16) __shared__ u16 lA[128*64];   // 16KB
  alignas(16) __shared__ u16 lB[256*64];   // 32KB
  const int tid = threadIdx.x;
  const unsigned bxg = blockIdx.x;

  if (bxg < 1024){
    // ---------------- convert ----------------
    const long long stride = 1024LL * 256LL;
    const long long base   = (long long)bxg * 256 + tid;
    if (base == 0) a.bc2f[0] = a.bc2[0];
    for (int s = 0; s < 10; s++){
      const int n  = a.n[s];
      const int n8 = n >> 3;
      const float* sp = a.src[s];
      u16* dst = a.dst[s];
      for (long long i = base; i < n8; i += stride){
        float4 lo = ((const float4*)sp)[i*2];
        float4 hi = ((const float4*)sp)[i*2+1];
        u16x8 p;
        p[0]=f2b(lo.x); p[1]=f2b(lo.y); p[2]=f2b(lo.z); p[3]=f2b(lo.w);
        p[4]=f2b(hi.x); p[5]=f2b(hi.y); p[6]=f2b(hi.z); p[7]=f2b(hi.w);
        *(u16x8*)(dst + (i<<3)) = p;
      }
      for (long long i = ((long long)n8<<3) + base; i < n; i += stride)
        dst[i] = f2b(sp[i]);
    }
  } else if (bxg < 1280){
    // ---------------- build_wb ----------------
    const int f  = (int)bxg - 1024;
    const int bwx = f & 1, bwy = (f >> 1) & 1, z = f >> 2;
    const int s = z >> 3, t = z & 7;
    if (s == t) return;   // diagonal tiles are never read by stage 2 (k-tile skip)
    const long long zoff = (long long)z * 65536;
    const int lane = tid & 63;
    const int w    = tid >> 6;

    f32x4 acc[4][4];
    #pragma unroll
    for (int i=0;i<4;i++)
      #pragma unroll
      for (int j=0;j<4;j++)
        #pragma unroll
        for (int r=0;r<4;r++) acc[i][j][r] = 0.0f;

    const int wr = (w >> 1) * 64, wc = (w & 1) * 64;
    const int fm = lane & 15;
    const int fk = (lane >> 4) * 8;

    int srow[4], sq[4];
    #pragma unroll
    for (int i=0;i<4;i++){
      int c = i*256 + tid;
      srow[i] = c >> 3;
      sq[i]   = (c & 7) ^ (srow[i] & 7);
    }

    for (int k0 = 0; k0 < 256; k0 += 64){
      s16x8 va[4], vt[4];
      #pragma unroll
      for (int i=0;i<4;i++){
        long long aidx = zoff + (long long)(bwx*128 + srow[i]) * 256 + k0 + sq[i]*8;
        va[i] = load8_f32(a.Wo, aidx);
      }
      #pragma unroll
      for (int j=0;j<4;j++){
        int id = j*256 + tid;
        int e  = id >> 4;
        int dc = (id & 15) * 8;
        long long bidx = zoff + (long long)(k0 + e) * 256 + bwy*128 + dc;
        vt[j] = load8_f32(a.Wv, bidx);
      }
      __syncthreads();
      #pragma unroll
      for (int i=0;i<4;i++){
        int c = i*256 + tid;
        *(s16x8*)(lA + c*8) = va[i];
      }
      #pragma unroll
      for (int j=0;j<4;j++){
        int id = j*256 + tid;
        int e  = id >> 4;
        int dc = (id & 15) * 8;
        #pragma unroll
        for (int u=0; u<8; u++){
          int d = dc + u;
          lB[(d*8 + ((e>>3) ^ (d & 7)))*8 + (e & 7)] = (u16)vt[j][u];
        }
      }
      __syncthreads();
      #pragma unroll
      for (int kk = 0; kk < 64; kk += 32){
        s16x8 af[4], bfr[4];
        const int qf = (kk + fk) >> 3;
        #pragma unroll
        for (int mi=0; mi<4; mi++){
          int r = wr + mi*16 + fm;
          af[mi] = *(const s16x8*)(lA + (r*8 + (qf ^ (r & 7))) * 8);
        }
        #pragma unroll
        for (int ni=0; ni<4; ni++){
          int r = wc + ni*16 + fm;
          bfr[ni] = *(const s16x8*)(lB + (r*8 + (qf ^ (r & 7))) * 8);
        }
        #pragma unroll
        for (int mi=0; mi<4; mi++)
          #pragma unroll
          for (int ni=0; ni<4; ni++)
            acc[mi][ni] = __builtin_amdgcn_mfma_f32_16x16x32_bf16(af[mi], bfr[ni], acc[mi][ni], 0, 0, 0);
      }
      __syncthreads();
    }
    #pragma unroll
    for (int mi=0; mi<4; mi++){
      #pragma unroll
      for (int ni=0; ni<4; ni++){
        int d = bwy*128 + wc + ni*16 + fm;
        #pragma unroll
        for (int r=0; r<4; r++){
          int o = bwx*128 + wr + mi*16 + (lane>>4)*4 + r;
          a.WB[(long long)(s*256 + o) * 2048 + t*256 + d] = f2b(acc[mi][ni][r]);
        }
      }
    }
  } else if (bxg < 1312){
    // ---------------- cb (atomic-free) ----------------
    const int f = (int)bxg - 1280;
    const int s = f >> 2, chunk = f & 3;
    const int lane = tid & 63, wv = tid >> 6;
    float pp[16];
    #pragma unroll
    for (int i=0;i<16;i++) pp[i] = 0.0f;
    #pragma unroll
    for (int t2 = 0; t2 < 8; t2++){
      if (t2 == s) continue;
      const int z = s*8 + t2;
      float4 bvv = *(const float4*)(a.bv + (long long)z*256 + lane*4);
      #pragma unroll
      for (int i=0;i<16;i++){
        int row = chunk*64 + wv*16 + i;
        float4 w4 = *(const float4*)(a.Wo + (long long)z*65536 + (long long)row*256 + lane*4);
        pp[i] += w4.x*bvv.x + w4.y*bvv.y + w4.z*bvv.z + w4.w*bvv.w;
      }
    }
    #pragma unroll
    for (int i=0;i<16;i++){
      #pragma unroll
      for (int off=32; off>0; off>>=1) pp[i] += __shfl_xor(pp[i], off);
    }
    if (lane == 0){
      #pragma unroll
      for (int i=0;i<16;i++){
        int row = chunk*64 + wv*16 + i;
        float bos = 0.0f;
        #pragma unroll
        for (int t2=0; t2<8; t2++){
          if (t2 == s) continue;
          bos += a.bo[(long long)(s*8+t2)*256 + row];
        }
        a.cb[s*256 + row] = (pp[i] + bos) * (1.0f/7.0f);
      }
    }
  } else {
    // ---------------- qctx: 64 q-rows per block, K=256, fp32 inputs ----------------
    const int f = (int)bxg - 1312;           // 0..127
    const long long brow0 = (long long)f * 64;
    const int lane = tid & 63;
    const int w    = tid >> 6;
    const int fm = lane & 15;
    const int fk = (lane >> 4) * 8;

    f32x4 acc[16];
    #pragma unroll
    for (int j=0;j<16;j++)
      #pragma unroll
      for (int r=0;r<4;r++) acc[j][r] = 0.0f;

    for (int k0 = 0; k0 < 256; k0 += 64){
      s16x8 va[2], vb[8];
      #pragma unroll
      for (int i=0;i<2;i++){
        int c = i*256 + tid;
        int r = c >> 3, cs = c & 7;
        int gq = cs ^ (r & 7);
        va[i] = load8_f32(a.q, (brow0 + r) * 256 + k0 + gq*8);
      }
      #pragma unroll
      for (int j=0;j<8;j++){
        int c = j*256 + tid;
        int r = c >> 3, cs = c & 7;
        int gq = cs ^ (r & 7);
        vb[j] = load8_f32(a.Wc1f, (long long)r * 512 + k0 + gq*8);
      }
      __syncthreads();
      #pragma unroll
      for (int i=0;i<2;i++){
        int c = i*256 + tid;
        *(s16x8*)(lA + c*8) = va[i];
      }
      #pragma unroll
      for (int j=0;j<8;j++){
        int c = j*256 + tid;
        *(s16x8*)(lB + c*8) = vb[j];
      }
      __syncthreads();
      #pragma unroll
      for (int kk = 0; kk < 64; kk += 32){
        const int qf = (kk + fk) >> 3;
        int ra = w*16 + fm;
        s16x8 af = *(const s16x8*)(lA + (ra*8 + (qf ^ (ra & 7))) * 8);
        #pragma unroll
        for (int ni=0; ni<16; ni++){
          int r = ni*16 + fm;
          s16x8 bfr = *(const s16x8*)(lB + (r*8 + (qf ^ (r & 7))) * 8);
          acc[ni] = __builtin_amdgcn_mfma_f32_16x16x32_bf16(af, bfr, acc[ni], 0, 0, 0);
        }
      }
      __syncthreads();
    }
    #pragma unroll
    for (int ni=0; ni<16; ni++){
      int n = ni*16 + fm;
      #pragma unroll
      for (int r=0; r<4; r++){
        long long b = brow0 + w*16 + (lane>>4)*4 + r;
        a.qctx[b * 256 + n] = f2b(acc[ni][r]);
      }
    }
  }
}

struct GArgs {
  const u16* A;  long long a_z; long long a_piece; int lda;
  const u16* A2; long long a2_z;
  const u16* B;  long long b_z; int ldb;
  u16*       C;  long long c_z; long long c_npiece; int ldc;
  const u16* bias; long long bias_z;
  const float* cbias;
  float scale;
  int K;
  int relu;
};

// ---------- 256x256 8-phase pipelined GEMM, STAGE-2 SPECIALIZED (diag-skip) ----------
__global__ __launch_bounds__(512, 2) void gemm_8ph(GArgs g){
  alignas(16) __shared__ u16 L[65536]; // [buf(2)][A/B(2)][256 rows * 64 cols]
  const int tid  = threadIdx.x;
  const int lane = tid & 63;
  const int w    = tid >> 6;        // 0..7

  const int wr  = w >> 2;
  const int wcn = w & 3;
  const int fm  = lane & 15;
  const int fq  = lane >> 4;

  const long long arow0 = (long long)blockIdx.x * 256;
  const long long nrow0 = (long long)blockIdx.y * 256;
  const int ny4 = (int)blockIdx.y * 4;

  const int r0  = tid >> 3;
  const int r1  = r0 + 64;
  const int cs  = tid & 7;
  const int gc0 = cs ^ (r0 & 7);
  const int gc1 = cs ^ (r1 & 7);
  const int ldst0 = (w * 64) * 8;
  const int ldst1 = (512 + w * 64) * 8;

  const u16* Az = g.A;
  const u16* Bz = g.B;

  const long long gA0 = (arow0 + r0) * 256  + gc0 * 8;
  const long long gA1 = (arow0 + r1) * 256  + gc1 * 8;
  const long long gB0 = (nrow0 + r0) * 2048 + gc0 * 8;
  const long long gB1 = (nrow0 + r1) * 2048 + gc1 * 8;

#define MAPK(j) ((((j) >= ny4) ? (j) + 4 : (j)) << 6)

#define STAGE_A8(c, k0s, h) do{ \
    const u16* gb_ = Az + (long long)((k0s) >> 8) * 2097152LL + ((k0s) & 255) + (long long)(h) * 32768LL; \
    u16* lb_ = L + ((c) * 2 + 0) * 16384 + (h) * 8192; \
    async_cp16(gb_ + gA0, lb_ + ldst0); \
    async_cp16(gb_ + gA1, lb_ + ldst1); \
  }while(0)
#define STAGE_B8(c, k0s, h) do{ \
    const u16* gb_ = Bz + (k0s) + (long long)(h) * 262144LL; \
    u16* lb_ = L + ((c) * 2 + 1) * 16384 + (h) * 8192; \
    async_cp16(gb_ + gB0, lb_ + ldst0); \
    async_cp16(gb_ + gB1, lb_ + ldst1); \
  }while(0)

  f32x4 acc[8][4];
  #pragma unroll
  for (int i=0;i<8;i++)
    #pragma unroll
    for (int j=0;j<4;j++)
      #pragma unroll
      for (int r=0;r<4;r++) acc[i][j][r] = 0.0f;

  STAGE_A8(0, MAPK(0), 0);  STAGE_A8(0, MAPK(0), 1);
  STAGE_B8(0, MAPK(0), 0);  STAGE_B8(0, MAPK(0), 1);
  STAGE_B8(1, MAPK(1), 0);  STAGE_B8(1, MAPK(1), 1);
  asm volatile("s_waitcnt vmcnt(4)" ::: "memory");
  __builtin_amdgcn_s_barrier();

#define TILE8(cc, k0n1, k0n2, v1, v2) do{ \
    const u16* lA_ = L + ((cc) * 2 + 0) * 16384; \
    const u16* lB_ = L + ((cc) * 2 + 1) * 16384; \
    s16x8 bf[4][2]; \
    _Pragma("unroll") \
    for (int q = 0; q < 4; ++q){ \
      if (q == 0 && (v1)) STAGE_A8((cc) ^ 1, (k0n1), 0); \
      if (q == 1 && (v1)) STAGE_A8((cc) ^ 1, (k0n1), 1); \
      if (q == 2 && (v2)) STAGE_B8((cc), (k0n2), 0); \
      if (q == 3 && (v2)) STAGE_B8((cc), (k0n2), 1); \
      if (q == 0){ \
        _Pragma("unroll") \
        for (int ni = 0; ni < 4; ni++){ \
          const int R = wcn * 64 + ni * 16 + fm; \
          _Pragma("unroll") \
          for (int kk = 0; kk < 2; kk++){ \
            const int qf = kk * 4 + fq; \
            bf[ni][kk] = *(const s16x8*)(lB_ + R * 64 + ((qf ^ (R & 7)) << 3)); \
          } \
        } \
      } \
      s16x8 af[2][2]; \
      _Pragma("unroll") \
      for (int j = 0; j < 2; j++){ \
        const int R = wr * 128 + (q * 2 + j) * 16 + fm; \
        _Pragma("unroll") \
        for (int kk = 0; kk < 2; kk++){ \
          const int qf = kk * 4 + fq; \
          af[j][kk] = *(const s16x8*)(lA_ + R * 64 + ((qf ^ (R & 7)) << 3)); \
        } \
      } \
      __builtin_amdgcn_s_barrier(); \
      __builtin_amdgcn_s_setprio(1); \
      _Pragma("unroll") \
      for (int kk = 0; kk < 2; kk++) \
        _Pragma("unroll") \
        for (int j = 0; j < 2; j++) \
          _Pragma("unroll") \
          for (int ni = 0; ni < 4; ni++) \
            acc[q*2+j][ni] = __builtin_amdgcn_mfma_f32_16x16x32_bf16(af[j][kk], bf[ni][kk], acc[q*2+j][ni], 0, 0, 0); \
      __builtin_amdgcn_s_setprio(0); \
      if (q == 3){ \
        if (v2)      asm volatile("s_waitcnt vmcnt(4)" ::: "memory"); \
        else if (v1) asm volatile("s_waitcnt vmcnt(0)" ::: "memory"); \
      } \
      __builtin_amdgcn_s_barrier(); \
    } \
  }while(0)

  #pragma unroll 1
  for (int j = 0; j < 28; j += 2){
    TILE8(0, MAPK(j+1), MAPK(j+2), (j+1) < 28, (j+2) < 28);
    TILE8(1, MAPK(j+2), MAPK(j+3), (j+2) < 28, (j+3) < 28);
  }

  u16* Cb = g.C;
  #pragma unroll
  for (int mi = 0; mi < 8; mi++){
    #pragma unroll
    for (int ni = 0; ni < 4; ni++){
      const int n = (int)nrow0 + wcn * 64 + ni * 16 + fm;
      float bb = g.cbias ? g.cbias[n] : 0.0f;
      const long long cn = ((long long)(n >> 8)) * 2097152LL + (n & 255);
      #pragma unroll
      for (int r = 0; r < 4; r++){
        const long long b = arow0 + wr * 128 + mi * 16 + fq * 4 + r;
        float v = acc[mi][ni][r] * g.scale + bb;
        Cb[cn + b * 256] = f2b(v);
      }
    }
  }
#undef STAGE_A8
#undef STAGE_B8
#undef TILE8
#undef MAPK
}

// ---------- fused stages 3+4+5b: hid -> fused -> score, one kernel ----------
// Phase A now double-buffered: weight tiles alternate lB / lH (lH free until pack);
// x|cross rows alternate lAb[0]/lAb[1]. STAGE(t+1) issued before compute(t);
// vmcnt(0)+barrier at tile end -> t+1's load latency hides under t's MFMA.
// LDS: lB 32KB + lH 32KB + lAb 16KB = 80KB -> 2 blocks/CU.
struct S34Args {
  const u16* X;    // [z*BD + b*256 + k]
  const u16* CR;   // cross, same layout
  const u16* W1;   // [z*131072 + d*512 + k]
  const u16* W2;   // [z*65536 + o*256 + d]
  const u16* Wc1h; // [d'*512 + 256 + o]
  const u16* b1;   // [z*256 + d]
  const u16* b2;   // [z*256 + o]
  const u16* bc1;  // [256]
  const u16* wc2;  // [256]
  const u16* qctx; // [b*256 + d']
  const float* bc2f;
  float*     scores; // [z*BB + b]
  u16*       F;    // fused out, [z*BD + b*256 + o]
};
__global__ __launch_bounds__(256, 2) void gemm_s345(S34Args a){
  alignas(16) __shared__ u16 lB[256*64];     // 32KB: weight buf0 (all phases)
  alignas(16) __shared__ u16 lH[64*256];     // 32KB: weight buf1 (phase A) -> hid/fused tile
  alignas(16) __shared__ u16 lAb[2][64*64];  // 2x8KB: x|cross dbuf (phase A)

  const int tid  = threadIdx.x;
  const int lane = tid & 63;
  const int w    = tid >> 6;
  const int z    = blockIdx.z;

  const int fm = lane & 15;
  const int fq = lane >> 4;
  const long long arow0 = (long long)blockIdx.x * 64;
  const long long BD = (long long)BB * DD;

  const int sr = lane >> 3;
  const int sq = (lane & 7) ^ sr;

  const u16* Xz  = a.X  + (long long)z * BD;
  const u16* CRz = a.CR + (long long)z * BD;
  const u16* W1z = a.W1 + (long long)z * 131072;
  const u16* W2z = a.W2 + (long long)z * 65536;

  // ---------------- phase A: hid (swapped operands), dbuf pipelined ----------------
  f32x4 acc[16];
  #pragma unroll
  for (int j=0;j<16;j++)
    #pragma unroll
    for (int r=0;r<4;r++) acc[j][r] = 0.0f;

  // stage x|cross tile t (t*64 in K=512) -> dst
#define STA_A(t, dst) do{ \
    const u16* At_ = ((t) < 4) ? (Xz + (t)*64) : (CRz + ((t)-4)*64); \
    _Pragma("unroll") \
    for (int i=0;i<2;i++){ \
      int r = i*32 + w*8 + sr; \
      async_cp16(At_ + (arow0 + r) * 256 + sq*8, (dst) + (i*256 + w*64) * 8); \
    } \
  }while(0)
  // stage W1 tile t -> dst (lB or lH)
#define STB_A(t, dst) do{ \
    const u16* Bt_ = W1z + (t)*64; \
    _Pragma("unroll") \
    for (int i=0;i<8;i++){ \
      int r = i*32 + w*8 + sr; \
      async_cp16(Bt_ + (long long)r * 512 + sq*8, (dst) + (i*256 + w*64) * 8); \
    } \
  }while(0)
#define COMPUTE_A(la, wb) do{ \
    _Pragma("unroll") \
    for (int kk = 0; kk < 64; kk += 32){ \
      const int qf = (kk >> 3) + fq; \
      int ra = w*16 + fm; \
      s16x8 af = *(const s16x8*)((la) + (ra*8 + (qf ^ (ra & 7))) * 8); \
      _Pragma("unroll") \
      for (int ni=0; ni<16; ni++){ \
        int r = ni*16 + fm; \
        s16x8 bfr = *(const s16x8*)((wb) + (r*8 + (qf ^ (r & 7))) * 8); \
        acc[ni] = __builtin_amdgcn_mfma_f32_16x16x32_bf16(bfr, af, acc[ni], 0, 0, 0); \
      } \
    } \
  }while(0)

  // prologue: tile 0 -> lAb[0], lB
  STA_A(0, lAb[0]);
  STB_A(0, lB);
  asm volatile("s_waitcnt vmcnt(0)" ::: "memory");
  __builtin_amdgcn_s_barrier();

  #pragma unroll
  for (int tp = 0; tp < 4; tp++){
    const int t0 = tp*2, t1 = tp*2 + 1;
    // even tile: read lAb[0], lB ; stage t0+1 -> lAb[1], lH
    if (t0 + 1 < 8){ STA_A(t0+1, lAb[1]); STB_A(t0+1, lH); }
    COMPUTE_A(lAb[0], lB);
    asm volatile("s_waitcnt vmcnt(0)" ::: "memory");
    __builtin_amdgcn_s_barrier();
    // odd tile: read lAb[1], lH ; stage t1+1 -> lAb[0], lB
    if (t1 + 1 < 8){ STA_A(t1+1, lAb[0]); STB_A(t1+1, lB); }
    COMPUTE_A(lAb[1], lH);
    asm volatile("s_waitcnt vmcnt(0)" ::: "memory");
    __builtin_amdgcn_s_barrier();
  }
#undef STA_A
#undef STB_A
#undef COMPUTE_A

  // pack relu(hid + b1) -> lH[b][d], swizzled chunks (16B chunk c; c low3 ^= b&7)
  // (all waves past tile-7 barrier -> lH free to overwrite)
  {
    const int b = w*16 + fm;
    #pragma unroll
    for (int ni=0; ni<16; ni++){
      s16x4 b1v = *(const s16x4*)(a.b1 + (long long)z*256 + ni*16 + fq*4);
      u16x4 pk;
      #pragma unroll
      for (int r=0; r<4; r++){
        float v = acc[ni][r] + b2f((u16)b1v[r]);
        v = v > 0.0f ? v : 0.0f;
        pk[r] = f2b(v);
      }
      const int c = ni*2 + (fq >> 1);              // 16B-chunk index 0..31
      const int csw = (c & ~7) | ((c & 7) ^ (b & 7));
      *(u16x4*)(lH + b*256 + csw*8 + (fq & 1)*4) = pk;
    }
  }

  // ---------------- phase B: fused = hid @ W2^T + b2 (swapped operands) ----------------
  f32x4 acc2[16];
  #pragma unroll
  for (int j=0;j<16;j++)
    #pragma unroll
    for (int r=0;r<4;r++) acc2[j][r] = 0.0f;

  for (int k0 = 0; k0 < 256; k0 += 64){
    const u16* Bt = W2z + k0;
    __syncthreads();
    #pragma unroll
    for (int i=0;i<8;i++){
      int r = i*32 + w*8 + sr;
      async_cp16(Bt + (long long)r * 256 + sq*8, lB + (i*256 + w*64) * 8);
    }
    __syncthreads();
    #pragma unroll
    for (int kk = 0; kk < 64; kk += 32){
      const int ra = w*16 + fm;
      const int qa = ((k0 + kk) >> 3) + fq;        // 0..31 chunk in lH row
      const int qsw = (qa & ~7) | ((qa & 7) ^ (ra & 7));
      s16x8 af = *(const s16x8*)(lH + ra*256 + qsw*8);
      const int qf = (kk >> 3) + fq;               // 0..7 chunk in lB row
      #pragma unroll
      for (int ni=0; ni<16; ni++){
        int r = ni*16 + fm;
        s16x8 bfr = *(const s16x8*)(lB + (r*8 + (qf ^ (r & 7))) * 8);
        acc2[ni] = __builtin_amdgcn_mfma_f32_16x16x32_bf16(bfr, af, acc2[ni], 0, 0, 0);
      }
    }
  }

  __syncthreads();

  // fused + b2 -> global (u16x4) AND pack into lH[b][o]
  {
    const int b = w*16 + fm;
    u16* Fz = a.F + (long long)z * BD;
    #pragma unroll
    for (int ni=0; ni<16; ni++){
      s16x4 b2v = *(const s16x4*)(a.b2 + (long long)z*256 + ni*16 + fq*4);
      u16x4 pk;
      #pragma unroll
      for (int r=0; r<4; r++)
        pk[r] = f2b(acc2[ni][r] + b2f((u16)b2v[r]));
      *(u16x4*)(Fz + (arow0 + b)*256 + ni*16 + fq*4) = pk;
      const int c = ni*2 + (fq >> 1);
      const int csw = (c & ~7) | ((c & 7) ^ (b & 7));
      *(u16x4*)(lH + b*256 + csw*8 + (fq & 1)*4) = pk;
    }
  }

  // ---------------- phase C: ch = fused @ Wc1h^T (standard operands) ----------------
  f32x4 acc3[16];
  #pragma unroll
  for (int j=0;j<16;j++)
    #pragma unroll
    for (int r=0;r<4;r++) acc3[j][r] = 0.0f;

  for (int k0 = 0; k0 < 256; k0 += 64){
    const u16* Bt = a.Wc1h + k0;
    __syncthreads();
    #pragma unroll
    for (int i=0;i<8;i++){
      int r = i*32 + w*8 + sr;
      async_cp16(Bt + (long long)r * 512 + sq*8, lB + (i*256 + w*64) * 8);
    }
    __syncthreads();
    #pragma unroll
    for (int kk = 0; kk < 64; kk += 32){
      const int ra = w*16 + fm;
      const int qa = ((k0 + kk) >> 3) + fq;
      const int qsw = (qa & ~7) | ((qa & 7) ^ (ra & 7));
      s16x8 af = *(const s16x8*)(lH + ra*256 + qsw*8);
      const int qf = (kk >> 3) + fq;
      #pragma unroll
      for (int ni=0; ni<16; ni++){
        int r = ni*16 + fm;
        s16x8 bfr = *(const s16x8*)(lB + (r*8 + (qf ^ (r & 7))) * 8);
        acc3[ni] = __builtin_amdgcn_mfma_f32_16x16x32_bf16(af, bfr, acc3[ni], 0, 0, 0);
      }
    }
  }

  // score epilogue: relu(ch + qctx + bc1) . wc2 -> sigmoid -> scores
  float p[4] = {0.f, 0.f, 0.f, 0.f};
  #pragma unroll
  for (int ni=0; ni<16; ni++){
    int n = ni*16 + fm;
    float bb = b2f(a.bc1[n]);
    float wcv = b2f(a.wc2[n]);
    #pragma unroll
    for (int r=0; r<4; r++){
      long long b = arow0 + w*16 + fq*4 + r;
      float v = acc3[ni][r] + bb + b2f(a.qctx[b*256 + n]);
      v = v > 0.0f ? v : 0.0f;
      p[r] += v * wcv;
    }
  }
  #pragma unroll
  for (int r=0; r<4; r++){
    #pragma unroll
    for (int off=1; off<16; off<<=1) p[r] += __shfl_xor(p[r], off);
  }
  if (fm == 0){
    float bc2v = a.bc2f[0];
    #pragma unroll
    for (int r=0; r<4; r++){
      long long b = arow0 + w*16 + fq*4 + r;
      a.scores[(long long)z*BB + b] = 1.0f / (1.0f + __expf(-(p[r] + bc2v)));
    }
  }
}

// out[b,:] = (1/8) sum_m fused[m,b,:] * scores[m,b]   (grid-stride over b)
__global__ __launch_bounds__(256) void final_gate(const u16* fused, const float* scores, float* out){
  const int tid = threadIdx.x;
  for (int b = blockIdx.x; b < BB; b += gridDim.x){
    float acc = 0.0f;
    #pragma unroll
    for (int m=0; m<8; m++)
      acc += b2f(fused[((long long)m*BB + b)*256 + tid]) * scores[(long long)m*BB + b];
    out[(long long)b*256 + tid] = acc * 0.125f;
  }
}

extern "C" void kernel_launch(void* const* d_in, const int* in_sizes, int n_in,
                              void* d_out, int out_size, void* d_ws, size_t ws_size,
                              hipStream_t stream){
  const float* x   = (const float*)d_in[0];
  const float* q   = (const float*)d_in[1];
  const float* Wv  = (const float*)d_in[2];
  const float* bv  = (const float*)d_in[3];
  const float* Wo  = (const float*)d_in[4];
  const float* bo  = (const float*)d_in[5];
  const float* W1  = (const float*)d_in[6];
  const float* b1  = (const float*)d_in[7];
  const float* W2  = (const float*)d_in[8];
  const float* b2  = (const float*)d_in[9];
  const float* Wc1 = (const float*)d_in[10];
  const float* bc1 = (const float*)d_in[11];
  const float* wc2 = (const float*)d_in[12];
  const float* bc2 = (const float*)d_in[13];

  char* ws = (char*)d_ws;
  u16*   xb    = (u16*)(ws + 0LL);            // 32MB; dead after s345 phase A -> fused
  u16*   cross = (u16*)(ws + 37748736LL);     // 32MB
  u16*   qctx  = (u16*)(ws + 71303168LL);     // 4MB (free region; written by prep)
  u16*   WB    = (u16*)(ws + 104857600LL);    // 8MB; scores reuse upper half after stage2
  u16*   W1b   = (u16*)(ws + 113246208LL);    // 2MB
  u16*   W2b   = (u16*)(ws + 115343360LL);    // 1MB
  u16*   Wc1b  = (u16*)(ws + 116391936LL);    // 256KB
  u16*   b1b   = (u16*)(ws + 116654080LL);    // 4KB
  u16*   b2b   = (u16*)(ws + 116658176LL);    // 4KB
  u16*   bc1b  = (u16*)(ws + 116662272LL);    // 512B
  u16*   wc2b  = (u16*)(ws + 116662784LL);    // 512B
  float* bc2f  = (float*)(ws + 116663296LL);  // 64B (fp32 copy)
  float* cb    = (float*)(ws + 116663424LL);  // 8KB
  u16*   fused = xb;
  float* scores = (float*)(ws + 104857600LL + 4194304LL); // 256KB (dead WB upper half)

  PrepArgs pa{};
  pa.src[0]=x;   pa.dst[0]=xb;   pa.n[0]=MMOD*BB*DD;
  pa.src[1]=x;   pa.dst[1]=xb;   pa.n[1]=0;            // (qb no longer needed)
  pa.src[2]=W1;  pa.dst[2]=W1b;  pa.n[2]=MMOD*DD*2*DD;
  pa.src[3]=W2;  pa.dst[3]=W2b;  pa.n[3]=MMOD*DD*DD;
  pa.src[4]=Wc1; pa.dst[4]=Wc1b; pa.n[4]=DD*2*DD;
  pa.src[5]=b1;  pa.dst[5]=b1b;  pa.n[5]=MMOD*DD;
  pa.src[6]=b2;  pa.dst[6]=b2b;  pa.n[6]=MMOD*DD;
  pa.src[7]=bc1; pa.dst[7]=bc1b; pa.n[7]=DD;
  pa.src[8]=wc2; pa.dst[8]=wc2b; pa.n[8]=DD;
  pa.src[9]=bc2; pa.dst[9]=bc1b; pa.n[9]=0;
  pa.bc2 = bc2; pa.bc2f = bc2f;
  pa.Wo = Wo; pa.Wv = Wv; pa.WB = WB;
  pa.bv = bv; pa.bo = bo; pa.cb = cb;
  pa.q = q; pa.Wc1f = Wc1; pa.qctx = qctx;
  prep_kernel<<<1440, 256, 0, stream>>>(pa);

  const long long BD = (long long)BB * DD;

  // Stage 2 (256^2 8-phase, diag-skip): cross[s,b,o] = (1/7) sum_{k,t!=s} xb'[b,k]*WB[(s,o),k] + cb
  GArgs g2{};
  g2.A = xb; g2.a_z = 0; g2.a_piece = BD; g2.lda = 256; g2.A2 = 0; g2.a2_z = 0;
  g2.B = WB; g2.b_z = 0; g2.ldb = 2048;
  g2.C = cross; g2.c_z = 0; g2.c_npiece = BD; g2.ldc = 256;
  g2.bias = 0; g2.bias_z = 0; g2.cbias = cb;
  g2.scale = 1.0f/7.0f; g2.K = 2048; g2.relu = 0;
  gemm_8ph<<<dim3(32,8,1), 512, 0, stream>>>(g2);

  // Stages 3+4+5b fused
  S34Args s34{};
  s34.X = xb; s34.CR = cross; s34.W1 = W1b; s34.W2 = W2b; s34.Wc1h = Wc1b + 256;
  s34.b1 = b1b; s34.b2 = b2b; s34.bc1 = bc1b; s34.wc2 = wc2b;
  s34.qctx = qctx; s34.bc2f = bc2f; s34.scores = scores; s34.F = fused;
  gemm_s345<<<dim3(128,1,8), 256, 0, stream>>>(s34);

  final_gate<<<dim3(1024), 256, 0, stream>>>(fused, scores, (float*)d_out);

  (void)in_sizes; (void)n_in; (void)out_size; (void)ws_size;
}